// Round 13
// baseline (4543.204 us; speedup 1.0000x reference)
//
#include <hip/hip_runtime.h>
#include <hip/hip_bf16.h>

// GPT-2 small forward on gfx950. bf16 MFMA GEMMs (f32 accum), flash attention.
// R13: BARRIER-FREE GEMM. Diagnosis: all five prior structures pinned at
//      MfmaUtil ~25% (the 2-phase ceiling, m233) because per-tile barriers
//      lockstep the waves: [all read LDS][all MFMA] phases serialize.
//      Fix: wave-PRIVATE double-buffered LDS (each wave stages its own
//      64x32 A band + 64x32 B band; 16KB/wave, 64KB/block, 2 blocks/CU).
//      All ordering is intra-wave via vmcnt(8)/lgkmcnt(0); ZERO s_barrier
//      in the K-loop -> waves de-phase and cover each other's read windows.

typedef __bf16 bh_t;
typedef __bf16 bfx4 __attribute__((ext_vector_type(4)));
typedef __bf16 bfx8 __attribute__((ext_vector_type(8)));
typedef float  fx4  __attribute__((ext_vector_type(4)));

#define CDIM 768
#define TSEQ 1024
#define NHEAD 12
#define HDIM 64
#define NLAYER 12
#define MROWS 4096          // B*T
#define VOCAB 50257

__device__ __forceinline__ void gload_lds16(const void* g, void* l) {
  __builtin_amdgcn_global_load_lds(
      (const __attribute__((address_space(1))) void*)g,
      (__attribute__((address_space(3))) void*)l, 16, 0, 0);
}

__device__ __forceinline__ fx4 mfma16(bfx8 a, bfx8 b, fx4 c) {
  return __builtin_amdgcn_mfma_f32_16x16x32_bf16(a, b, c, 0, 0, 0);
}

// ---------------------------------------------------------------------------
// 128x128 GEMM, BK=32, wave-private dbuf LDS (64KB/block), 2 blocks/CU,
// NO barriers. 4 waves (2M x 2N), wave tile 64x64, acc 4x4.
// Per wave per tile: 8 gload_lds (own A+B bands) + 8 ds_read_b128 + 16 MFMA.
// vmcnt(8) retires own tile-t loads while tile-t+1's 8 stay in flight.
// Swizzle slot ^= (row>>1)&3 on both stage-source and read (verified 0-conflict).
// blockIdx.z = split-K slice. flags: 1=bias, 4=gelu, 8=out bf16. nt even.
// ---------------------------------------------------------------------------
__global__ __launch_bounds__(256, 2) void gemm_wp(
    const bh_t* __restrict__ A, const bh_t* __restrict__ B,
    const float* __restrict__ bias, void* __restrict__ outp,
    int M, int N, int K, int lda, int flags)
{
  __shared__ bh_t LA[2][4][64][32];   // [buf][wave][row][k]
  __shared__ bh_t LB[2][4][64][32];
  const int tid = threadIdx.x;
  const int wid = tid >> 6, lane = tid & 63;
  const int g = lane >> 4, r16 = lane & 15;
  const int wr = wid >> 1, wc = wid & 1;        // 2M x 2N waves
  const int m0 = blockIdx.x * 128, n0 = blockIdx.y * 128;
  const int swk = (g ^ ((r16 >> 1) & 3)) * 8;   // swizzled slot offset (elems)

  const bh_t* AbW = A + (size_t)blockIdx.z * K + (size_t)(m0 + wr * 64) * lda;
  const bh_t* BbW = B + (size_t)blockIdx.z * K + (size_t)(n0 + wc * 64) * lda;
  const int nt = K >> 5;

  bh_t* myA0 = &LA[0][wid][0][0];
  bh_t* myA1 = &LA[1][wid][0][0];
  bh_t* myB0 = &LB[0][wid][0][0];
  bh_t* myB1 = &LB[1][wid][0][0];

  fx4 acc[4][4] = {};

  // stage tile t into this wave's private buffers: 4+4 gloads per lane.
  auto stage = [&](bh_t* dA, bh_t* dB, int t) {
    const int k0 = t << 5;
    #pragma unroll
    for (int j = 0; j < 4; ++j) {
      const int idx = j * 64 + lane;            // 0..255 16B-units
      const int row = idx >> 2;                 // 0..63
      const int slot = (idx & 3) ^ ((row >> 1) & 3);
      gload_lds16(AbW + (size_t)row * lda + k0 + slot * 8, dA + (size_t)idx * 8);
    }
    #pragma unroll
    for (int j = 0; j < 4; ++j) {
      const int idx = j * 64 + lane;
      const int row = idx >> 2;
      const int slot = (idx & 3) ^ ((row >> 1) & 3);
      gload_lds16(BbW + (size_t)row * lda + k0 + slot * 8, dB + (size_t)idx * 8);
    }
  };

  // tile t: prefetch t+1 into the other buffer, wait own tile-t loads
  // (vmcnt(8): t+1's 8 stay in flight), read frags, 16 MFMA. NO barrier.
#define WP_TILE(CA, CB, NA, NB, T)                                            \
  {                                                                           \
    if ((T) + 1 < nt) {                                                       \
      stage(NA, NB, (T) + 1);                                                 \
      asm volatile("s_waitcnt vmcnt(8)" ::: "memory");                        \
    } else {                                                                  \
      asm volatile("s_waitcnt vmcnt(0)" ::: "memory");                        \
    }                                                                         \
    bfx8 av[4], bv[4];                                                        \
    _Pragma("unroll")                                                         \
    for (int ni = 0; ni < 4; ++ni)                                            \
      bv[ni] = *(const bfx8*)(CB + (size_t)(ni * 16 + r16) * 32 + swk);       \
    _Pragma("unroll")                                                         \
    for (int mi = 0; mi < 4; ++mi)                                            \
      av[mi] = *(const bfx8*)(CA + (size_t)(mi * 16 + r16) * 32 + swk);       \
    asm volatile("s_waitcnt lgkmcnt(0)" ::: "memory");                        \
    __builtin_amdgcn_s_setprio(1);                                            \
    _Pragma("unroll")                                                         \
    for (int mi = 0; mi < 4; ++mi)                                            \
      _Pragma("unroll")                                                       \
      for (int ni = 0; ni < 4; ++ni)                                          \
        acc[mi][ni] = mfma16(av[mi], bv[ni], acc[mi][ni]);                    \
    __builtin_amdgcn_s_setprio(0);                                            \
  }

  stage(myA0, myB0, 0);
  for (int t = 0; t < nt; t += 2) {
    WP_TILE(myA0, myB0, myA1, myB1, t);
    WP_TILE(myA1, myB1, myA0, myB0, t + 1);
  }
#undef WP_TILE

  const bool hasBias = flags & 1, doGelu = flags & 4, outBf = flags & 8;
  float* outF = (float*)outp + (size_t)blockIdx.z * ((size_t)M * N);
  bh_t*  outB = (bh_t*)outp;
  #pragma unroll
  for (int mi = 0; mi < 4; ++mi) {
    const int rowb = m0 + wr * 64 + mi * 16 + 4 * g;
    #pragma unroll
    for (int ni = 0; ni < 4; ++ni) {
      const int col = n0 + wc * 64 + ni * 16 + r16;
      if (col >= N) continue;
      const float bv = hasBias ? bias[col] : 0.0f;
      #pragma unroll
      for (int rr = 0; rr < 4; ++rr) {
        const size_t idx = (size_t)(rowb + rr) * N + col;
        float v = acc[mi][ni][rr] + bv;
        if (doGelu) v = 0.5f * v * (1.0f + erff(v * 0.70710678118654752f));
        if (outBf) outB[idx] = (bh_t)v; else outF[idx] = v;
      }
    }
  }
}

// ---------------------------------------------------------------------------
// fused split-K reduce + residual + LayerNorm
// ---------------------------------------------------------------------------
__global__ __launch_bounds__(256) void skred_ln(
    const float* __restrict__ part, const float* __restrict__ bias,
    float* __restrict__ x, const float* __restrict__ w,
    const float* __restrict__ bb, bh_t* __restrict__ out, int S)
{
  const int wave = threadIdx.x >> 6, lane = threadIdx.x & 63;
  const int row = blockIdx.x * 4 + wave;
  const size_t base = (size_t)row * CDIM;
  const int off = lane * 4;
  const size_t stride = (size_t)MROWS * CDIM;

  float4 v0 = *(const float4*)(x + base + off);
  float4 v1 = *(const float4*)(x + base + 256 + off);
  float4 v2 = *(const float4*)(x + base + 512 + off);
  for (int s = 0; s < S; ++s) {
    const float* pr = part + s * stride + base;
    const float4 p0 = *(const float4*)(pr + off);
    const float4 p1 = *(const float4*)(pr + 256 + off);
    const float4 p2 = *(const float4*)(pr + 512 + off);
    v0.x += p0.x; v0.y += p0.y; v0.z += p0.z; v0.w += p0.w;
    v1.x += p1.x; v1.y += p1.y; v1.z += p1.z; v1.w += p1.w;
    v2.x += p2.x; v2.y += p2.y; v2.z += p2.z; v2.w += p2.w;
  }
  const float4 q0 = *(const float4*)(bias + off);
  const float4 q1 = *(const float4*)(bias + 256 + off);
  const float4 q2 = *(const float4*)(bias + 512 + off);
  v0.x += q0.x; v0.y += q0.y; v0.z += q0.z; v0.w += q0.w;
  v1.x += q1.x; v1.y += q1.y; v1.z += q1.z; v1.w += q1.w;
  v2.x += q2.x; v2.y += q2.y; v2.z += q2.z; v2.w += q2.w;
  *(float4*)(x + base + off) = v0;
  *(float4*)(x + base + 256 + off) = v1;
  *(float4*)(x + base + 512 + off) = v2;

  float s1 = v0.x + v0.y + v0.z + v0.w + v1.x + v1.y + v1.z + v1.w
           + v2.x + v2.y + v2.z + v2.w;
  float ss = v0.x*v0.x + v0.y*v0.y + v0.z*v0.z + v0.w*v0.w
           + v1.x*v1.x + v1.y*v1.y + v1.z*v1.z + v1.w*v1.w
           + v2.x*v2.x + v2.y*v2.y + v2.z*v2.z + v2.w*v2.w;
  #pragma unroll
  for (int d = 1; d < 64; d <<= 1) { s1 += __shfl_xor(s1, d); ss += __shfl_xor(ss, d); }
  const float mean = s1 * (1.0f / 768.0f);
  const float inv = rsqrtf(ss * (1.0f / 768.0f) - mean * mean + 1e-5f);
  bh_t* orow = out + base;

  const float4 w0 = *(const float4*)(w + off),       b0 = *(const float4*)(bb + off);
  const float4 w1 = *(const float4*)(w + 256 + off), b1 = *(const float4*)(bb + 256 + off);
  const float4 w2 = *(const float4*)(w + 512 + off), b2 = *(const float4*)(bb + 512 + off);
  bfx4 o;
  o[0] = (bh_t)((v0.x - mean) * inv * w0.x + b0.x);
  o[1] = (bh_t)((v0.y - mean) * inv * w0.y + b0.y);
  o[2] = (bh_t)((v0.z - mean) * inv * w0.z + b0.z);
  o[3] = (bh_t)((v0.w - mean) * inv * w0.w + b0.w);
  *(bfx4*)(orow + off) = o;
  o[0] = (bh_t)((v1.x - mean) * inv * w1.x + b1.x);
  o[1] = (bh_t)((v1.y - mean) * inv * w1.y + b1.y);
  o[2] = (bh_t)((v1.z - mean) * inv * w1.z + b1.z);
  o[3] = (bh_t)((v1.w - mean) * inv * w1.w + b1.w);
  *(bfx4*)(orow + 256 + off) = o;
  o[0] = (bh_t)((v2.x - mean) * inv * w2.x + b2.x);
  o[1] = (bh_t)((v2.y - mean) * inv * w2.y + b2.y);
  o[2] = (bh_t)((v2.z - mean) * inv * w2.z + b2.z);
  o[3] = (bh_t)((v2.w - mean) * inv * w2.w + b2.w);
  *(bfx4*)(orow + 512 + off) = o;
}

// ---------------------------------------------------------------------------
// Flash attention, causal. One wave per (b, h, 16 q-rows).
// ---------------------------------------------------------------------------
__global__ __launch_bounds__(256) void attn_fwd(
    const bh_t* __restrict__ qkv, const bh_t* __restrict__ vT,
    bh_t* __restrict__ outb)
{
  __shared__ bh_t P[4][16][56];
  const int wave = threadIdx.x >> 6, lane = threadIdx.x & 63;
  const int g = lane >> 4, r16 = lane & 15;
  const int gw = blockIdx.x * 4 + wave;
  const int qblk = gw & 63;
  const int bh = gw >> 6;
  const int h = bh % NHEAD, b = bh / NHEAD;
  const int qbase = qblk * 16;
  const int qidx = qbase + r16;

  const bh_t* qp = qkv + (size_t)(b * TSEQ + qbase + r16) * (3 * CDIM) + h * HDIM + 8 * g;
  const bfx8 qf0 = *(const bfx8*)qp;
  const bfx8 qf1 = *(const bfx8*)(qp + 32);

  fx4 o[4] = {};
  float m = -INFINITY, l = 0.0f;
  const int ntiles = qblk / 2 + 1;

  for (int t = 0; t < ntiles; ++t) {
    const int kv0 = t * 32;
    const bh_t* kp = qkv + (size_t)(b * TSEQ + kv0 + r16) * (3 * CDIM) + CDIM + h * HDIM + 8 * g;
    const bfx8 ka0 = *(const bfx8*)kp;
    const bfx8 ka1 = *(const bfx8*)(kp + 32);
    const bfx8 kb0 = *(const bfx8*)(kp + 16 * (3 * CDIM));
    const bfx8 kb1 = *(const bfx8*)(kp + 16 * (3 * CDIM) + 32);
    fx4 s0 = {}, s1 = {};
    s0 = mfma16(ka0, qf0, s0); s0 = mfma16(ka1, qf1, s0);   // S^T: [kv][q]
    s1 = mfma16(kb0, qf0, s1); s1 = mfma16(kb1, qf1, s1);

    float mx = -INFINITY;
    float sv0[4], sv1[4];
    #pragma unroll
    for (int rr = 0; rr < 4; ++rr) {
      const int kva = kv0 + 4 * g + rr;
      const int kvb = kva + 16;
      sv0[rr] = (kva <= qidx) ? s0[rr] * 0.125f : -INFINITY;
      sv1[rr] = (kvb <= qidx) ? s1[rr] * 0.125f : -INFINITY;
      mx = fmaxf(mx, fmaxf(sv0[rr], sv1[rr]));
    }
    mx = fmaxf(mx, __shfl_xor(mx, 16));
    mx = fmaxf(mx, __shfl_xor(mx, 32));
    const float mnew = fmaxf(m, mx);
    const float corr = __expf(m - mnew);

    float ps = 0.0f;
    float pv0[4], pv1[4];
    #pragma unroll
    for (int rr = 0; rr < 4; ++rr) {
      pv0[rr] = __expf(sv0[rr] - mnew);
      pv1[rr] = __expf(sv1[rr] - mnew);
      ps += pv0[rr] + pv1[rr];
    }
    ps += __shfl_xor(ps, 16);
    ps += __shfl_xor(ps, 32);
    l = l * corr + ps;
    m = mnew;

    #pragma unroll
    for (int rr = 0; rr < 4; ++rr) {
      const float cr = __shfl(corr, 4 * g + rr);
      o[0][rr] *= cr; o[1][rr] *= cr; o[2][rr] *= cr; o[3][rr] *= cr;
    }

    bfx4 w0, w1;
    #pragma unroll
    for (int rr = 0; rr < 4; ++rr) { w0[rr] = (bh_t)pv0[rr]; w1[rr] = (bh_t)pv1[rr]; }
    *(bfx4*)&P[wave][r16][4 * g]      = w0;
    *(bfx4*)&P[wave][r16][16 + 4 * g] = w1;
    __builtin_amdgcn_wave_barrier();
    const bfx8 pf = *(const bfx8*)&P[wave][r16][8 * g];

    #pragma unroll
    for (int fi = 0; fi < 4; ++fi) {
      const bh_t* vp = vT + (size_t)(bh * HDIM + fi * 16 + r16) * TSEQ + kv0 + 8 * g;
      const bfx8 vf = *(const bfx8*)vp;
      o[fi] = mfma16(pf, vf, o[fi]);
    }
  }

  #pragma unroll
  for (int rr = 0; rr < 4; ++rr) {
    const float lr = __shfl(l, 4 * g + rr);
    const float inv = 1.0f / lr;
    const int trow = b * TSEQ + qbase + 4 * g + rr;
    #pragma unroll
    for (int fi = 0; fi < 4; ++fi)
      outb[(size_t)trow * CDIM + h * HDIM + fi * 16 + r16] = (bh_t)(o[fi][rr] * inv);
  }
}

// ---------------------------------------------------------------------------
// LayerNorm: f32 in -> bf16 out. One wave per row. (layer 0 entry only)
// ---------------------------------------------------------------------------
__global__ __launch_bounds__(256) void ln_fwd(
    const float* __restrict__ x, const float* __restrict__ w,
    const float* __restrict__ bb, bh_t* __restrict__ out)
{
  const int wave = threadIdx.x >> 6, lane = threadIdx.x & 63;
  const int row = blockIdx.x * 4 + wave;
  const float* xr = x + (size_t)row * CDIM;
  const int off = lane * 4;
  const float4 v0 = *(const float4*)(xr + off);
  const float4 v1 = *(const float4*)(xr + 256 + off);
  const float4 v2 = *(const float4*)(xr + 512 + off);
  float s  = v0.x + v0.y + v0.z + v0.w + v1.x + v1.y + v1.z + v1.w
           + v2.x + v2.y + v2.z + v2.w;
  float ss = v0.x*v0.x + v0.y*v0.y + v0.z*v0.z + v0.w*v0.w
           + v1.x*v1.x + v1.y*v1.y + v1.z*v1.z + v1.w*v1.w
           + v2.x*v2.x + v2.y*v2.y + v2.z*v2.z + v2.w*v2.w;
  #pragma unroll
  for (int d = 1; d < 64; d <<= 1) { s += __shfl_xor(s, d); ss += __shfl_xor(ss, d); }
  const float mean = s * (1.0f / 768.0f);
  const float inv = rsqrtf(ss * (1.0f / 768.0f) - mean * mean + 1e-5f);
  bh_t* orow = out + (size_t)row * CDIM;

  const float4 w0 = *(const float4*)(w + off),  b0 = *(const float4*)(bb + off);
  const float4 w1 = *(const float4*)(w + 256 + off), b1 = *(const float4*)(bb + 256 + off);
  const float4 w2 = *(const float4*)(w + 512 + off), b2 = *(const float4*)(bb + 512 + off);
  bfx4 o;
  o[0] = (bh_t)((v0.x - mean) * inv * w0.x + b0.x);
  o[1] = (bh_t)((v0.y - mean) * inv * w0.y + b0.y);
  o[2] = (bh_t)((v0.z - mean) * inv * w0.z + b0.z);
  o[3] = (bh_t)((v0.w - mean) * inv * w0.w + b0.w);
  *(bfx4*)(orow + off) = o;
  o[0] = (bh_t)((v1.x - mean) * inv * w1.x + b1.x);
  o[1] = (bh_t)((v1.y - mean) * inv * w1.y + b1.y);
  o[2] = (bh_t)((v1.z - mean) * inv * w1.z + b1.z);
  o[3] = (bh_t)((v1.w - mean) * inv * w1.w + b1.w);
  *(bfx4*)(orow + 256 + off) = o;
  o[0] = (bh_t)((v2.x - mean) * inv * w2.x + b2.x);
  o[1] = (bh_t)((v2.y - mean) * inv * w2.y + b2.y);
  o[2] = (bh_t)((v2.z - mean) * inv * w2.z + b2.z);
  o[3] = (bh_t)((v2.w - mean) * inv * w2.w + b2.w);
  *(bfx4*)(orow + 512 + off) = o;
}

// ---------------------------------------------------------------------------
__global__ void embed_k(const int* __restrict__ ids, const float* __restrict__ tok,
                        const float* __restrict__ pos, float* __restrict__ x)
{
  const int bt = blockIdx.x;
  const int t = bt & (TSEQ - 1);
  const int id = ids[bt];
  const float* tr = tok + (size_t)id * CDIM;
  const float* pr = pos + (size_t)t * CDIM;
  float* xr = x + (size_t)bt * CDIM;
  for (int j = threadIdx.x; j < CDIM; j += 256) xr[j] = tr[j] + pr[j];
}

// transpose + f32->bf16: in [L][R][Cn] -> out [L][Cn][R]
__global__ void tconv(const float* __restrict__ in, bh_t* __restrict__ out, int R, int Cn)
{
  __shared__ float tile[32][33];
  const size_t msz = (size_t)R * Cn;
  in  += msz * blockIdx.z;
  out += msz * blockIdx.z;
  const int tx = threadIdx.x & 31, ty = threadIdx.x >> 5;
  const int c0 = blockIdx.x * 32, r0 = blockIdx.y * 32;
  #pragma unroll
  for (int i = 0; i < 32; i += 8)
    tile[ty + i][tx] = in[(size_t)(r0 + ty + i) * Cn + c0 + tx];
  __syncthreads();
  #pragma unroll
  for (int i = 0; i < 32; i += 8)
    out[(size_t)(c0 + ty + i) * R + r0 + tx] = (bh_t)tile[tx][ty + i];
}

// tok_emb f32 [V][C] -> bf16 [VPAD][C], zero-padded rows
#define VPAD 50304
__global__ void embconv(const float* __restrict__ in, bh_t* __restrict__ out)
{
  const size_t i4 = ((size_t)blockIdx.x * 256 + threadIdx.x) * 4;
  if (i4 >= (size_t)VPAD * CDIM) return;
  const size_t vlim = (size_t)VOCAB * CDIM;
  float4 f = make_float4(0.f, 0.f, 0.f, 0.f);
  if (i4 < vlim) f = *(const float4*)(in + i4);
  bfx4 o;
  o[0] = (bh_t)f.x; o[1] = (bh_t)f.y; o[2] = (bh_t)f.z; o[3] = (bh_t)f.w;
  *(bfx4*)(out + i4) = o;
}

// V slice of qkv -> vT[bh*64 + d][t]
__global__ void vtrans(const bh_t* __restrict__ qkv, bh_t* __restrict__ vT)
{
  __shared__ bh_t tile[32][34];
  const int bh = blockIdx.z;
  const int b = bh / NHEAD, h = bh % NHEAD;
  const int d0 = blockIdx.x * 32, t0 = blockIdx.y * 32;
  const int tx = threadIdx.x & 31, ty = threadIdx.x >> 5;
  #pragma unroll
  for (int i = 0; i < 32; i += 8)
    tile[ty + i][tx] = qkv[(size_t)(b * TSEQ + t0 + ty + i) * (3 * CDIM) + 2 * CDIM + h * HDIM + d0 + tx];
  __syncthreads();
  #pragma unroll
  for (int i = 0; i < 32; i += 8)
    vT[(size_t)(bh * HDIM + d0 + ty + i) * TSEQ + t0 + tx] = tile[tx][ty + i];
}

// ---------------------------------------------------------------------------
extern "C" void kernel_launch(void* const* d_in, const int* in_sizes, int n_in,
                              void* d_out, int out_size, void* d_ws, size_t ws_size,
                              hipStream_t stream)
{
  (void)in_sizes; (void)n_in; (void)out_size; (void)ws_size;
  const int*   ids    = (const int*)d_in[0];
  const float* tok    = (const float*)d_in[1];
  const float* pos    = (const float*)d_in[2];
  const float* qkv_w  = (const float*)d_in[3];
  const float* qkv_b  = (const float*)d_in[4];
  const float* proj_w = (const float*)d_in[5];
  const float* proj_b = (const float*)d_in[6];
  const float* ln1_w  = (const float*)d_in[7];
  const float* ln1_b  = (const float*)d_in[8];
  const float* ln2_w  = (const float*)d_in[9];
  const float* ln2_b  = (const float*)d_in[10];
  const float* fc1_w  = (const float*)d_in[11];
  const float* fc1_b  = (const float*)d_in[12];
  const float* fc2_w  = (const float*)d_in[13];
  const float* fc2_b  = (const float*)d_in[14];
  const float* lnf_w  = (const float*)d_in[15];
  const float* lnf_b  = (const float*)d_in[16];

  // ---- scratch in ws (activations + embT), ~153 MB
  char* wp = (char*)d_ws;
  auto carve = [&](size_t bytes) { char* p = wp; wp += (bytes + 255) & ~(size_t)255; return p; };
  float* x     = (float*)carve((size_t)MROWS * CDIM * 4);
  bh_t*  hbuf  = (bh_t*)carve((size_t)MROWS * CDIM * 2);
  bh_t*  qkvb  = (bh_t*)carve((size_t)MROWS * 3 * CDIM * 2);
  bh_t*  vT    = (bh_t*)carve((size_t)48 * HDIM * TSEQ * 2);
  bh_t*  attno = (bh_t*)carve((size_t)MROWS * CDIM * 2);
  bh_t*  mlp1  = (bh_t*)carve((size_t)MROWS * 3072 * 2);
  bh_t*  embT  = (bh_t*)carve((size_t)VPAD * CDIM * 2);

  // ---- staged in d_out (dead before lm_head overwrites it), ~270 MB of 823
  char* op = (char*)d_out;
  auto carveO = [&](size_t bytes) { char* p = op; op += (bytes + 255) & ~(size_t)255; return p; };
  bh_t* qkvwT  = (bh_t*)carveO((size_t)NLAYER * 3 * CDIM * CDIM * 2);
  bh_t* projwT = (bh_t*)carveO((size_t)NLAYER * CDIM * CDIM * 2);
  bh_t* fc1wT  = (bh_t*)carveO((size_t)NLAYER * 3072 * CDIM * 2);
  bh_t* fc2wT  = (bh_t*)carveO((size_t)NLAYER * CDIM * 3072 * 2);
  float* skpart = (float*)carveO((size_t)4 * MROWS * CDIM * 4);   // split-K partials

  tconv<<<dim3(2304 / 32, 768 / 32, NLAYER), 256, 0, stream>>>(qkv_w, qkvwT, 768, 2304);
  tconv<<<dim3(768 / 32, 768 / 32, NLAYER), 256, 0, stream>>>(proj_w, projwT, 768, 768);
  tconv<<<dim3(3072 / 32, 768 / 32, NLAYER), 256, 0, stream>>>(fc1_w, fc1wT, 768, 3072);
  tconv<<<dim3(768 / 32, 3072 / 32, NLAYER), 256, 0, stream>>>(fc2_w, fc2wT, 3072, 768);
  embconv<<<((VPAD * CDIM / 4) + 255) / 256, 256, 0, stream>>>(tok, embT);
  embed_k<<<MROWS, 256, 0, stream>>>(ids, tok, pos, x);

  ln_fwd<<<MROWS / 4, 256, 0, stream>>>(x, ln1_w, ln1_b, hbuf);
  for (int l = 0; l < NLAYER; ++l) {
    // qkv: grid 32x18 = 576 blocks
    gemm_wp<<<dim3(32, 18), 256, 0, stream>>>(hbuf, qkvwT + (size_t)l * 3 * CDIM * CDIM,
        qkv_b + l * 3 * CDIM, qkvb, MROWS, 3 * CDIM, CDIM, CDIM, 1 | 8);
    vtrans<<<dim3(2, 32, 48), 256, 0, stream>>>(qkvb, vT);
    attn_fwd<<<768, 256, 0, stream>>>(qkvb, vT, attno);
    // proj: split-K x4 (K_eff=192, nt=6), grid 32x6x4 = 768 blocks
    gemm_wp<<<dim3(32, 6, 4), 256, 0, stream>>>(attno,
        projwT + (size_t)l * CDIM * CDIM, nullptr, skpart, MROWS, CDIM, 192, CDIM, 0);
    skred_ln<<<MROWS / 4, 256, 0, stream>>>(skpart, proj_b + l * CDIM, x,
        ln2_w + l * CDIM, ln2_b + l * CDIM, hbuf, 4);
    // fc1: grid 32x24 = 768 blocks
    gemm_wp<<<dim3(32, 24), 256, 0, stream>>>(hbuf, fc1wT + (size_t)l * 3072 * CDIM,
        fc1_b + l * 3072, mlp1, MROWS, 3072, CDIM, CDIM, 1 | 4 | 8);
    // fc2: split-K x4 (K_eff=768, nt=24), grid 32x6x4 = 768 blocks
    gemm_wp<<<dim3(32, 6, 4), 256, 0, stream>>>(mlp1, fc2wT + (size_t)l * CDIM * 3072,
        nullptr, skpart, MROWS, CDIM, 768, 3072, 0);
    const float* nw = (l + 1 < NLAYER) ? ln1_w + (l + 1) * CDIM : lnf_w;
    const float* nb = (l + 1 < NLAYER) ? ln1_b + (l + 1) * CDIM : lnf_b;
    skred_ln<<<MROWS / 4, 256, 0, stream>>>(skpart, fc2_b + l * CDIM, x, nw, nb, hbuf, 4);
  }
  // lm_head: grid 32x393 = 12576 blocks (393*128 = 50304 covers VOCAB)
  gemm_wp<<<dim3(32, 393), 256, 0, stream>>>(hbuf, embT, nullptr,
      (float*)d_out, MROWS, VOCAB, CDIM, CDIM, 0);
}

// Round 14
// 3924.566 us; speedup vs baseline: 1.1576x; 1.1576x over previous
//
#include <hip/hip_runtime.h>
#include <hip/hip_bf16.h>

// GPT-2 small forward on gfx950. bf16 MFMA GEMMs (f32 accum), flash attention.
// R14: revert R13 (wave-private LDS: occupancy halved, staging duplicated,
//      -19%). Back to R12 gemm256n for qkv/fc1/lm_head. NEW: proj/fc2 run
//      WITHOUT split-K on gemm_n64 (128x64 tile, 24KB LDS, 4 blocks/CU,
//      grid 32x12=384): kills 100MB/instance of f32 partial write+read
//      (skred_ln removed; bias+residual fused into GEMM epilogue, LN = ln_fwd).

typedef __bf16 bh_t;
typedef __bf16 bfx4 __attribute__((ext_vector_type(4)));
typedef __bf16 bfx8 __attribute__((ext_vector_type(8)));
typedef float  fx4  __attribute__((ext_vector_type(4)));

#define CDIM 768
#define TSEQ 1024
#define NHEAD 12
#define HDIM 64
#define NLAYER 12
#define MROWS 4096          // B*T
#define VOCAB 50257
#define VPAD  50304         // 393 * 128

__device__ __forceinline__ void gload_lds16(const void* g, void* l) {
  __builtin_amdgcn_global_load_lds(
      (const __attribute__((address_space(1))) void*)g,
      (__attribute__((address_space(3))) void*)l, 16, 0, 0);
}

__device__ __forceinline__ fx4 mfma16(bfx8 a, bfx8 b, fx4 c) {
  return __builtin_amdgcn_mfma_f32_16x16x32_bf16(a, b, c, 0, 0, 0);
}

// ---------------------------------------------------------------------------
// 256x128 GEMM (R12 structure, best measured). BK=32, 48KB LDS dbuf,
// 8 waves as 4Mx2N (64x64/wave, acc 4x4). Swizzle slot^=(row>>1)&3.
// blockIdx.z = split-K (unused now, kept). flags: 1=bias,4=gelu,8=out bf16.
// ---------------------------------------------------------------------------
__global__ __launch_bounds__(512, 4) void gemm256n(
    const bh_t* __restrict__ A, const bh_t* __restrict__ B,
    const float* __restrict__ bias, void* __restrict__ outp,
    int M, int N, int K, int lda, int flags)
{
  __shared__ bh_t A0[256][32], B0s[128][32];
  __shared__ bh_t A1[256][32], B1s[128][32];
  const int tid = threadIdx.x;
  const int wid = tid >> 6, lane = tid & 63;
  const int g = lane >> 4, r16 = lane & 15;
  const int wr = wid >> 1, wc = wid & 1;        // 4M x 2N waves
  const int m0 = blockIdx.x * 256, n0 = blockIdx.y * 128;
  const int swk = (g ^ ((r16 >> 1) & 3)) * 8;

  const bh_t* Ab = A + (size_t)blockIdx.z * K + (size_t)m0 * lda;
  const bh_t* Bb = B + (size_t)blockIdx.z * K + (size_t)n0 * lda;
  const int nt = K >> 5;

  fx4 acc[4][4] = {};

  auto stage = [&](bh_t* dA, bh_t* dB, int t) {
    const int k0 = t << 5;
    #pragma unroll
    for (int j = 0; j < 2; ++j) {
      const int idx = j * 512 + tid;
      const int row = idx >> 2;
      const int slot = (idx & 3) ^ ((row >> 1) & 3);
      gload_lds16(Ab + (size_t)row * lda + k0 + slot * 8, dA + (size_t)idx * 8);
    }
    {
      const int idx = tid;
      const int row = idx >> 2;
      const int slot = (idx & 3) ^ ((row >> 1) & 3);
      gload_lds16(Bb + (size_t)row * lda + k0 + slot * 8, dB + (size_t)idx * 8);
    }
  };

#define N_TILE(CA, CB, NA, NB, T)                                             \
  {                                                                           \
    if ((T) + 1 < nt) stage(&NA[0][0], &NB[0][0], (T) + 1);                   \
    bfx8 av[4], bv[4];                                                        \
    _Pragma("unroll")                                                         \
    for (int ni = 0; ni < 4; ++ni)                                            \
      bv[ni] = *(const bfx8*)(&CB[wc * 64 + ni * 16 + r16][0] + swk);         \
    _Pragma("unroll")                                                         \
    for (int mi = 0; mi < 4; ++mi)                                            \
      av[mi] = *(const bfx8*)(&CA[wr * 64 + mi * 16 + r16][0] + swk);         \
    asm volatile("s_waitcnt lgkmcnt(0)" ::: "memory");                        \
    __builtin_amdgcn_s_setprio(1);                                            \
    _Pragma("unroll")                                                         \
    for (int mi = 0; mi < 4; ++mi)                                            \
      _Pragma("unroll")                                                       \
      for (int ni = 0; ni < 4; ++ni)                                          \
        acc[mi][ni] = mfma16(av[mi], bv[ni], acc[mi][ni]);                    \
    __builtin_amdgcn_s_setprio(0);                                            \
    asm volatile("s_waitcnt vmcnt(0)" ::: "memory");                          \
    __builtin_amdgcn_s_barrier();                                             \
    asm volatile("" ::: "memory");                                            \
  }

  stage(&A0[0][0], &B0s[0][0], 0);
  asm volatile("s_waitcnt vmcnt(0)" ::: "memory");
  __builtin_amdgcn_s_barrier();
  asm volatile("" ::: "memory");

  for (int t = 0; t < nt; t += 2) {
    N_TILE(A0, B0s, A1, B1s, t);
    N_TILE(A1, B1s, A0, B0s, t + 1);
  }
#undef N_TILE

  const bool hasBias = flags & 1, doGelu = flags & 4, outBf = flags & 8;
  float* outF = (float*)outp + (size_t)blockIdx.z * ((size_t)M * N);
  bh_t*  outB = (bh_t*)outp;
  #pragma unroll
  for (int mi = 0; mi < 4; ++mi) {
    const int rowb = m0 + wr * 64 + mi * 16 + 4 * g;
    #pragma unroll
    for (int ni = 0; ni < 4; ++ni) {
      const int col = n0 + wc * 64 + ni * 16 + r16;
      if (col >= N) continue;
      const float bv = hasBias ? bias[col] : 0.0f;
      #pragma unroll
      for (int rr = 0; rr < 4; ++rr) {
        const size_t idx = (size_t)(rowb + rr) * N + col;
        float v = acc[mi][ni][rr] + bv;
        if (doGelu) v = 0.5f * v * (1.0f + erff(v * 0.70710678118654752f));
        if (outBf) outB[idx] = (bh_t)v; else outF[idx] = v;
      }
    }
  }
}

// ---------------------------------------------------------------------------
// 128x64 GEMM, BK=32, 24KB LDS dbuf, 4 blocks/CU. 4 waves (2Mx2N, 64x32/wave,
// acc 4x2). Same swizzle/schedule family as gemm256n. No split-K.
// flags: 1=bias, 2=residual(f32 in outp layout), 8=out bf16 (else f32).
// Used for proj (K=768) and fc2 (K=3072): bias+residual fused -> writes x.
// ---------------------------------------------------------------------------
__global__ __launch_bounds__(256, 4) void gemm_n64(
    const bh_t* __restrict__ A, const bh_t* __restrict__ B,
    const float* __restrict__ bias, const float* __restrict__ resid,
    void* __restrict__ outp, int M, int N, int K, int lda, int flags)
{
  __shared__ bh_t A0[128][32], B0s[64][32];
  __shared__ bh_t A1[128][32], B1s[64][32];
  const int tid = threadIdx.x;
  const int wid = tid >> 6, lane = tid & 63;
  const int g = lane >> 4, r16 = lane & 15;
  const int wr = wid >> 1, wc = wid & 1;        // 2M x 2N waves
  const int m0 = blockIdx.x * 128, n0 = blockIdx.y * 64;
  const int swk = (g ^ ((r16 >> 1) & 3)) * 8;

  const bh_t* Ab = A + (size_t)m0 * lda;
  const bh_t* Bb = B + (size_t)n0 * lda;
  const int nt = K >> 5;

  fx4 acc[4][2] = {};

  // stage: A 128x32 (2 loads/thread) + B 64x32 (1 load/thread), pre-swizzled src
  auto stage = [&](bh_t* dA, bh_t* dB, int t) {
    const int k0 = t << 5;
    #pragma unroll
    for (int j = 0; j < 2; ++j) {
      const int idx = j * 256 + tid;          // 0..511
      const int row = idx >> 2;               // 0..127
      const int slot = (idx & 3) ^ ((row >> 1) & 3);
      gload_lds16(Ab + (size_t)row * lda + k0 + slot * 8, dA + (size_t)idx * 8);
    }
    {
      const int idx = tid;                    // 0..255
      const int row = idx >> 2;               // 0..63
      const int slot = (idx & 3) ^ ((row >> 1) & 3);
      gload_lds16(Bb + (size_t)row * lda + k0 + slot * 8, dB + (size_t)idx * 8);
    }
  };

#define N64_TILE(CA, CB, NA, NB, T)                                           \
  {                                                                           \
    if ((T) + 1 < nt) stage(&NA[0][0], &NB[0][0], (T) + 1);                   \
    bfx8 av[4], bv[2];                                                        \
    _Pragma("unroll")                                                         \
    for (int ni = 0; ni < 2; ++ni)                                            \
      bv[ni] = *(const bfx8*)(&CB[wc * 32 + ni * 16 + r16][0] + swk);         \
    _Pragma("unroll")                                                         \
    for (int mi = 0; mi < 4; ++mi)                                            \
      av[mi] = *(const bfx8*)(&CA[wr * 64 + mi * 16 + r16][0] + swk);         \
    asm volatile("s_waitcnt lgkmcnt(0)" ::: "memory");                        \
    __builtin_amdgcn_s_setprio(1);                                            \
    _Pragma("unroll")                                                         \
    for (int mi = 0; mi < 4; ++mi)                                            \
      _Pragma("unroll")                                                       \
      for (int ni = 0; ni < 2; ++ni)                                          \
        acc[mi][ni] = mfma16(av[mi], bv[ni], acc[mi][ni]);                    \
    __builtin_amdgcn_s_setprio(0);                                            \
    asm volatile("s_waitcnt vmcnt(0)" ::: "memory");                          \
    __builtin_amdgcn_s_barrier();                                             \
    asm volatile("" ::: "memory");                                            \
  }

  stage(&A0[0][0], &B0s[0][0], 0);
  asm volatile("s_waitcnt vmcnt(0)" ::: "memory");
  __builtin_amdgcn_s_barrier();
  asm volatile("" ::: "memory");

  for (int t = 0; t < nt; t += 2) {
    N64_TILE(A0, B0s, A1, B1s, t);
    N64_TILE(A1, B1s, A0, B0s, t + 1);
  }
#undef N64_TILE

  const bool hasBias = flags & 1, hasRes = flags & 2, outBf = flags & 8;
  float* outF = (float*)outp;
  bh_t*  outB = (bh_t*)outp;
  #pragma unroll
  for (int mi = 0; mi < 4; ++mi) {
    const int rowb = m0 + wr * 64 + mi * 16 + 4 * g;
    #pragma unroll
    for (int ni = 0; ni < 2; ++ni) {
      const int col = n0 + wc * 32 + ni * 16 + r16;
      if (col >= N) continue;
      const float bv = hasBias ? bias[col] : 0.0f;
      #pragma unroll
      for (int rr = 0; rr < 4; ++rr) {
        const size_t idx = (size_t)(rowb + rr) * N + col;
        float v = acc[mi][ni][rr] + bv;
        if (hasRes) v += resid[idx];
        if (outBf) outB[idx] = (bh_t)v; else outF[idx] = v;
      }
    }
  }
}

// ---------------------------------------------------------------------------
// LayerNorm: f32 in -> bf16 out. One wave per row.
// ---------------------------------------------------------------------------
__global__ __launch_bounds__(256) void ln_fwd(
    const float* __restrict__ x, const float* __restrict__ w,
    const float* __restrict__ bb, bh_t* __restrict__ out)
{
  const int wave = threadIdx.x >> 6, lane = threadIdx.x & 63;
  const int row = blockIdx.x * 4 + wave;
  const float* xr = x + (size_t)row * CDIM;
  const int off = lane * 4;
  const float4 v0 = *(const float4*)(xr + off);
  const float4 v1 = *(const float4*)(xr + 256 + off);
  const float4 v2 = *(const float4*)(xr + 512 + off);
  float s  = v0.x + v0.y + v0.z + v0.w + v1.x + v1.y + v1.z + v1.w
           + v2.x + v2.y + v2.z + v2.w;
  float ss = v0.x*v0.x + v0.y*v0.y + v0.z*v0.z + v0.w*v0.w
           + v1.x*v1.x + v1.y*v1.y + v1.z*v1.z + v1.w*v1.w
           + v2.x*v2.x + v2.y*v2.y + v2.z*v2.z + v2.w*v2.w;
  #pragma unroll
  for (int d = 1; d < 64; d <<= 1) { s += __shfl_xor(s, d); ss += __shfl_xor(ss, d); }
  const float mean = s * (1.0f / 768.0f);
  const float inv = rsqrtf(ss * (1.0f / 768.0f) - mean * mean + 1e-5f);
  bh_t* orow = out + (size_t)row * CDIM;

  const float4 w0 = *(const float4*)(w + off),  b0 = *(const float4*)(bb + off);
  const float4 w1 = *(const float4*)(w + 256 + off), b1 = *(const float4*)(bb + 256 + off);
  const float4 w2 = *(const float4*)(w + 512 + off), b2 = *(const float4*)(bb + 512 + off);
  bfx4 o;
  o[0] = (bh_t)((v0.x - mean) * inv * w0.x + b0.x);
  o[1] = (bh_t)((v0.y - mean) * inv * w0.y + b0.y);
  o[2] = (bh_t)((v0.z - mean) * inv * w0.z + b0.z);
  o[3] = (bh_t)((v0.w - mean) * inv * w0.w + b0.w);
  *(bfx4*)(orow + off) = o;
  o[0] = (bh_t)((v1.x - mean) * inv * w1.x + b1.x);
  o[1] = (bh_t)((v1.y - mean) * inv * w1.y + b1.y);
  o[2] = (bh_t)((v1.z - mean) * inv * w1.z + b1.z);
  o[3] = (bh_t)((v1.w - mean) * inv * w1.w + b1.w);
  *(bfx4*)(orow + 256 + off) = o;
  o[0] = (bh_t)((v2.x - mean) * inv * w2.x + b2.x);
  o[1] = (bh_t)((v2.y - mean) * inv * w2.y + b2.y);
  o[2] = (bh_t)((v2.z - mean) * inv * w2.z + b2.z);
  o[3] = (bh_t)((v2.w - mean) * inv * w2.w + b2.w);
  *(bfx4*)(orow + 512 + off) = o;
}

// ---------------------------------------------------------------------------
// Flash attention, causal. One wave per (b, h, 16 q-rows).
// ---------------------------------------------------------------------------
__global__ __launch_bounds__(256) void attn_fwd(
    const bh_t* __restrict__ qkv, const bh_t* __restrict__ vT,
    bh_t* __restrict__ outb)
{
  __shared__ bh_t P[4][16][56];
  const int wave = threadIdx.x >> 6, lane = threadIdx.x & 63;
  const int g = lane >> 4, r16 = lane & 15;
  const int gw = blockIdx.x * 4 + wave;
  const int qblk = gw & 63;
  const int bh = gw >> 6;
  const int h = bh % NHEAD, b = bh / NHEAD;
  const int qbase = qblk * 16;
  const int qidx = qbase + r16;

  const bh_t* qp = qkv + (size_t)(b * TSEQ + qbase + r16) * (3 * CDIM) + h * HDIM + 8 * g;
  const bfx8 qf0 = *(const bfx8*)qp;
  const bfx8 qf1 = *(const bfx8*)(qp + 32);

  fx4 o[4] = {};
  float m = -INFINITY, l = 0.0f;
  const int ntiles = qblk / 2 + 1;

  for (int t = 0; t < ntiles; ++t) {
    const int kv0 = t * 32;
    const bh_t* kp = qkv + (size_t)(b * TSEQ + kv0 + r16) * (3 * CDIM) + CDIM + h * HDIM + 8 * g;
    const bfx8 ka0 = *(const bfx8*)kp;
    const bfx8 ka1 = *(const bfx8*)(kp + 32);
    const bfx8 kb0 = *(const bfx8*)(kp + 16 * (3 * CDIM));
    const bfx8 kb1 = *(const bfx8*)(kp + 16 * (3 * CDIM) + 32);
    fx4 s0 = {}, s1 = {};
    s0 = mfma16(ka0, qf0, s0); s0 = mfma16(ka1, qf1, s0);   // S^T: [kv][q]
    s1 = mfma16(kb0, qf0, s1); s1 = mfma16(kb1, qf1, s1);

    float mx = -INFINITY;
    float sv0[4], sv1[4];
    #pragma unroll
    for (int rr = 0; rr < 4; ++rr) {
      const int kva = kv0 + 4 * g + rr;
      const int kvb = kva + 16;
      sv0[rr] = (kva <= qidx) ? s0[rr] * 0.125f : -INFINITY;
      sv1[rr] = (kvb <= qidx) ? s1[rr] * 0.125f : -INFINITY;
      mx = fmaxf(mx, fmaxf(sv0[rr], sv1[rr]));
    }
    mx = fmaxf(mx, __shfl_xor(mx, 16));
    mx = fmaxf(mx, __shfl_xor(mx, 32));
    const float mnew = fmaxf(m, mx);
    const float corr = __expf(m - mnew);

    float ps = 0.0f;
    float pv0[4], pv1[4];
    #pragma unroll
    for (int rr = 0; rr < 4; ++rr) {
      pv0[rr] = __expf(sv0[rr] - mnew);
      pv1[rr] = __expf(sv1[rr] - mnew);
      ps += pv0[rr] + pv1[rr];
    }
    ps += __shfl_xor(ps, 16);
    ps += __shfl_xor(ps, 32);
    l = l * corr + ps;
    m = mnew;

    #pragma unroll
    for (int rr = 0; rr < 4; ++rr) {
      const float cr = __shfl(corr, 4 * g + rr);
      o[0][rr] *= cr; o[1][rr] *= cr; o[2][rr] *= cr; o[3][rr] *= cr;
    }

    bfx4 w0, w1;
    #pragma unroll
    for (int rr = 0; rr < 4; ++rr) { w0[rr] = (bh_t)pv0[rr]; w1[rr] = (bh_t)pv1[rr]; }
    *(bfx4*)&P[wave][r16][4 * g]      = w0;
    *(bfx4*)&P[wave][r16][16 + 4 * g] = w1;
    __builtin_amdgcn_wave_barrier();
    const bfx8 pf = *(const bfx8*)&P[wave][r16][8 * g];

    #pragma unroll
    for (int fi = 0; fi < 4; ++fi) {
      const bh_t* vp = vT + (size_t)(bh * HDIM + fi * 16 + r16) * TSEQ + kv0 + 8 * g;
      const bfx8 vf = *(const bfx8*)vp;
      o[fi] = mfma16(pf, vf, o[fi]);
    }
  }

  #pragma unroll
  for (int rr = 0; rr < 4; ++rr) {
    const float lr = __shfl(l, 4 * g + rr);
    const float inv = 1.0f / lr;
    const int trow = b * TSEQ + qbase + 4 * g + rr;
    #pragma unroll
    for (int fi = 0; fi < 4; ++fi)
      outb[(size_t)trow * CDIM + h * HDIM + fi * 16 + r16] = (bh_t)(o[fi][rr] * inv);
  }
}

// ---------------------------------------------------------------------------
__global__ void embed_k(const int* __restrict__ ids, const float* __restrict__ tok,
                        const float* __restrict__ pos, float* __restrict__ x)
{
  const int bt = blockIdx.x;
  const int t = bt & (TSEQ - 1);
  const int id = ids[bt];
  const float* tr = tok + (size_t)id * CDIM;
  const float* pr = pos + (size_t)t * CDIM;
  float* xr = x + (size_t)bt * CDIM;
  for (int j = threadIdx.x; j < CDIM; j += 256) xr[j] = tr[j] + pr[j];
}

// transpose + f32->bf16: in [L][R][Cn] -> out [L][Cn][R]
__global__ void tconv(const float* __restrict__ in, bh_t* __restrict__ out, int R, int Cn)
{
  __shared__ float tile[32][33];
  const size_t msz = (size_t)R * Cn;
  in  += msz * blockIdx.z;
  out += msz * blockIdx.z;
  const int tx = threadIdx.x & 31, ty = threadIdx.x >> 5;
  const int c0 = blockIdx.x * 32, r0 = blockIdx.y * 32;
  #pragma unroll
  for (int i = 0; i < 32; i += 8)
    tile[ty + i][tx] = in[(size_t)(r0 + ty + i) * Cn + c0 + tx];
  __syncthreads();
  #pragma unroll
  for (int i = 0; i < 32; i += 8)
    out[(size_t)(c0 + ty + i) * R + r0 + tx] = (bh_t)tile[tx][ty + i];
}

// tok_emb f32 [V][C] -> bf16 [VPAD][C], zero-padded rows
__global__ void embconv(const float* __restrict__ in, bh_t* __restrict__ out)
{
  const size_t i4 = ((size_t)blockIdx.x * 256 + threadIdx.x) * 4;
  if (i4 >= (size_t)VPAD * CDIM) return;
  const size_t vlim = (size_t)VOCAB * CDIM;
  float4 f = make_float4(0.f, 0.f, 0.f, 0.f);
  if (i4 < vlim) f = *(const float4*)(in + i4);
  bfx4 o;
  o[0] = (bh_t)f.x; o[1] = (bh_t)f.y; o[2] = (bh_t)f.z; o[3] = (bh_t)f.w;
  *(bfx4*)(out + i4) = o;
}

// V slice of qkv -> vT[bh*64 + d][t]
__global__ void vtrans(const bh_t* __restrict__ qkv, bh_t* __restrict__ vT)
{
  __shared__ bh_t tile[32][34];
  const int bh = blockIdx.z;
  const int b = bh / NHEAD, h = bh % NHEAD;
  const int d0 = blockIdx.x * 32, t0 = blockIdx.y * 32;
  const int tx = threadIdx.x & 31, ty = threadIdx.x >> 5;
  #pragma unroll
  for (int i = 0; i < 32; i += 8)
    tile[ty + i][tx] = qkv[(size_t)(b * TSEQ + t0 + ty + i) * (3 * CDIM) + 2 * CDIM + h * HDIM + d0 + tx];
  __syncthreads();
  #pragma unroll
  for (int i = 0; i < 32; i += 8)
    vT[(size_t)(bh * HDIM + d0 + ty + i) * TSEQ + t0 + tx] = tile[tx][ty + i];
}

// ---------------------------------------------------------------------------
extern "C" void kernel_launch(void* const* d_in, const int* in_sizes, int n_in,
                              void* d_out, int out_size, void* d_ws, size_t ws_size,
                              hipStream_t stream)
{
  (void)in_sizes; (void)n_in; (void)out_size; (void)ws_size;
  const int*   ids    = (const int*)d_in[0];
  const float* tok    = (const float*)d_in[1];
  const float* pos    = (const float*)d_in[2];
  const float* qkv_w  = (const float*)d_in[3];
  const float* qkv_b  = (const float*)d_in[4];
  const float* proj_w = (const float*)d_in[5];
  const float* proj_b = (const float*)d_in[6];
  const float* ln1_w  = (const float*)d_in[7];
  const float* ln1_b  = (const float*)d_in[8];
  const float* ln2_w  = (const float*)d_in[9];
  const float* ln2_b  = (const float*)d_in[10];
  const float* fc1_w  = (const float*)d_in[11];
  const float* fc1_b  = (const float*)d_in[12];
  const float* fc2_w  = (const float*)d_in[13];
  const float* fc2_b  = (const float*)d_in[14];
  const float* lnf_w  = (const float*)d_in[15];
  const float* lnf_b  = (const float*)d_in[16];

  // ---- scratch in ws (activations + embT), ~153 MB
  char* wp = (char*)d_ws;
  auto carve = [&](size_t bytes) { char* p = wp; wp += (bytes + 255) & ~(size_t)255; return p; };
  float* x     = (float*)carve((size_t)MROWS * CDIM * 4);
  bh_t*  hbuf  = (bh_t*)carve((size_t)MROWS * CDIM * 2);
  bh_t*  qkvb  = (bh_t*)carve((size_t)MROWS * 3 * CDIM * 2);
  bh_t*  vT    = (bh_t*)carve((size_t)48 * HDIM * TSEQ * 2);
  bh_t*  attno = (bh_t*)carve((size_t)MROWS * CDIM * 2);
  bh_t*  mlp1  = (bh_t*)carve((size_t)MROWS * 3072 * 2);
  bh_t*  embT  = (bh_t*)carve((size_t)VPAD * CDIM * 2);

  // ---- staged in d_out (dead before lm_head overwrites it), ~220 MB of 823
  char* op = (char*)d_out;
  auto carveO = [&](size_t bytes) { char* p = op; op += (bytes + 255) & ~(size_t)255; return p; };
  bh_t* qkvwT  = (bh_t*)carveO((size_t)NLAYER * 3 * CDIM * CDIM * 2);
  bh_t* projwT = (bh_t*)carveO((size_t)NLAYER * CDIM * CDIM * 2);
  bh_t* fc1wT  = (bh_t*)carveO((size_t)NLAYER * 3072 * CDIM * 2);
  bh_t* fc2wT  = (bh_t*)carveO((size_t)NLAYER * CDIM * 3072 * 2);

  tconv<<<dim3(2304 / 32, 768 / 32, NLAYER), 256, 0, stream>>>(qkv_w, qkvwT, 768, 2304);
  tconv<<<dim3(768 / 32, 768 / 32, NLAYER), 256, 0, stream>>>(proj_w, projwT, 768, 768);
  tconv<<<dim3(3072 / 32, 768 / 32, NLAYER), 256, 0, stream>>>(fc1_w, fc1wT, 768, 3072);
  tconv<<<dim3(768 / 32, 3072 / 32, NLAYER), 256, 0, stream>>>(fc2_w, fc2wT, 3072, 768);
  embconv<<<((VPAD * CDIM / 4) + 255) / 256, 256, 0, stream>>>(tok, embT);
  embed_k<<<MROWS, 256, 0, stream>>>(ids, tok, pos, x);

  ln_fwd<<<MROWS / 4, 256, 0, stream>>>(x, ln1_w, ln1_b, hbuf);
  for (int l = 0; l < NLAYER; ++l) {
    // qkv: grid 16x18 = 288 blocks
    gemm256n<<<dim3(16, 18), 512, 0, stream>>>(hbuf, qkvwT + (size_t)l * 3 * CDIM * CDIM,
        qkv_b + l * 3 * CDIM, qkvb, MROWS, 3 * CDIM, CDIM, CDIM, 1 | 8);
    vtrans<<<dim3(2, 32, 48), 256, 0, stream>>>(qkvb, vT);
    attn_fwd<<<768, 256, 0, stream>>>(qkvb, vT, attno);
    // proj: no split-K, 128x64 tile, grid 32x12 = 384 blocks; +bias +residual -> x (f32)
    gemm_n64<<<dim3(32, 12), 256, 0, stream>>>(attno,
        projwT + (size_t)l * CDIM * CDIM, proj_b + l * CDIM, x, x,
        MROWS, CDIM, CDIM, CDIM, 1 | 2);
    ln_fwd<<<MROWS / 4, 256, 0, stream>>>(x, ln2_w + l * CDIM, ln2_b + l * CDIM, hbuf);
    // fc1: grid 16x24 = 384 blocks
    gemm256n<<<dim3(16, 24), 512, 0, stream>>>(hbuf, fc1wT + (size_t)l * 3072 * CDIM,
        fc1_b + l * 3072, mlp1, MROWS, 3072, CDIM, CDIM, 1 | 4 | 8);
    // fc2: no split-K, K=3072 (nt=96), grid 32x12; +bias +residual -> x
    gemm_n64<<<dim3(32, 12), 256, 0, stream>>>(mlp1,
        fc2wT + (size_t)l * CDIM * 3072, fc2_b + l * CDIM, x, x,
        MROWS, CDIM, 3072, 3072, 1 | 2);
    const float* nw = (l + 1 < NLAYER) ? ln1_w + (l + 1) * CDIM : lnf_w;
    const float* nb = (l + 1 < NLAYER) ? ln1_b + (l + 1) * CDIM : lnf_b;
    ln_fwd<<<MROWS / 4, 256, 0, stream>>>(x, nw, nb, hbuf);
  }
  // lm_head: grid 16x393 (393*128 = 50304 covers VOCAB)
  gemm256n<<<dim3(16, 393), 512, 0, stream>>>(hbuf, embT, nullptr,
      (float*)d_out, MROWS, VOCAB, CDIM, CDIM, 0);
}

// Round 15
// 3665.697 us; speedup vs baseline: 1.2394x; 1.0706x over previous
//
#include <hip/hip_runtime.h>
#include <hip/hip_bf16.h>

// GPT-2 small forward on gfx950. bf16 MFMA GEMMs (f32 accum), flash attention.
// R15: consolidate on R10 (best measured, 3683us): gemm256n (256x128, BK=32,
//      2-phase dbuf, 2 blocks/CU) for ALL GEMMs; split-K via grid-z + fused
//      skred_ln. Single change vs R10: proj split-K 4->2 (skred traffic
//      131->81MB, -8us/instance; GEMM block latency +2.7us; net ~-60us).
//      GEMM family is at the 2-phase structure ceiling (~25% MfmaUtil):
//      R11 falsified load-latency, R12 falsified LDS-BW, R13 falsified
//      occupancy, R6/R8 8-phase ports regressed.

typedef __bf16 bh_t;
typedef __bf16 bfx4 __attribute__((ext_vector_type(4)));
typedef __bf16 bfx8 __attribute__((ext_vector_type(8)));
typedef float  fx4  __attribute__((ext_vector_type(4)));

#define CDIM 768
#define TSEQ 1024
#define NHEAD 12
#define HDIM 64
#define NLAYER 12
#define MROWS 4096          // B*T
#define VOCAB 50257
#define VPAD  50432

__device__ __forceinline__ void gload_lds16(const void* g, void* l) {
  __builtin_amdgcn_global_load_lds(
      (const __attribute__((address_space(1))) void*)g,
      (__attribute__((address_space(3))) void*)l, 16, 0, 0);
}

__device__ __forceinline__ fx4 mfma16(bfx8 a, bfx8 b, fx4 c) {
  return __builtin_amdgcn_mfma_f32_16x16x32_bf16(a, b, c, 0, 0, 0);
}

// ---------------------------------------------------------------------------
// 256x128 GEMM, BK=32, 48KB LDS double-buffer, 2 blocks/CU. 8 waves (2Mx4N),
// wave tile 128x32, acc 8x2. Swizzle slot ^= (row>>1)&3 (2 lanes/bank = free).
// blockIdx.z = split-K slice (A,B advance z*K; f32 partial at z*M*N).
// flags: 1=bias, 4=gelu, 8=out bf16. K % 64 == 0. N ragged OK (col guard).
// ---------------------------------------------------------------------------
__global__ __launch_bounds__(512, 4) void gemm256n(
    const bh_t* __restrict__ A, const bh_t* __restrict__ B,
    const float* __restrict__ bias, void* __restrict__ outp,
    int M, int N, int K, int lda, int flags)
{
  __shared__ bh_t A0[256][32], B0s[128][32];
  __shared__ bh_t A1[256][32], B1s[128][32];
  const int tid = threadIdx.x;
  const int wid = tid >> 6, lane = tid & 63;
  const int g = lane >> 4, r16 = lane & 15;
  const int wr = wid >> 2, wc = wid & 3;
  const int m0 = blockIdx.x * 256, n0 = blockIdx.y * 128;
  const int swk = (g ^ ((r16 >> 1) & 3)) * 8;   // swizzled slot offset (elems)

  const bh_t* Ab = A + (size_t)blockIdx.z * K + (size_t)m0 * lda;
  const bh_t* Bb = B + (size_t)blockIdx.z * K + (size_t)n0 * lda;
  const int nt = K >> 5;

  fx4 acc[8][2] = {};

  // stage tile t: A 256x32 (2 loads/thread) + B 128x32 (1 load/thread);
  // source pre-swizzled with slot ^= (row>>1)&3, dst linear (both-sides rule).
  auto stage = [&](bh_t* dA, bh_t* dB, int t) {
    const int k0 = t << 5;
    #pragma unroll
    for (int j = 0; j < 2; ++j) {
      const int idx = j * 512 + tid;          // 16B units, 0..1023
      const int row = idx >> 2;
      const int slot = (idx & 3) ^ ((row >> 1) & 3);
      gload_lds16(Ab + (size_t)row * lda + k0 + slot * 8, dA + (size_t)idx * 8);
    }
    {
      const int idx = tid;                    // 0..511
      const int row = idx >> 2;
      const int slot = (idx & 3) ^ ((row >> 1) & 3);
      gload_lds16(Bb + (size_t)row * lda + k0 + slot * 8, dB + (size_t)idx * 8);
    }
  };

#define N_TILE(CA, CB, NA, NB, T)                                             \
  {                                                                           \
    if ((T) + 1 < nt) stage(&NA[0][0], &NB[0][0], (T) + 1);                   \
    bfx8 av[8], bv[2];                                                        \
    _Pragma("unroll")                                                         \
    for (int ni = 0; ni < 2; ++ni)                                            \
      bv[ni] = *(const bfx8*)(&CB[wc * 32 + ni * 16 + r16][0] + swk);         \
    _Pragma("unroll")                                                         \
    for (int mi = 0; mi < 8; ++mi)                                            \
      av[mi] = *(const bfx8*)(&CA[wr * 128 + mi * 16 + r16][0] + swk);        \
    asm volatile("s_waitcnt lgkmcnt(0)" ::: "memory");                        \
    __builtin_amdgcn_s_setprio(1);                                            \
    _Pragma("unroll")                                                         \
    for (int mi = 0; mi < 8; ++mi)                                            \
      _Pragma("unroll")                                                       \
      for (int ni = 0; ni < 2; ++ni)                                          \
        acc[mi][ni] = mfma16(av[mi], bv[ni], acc[mi][ni]);                    \
    __builtin_amdgcn_s_setprio(0);                                            \
    asm volatile("s_waitcnt vmcnt(0)" ::: "memory");                          \
    __builtin_amdgcn_s_barrier();                                             \
    asm volatile("" ::: "memory");                                            \
  }

  stage(&A0[0][0], &B0s[0][0], 0);
  asm volatile("s_waitcnt vmcnt(0)" ::: "memory");
  __builtin_amdgcn_s_barrier();
  asm volatile("" ::: "memory");

  for (int t = 0; t < nt; t += 2) {
    N_TILE(A0, B0s, A1, B1s, t);
    N_TILE(A1, B1s, A0, B0s, t + 1);
  }
#undef N_TILE

  const bool hasBias = flags & 1, doGelu = flags & 4, outBf = flags & 8;
  float* outF = (float*)outp + (size_t)blockIdx.z * ((size_t)M * N);
  bh_t*  outB = (bh_t*)outp;
  #pragma unroll
  for (int mi = 0; mi < 8; ++mi) {
    const int rowb = m0 + wr * 128 + mi * 16 + 4 * g;
    #pragma unroll
    for (int ni = 0; ni < 2; ++ni) {
      const int col = n0 + wc * 32 + ni * 16 + r16;
      if (col >= N) continue;
      const float bv = hasBias ? bias[col] : 0.0f;
      #pragma unroll
      for (int rr = 0; rr < 4; ++rr) {
        const size_t idx = (size_t)(rowb + rr) * N + col;
        float v = acc[mi][ni][rr] + bv;
        if (doGelu) v = 0.5f * v * (1.0f + erff(v * 0.70710678118654752f));
        if (outBf) outB[idx] = (bh_t)v; else outF[idx] = v;
      }
    }
  }
}

// ---------------------------------------------------------------------------
// fused split-K reduce + residual + LayerNorm
// ---------------------------------------------------------------------------
__global__ __launch_bounds__(256) void skred_ln(
    const float* __restrict__ part, const float* __restrict__ bias,
    float* __restrict__ x, const float* __restrict__ w,
    const float* __restrict__ bb, bh_t* __restrict__ out, int S)
{
  const int wave = threadIdx.x >> 6, lane = threadIdx.x & 63;
  const int row = blockIdx.x * 4 + wave;
  const size_t base = (size_t)row * CDIM;
  const int off = lane * 4;
  const size_t stride = (size_t)MROWS * CDIM;

  float4 v0 = *(const float4*)(x + base + off);
  float4 v1 = *(const float4*)(x + base + 256 + off);
  float4 v2 = *(const float4*)(x + base + 512 + off);
  for (int s = 0; s < S; ++s) {
    const float* pr = part + s * stride + base;
    const float4 p0 = *(const float4*)(pr + off);
    const float4 p1 = *(const float4*)(pr + 256 + off);
    const float4 p2 = *(const float4*)(pr + 512 + off);
    v0.x += p0.x; v0.y += p0.y; v0.z += p0.z; v0.w += p0.w;
    v1.x += p1.x; v1.y += p1.y; v1.z += p1.z; v1.w += p1.w;
    v2.x += p2.x; v2.y += p2.y; v2.z += p2.z; v2.w += p2.w;
  }
  const float4 q0 = *(const float4*)(bias + off);
  const float4 q1 = *(const float4*)(bias + 256 + off);
  const float4 q2 = *(const float4*)(bias + 512 + off);
  v0.x += q0.x; v0.y += q0.y; v0.z += q0.z; v0.w += q0.w;
  v1.x += q1.x; v1.y += q1.y; v1.z += q1.z; v1.w += q1.w;
  v2.x += q2.x; v2.y += q2.y; v2.z += q2.z; v2.w += q2.w;
  *(float4*)(x + base + off) = v0;
  *(float4*)(x + base + 256 + off) = v1;
  *(float4*)(x + base + 512 + off) = v2;

  float s1 = v0.x + v0.y + v0.z + v0.w + v1.x + v1.y + v1.z + v1.w
           + v2.x + v2.y + v2.z + v2.w;
  float ss = v0.x*v0.x + v0.y*v0.y + v0.z*v0.z + v0.w*v0.w
           + v1.x*v1.x + v1.y*v1.y + v1.z*v1.z + v1.w*v1.w
           + v2.x*v2.x + v2.y*v2.y + v2.z*v2.z + v2.w*v2.w;
  #pragma unroll
  for (int d = 1; d < 64; d <<= 1) { s1 += __shfl_xor(s1, d); ss += __shfl_xor(ss, d); }
  const float mean = s1 * (1.0f / 768.0f);
  const float inv = rsqrtf(ss * (1.0f / 768.0f) - mean * mean + 1e-5f);
  bh_t* orow = out + base;

  const float4 w0 = *(const float4*)(w + off),       b0 = *(const float4*)(bb + off);
  const float4 w1 = *(const float4*)(w + 256 + off), b1 = *(const float4*)(bb + 256 + off);
  const float4 w2 = *(const float4*)(w + 512 + off), b2 = *(const float4*)(bb + 512 + off);
  bfx4 o;
  o[0] = (bh_t)((v0.x - mean) * inv * w0.x + b0.x);
  o[1] = (bh_t)((v0.y - mean) * inv * w0.y + b0.y);
  o[2] = (bh_t)((v0.z - mean) * inv * w0.z + b0.z);
  o[3] = (bh_t)((v0.w - mean) * inv * w0.w + b0.w);
  *(bfx4*)(orow + off) = o;
  o[0] = (bh_t)((v1.x - mean) * inv * w1.x + b1.x);
  o[1] = (bh_t)((v1.y - mean) * inv * w1.y + b1.y);
  o[2] = (bh_t)((v1.z - mean) * inv * w1.z + b1.z);
  o[3] = (bh_t)((v1.w - mean) * inv * w1.w + b1.w);
  *(bfx4*)(orow + 256 + off) = o;
  o[0] = (bh_t)((v2.x - mean) * inv * w2.x + b2.x);
  o[1] = (bh_t)((v2.y - mean) * inv * w2.y + b2.y);
  o[2] = (bh_t)((v2.z - mean) * inv * w2.z + b2.z);
  o[3] = (bh_t)((v2.w - mean) * inv * w2.w + b2.w);
  *(bfx4*)(orow + 512 + off) = o;
}

// ---------------------------------------------------------------------------
// Flash attention, causal. One wave per (b, h, 16 q-rows).
// ---------------------------------------------------------------------------
__global__ __launch_bounds__(256) void attn_fwd(
    const bh_t* __restrict__ qkv, const bh_t* __restrict__ vT,
    bh_t* __restrict__ outb)
{
  __shared__ bh_t P[4][16][56];
  const int wave = threadIdx.x >> 6, lane = threadIdx.x & 63;
  const int g = lane >> 4, r16 = lane & 15;
  const int gw = blockIdx.x * 4 + wave;
  const int qblk = gw & 63;
  const int bh = gw >> 6;
  const int h = bh % NHEAD, b = bh / NHEAD;
  const int qbase = qblk * 16;
  const int qidx = qbase + r16;

  const bh_t* qp = qkv + (size_t)(b * TSEQ + qbase + r16) * (3 * CDIM) + h * HDIM + 8 * g;
  const bfx8 qf0 = *(const bfx8*)qp;
  const bfx8 qf1 = *(const bfx8*)(qp + 32);

  fx4 o[4] = {};
  float m = -INFINITY, l = 0.0f;
  const int ntiles = qblk / 2 + 1;

  for (int t = 0; t < ntiles; ++t) {
    const int kv0 = t * 32;
    const bh_t* kp = qkv + (size_t)(b * TSEQ + kv0 + r16) * (3 * CDIM) + CDIM + h * HDIM + 8 * g;
    const bfx8 ka0 = *(const bfx8*)kp;
    const bfx8 ka1 = *(const bfx8*)(kp + 32);
    const bfx8 kb0 = *(const bfx8*)(kp + 16 * (3 * CDIM));
    const bfx8 kb1 = *(const bfx8*)(kp + 16 * (3 * CDIM) + 32);
    fx4 s0 = {}, s1 = {};
    s0 = mfma16(ka0, qf0, s0); s0 = mfma16(ka1, qf1, s0);   // S^T: [kv][q]
    s1 = mfma16(kb0, qf0, s1); s1 = mfma16(kb1, qf1, s1);

    float mx = -INFINITY;
    float sv0[4], sv1[4];
    #pragma unroll
    for (int rr = 0; rr < 4; ++rr) {
      const int kva = kv0 + 4 * g + rr;
      const int kvb = kva + 16;
      sv0[rr] = (kva <= qidx) ? s0[rr] * 0.125f : -INFINITY;
      sv1[rr] = (kvb <= qidx) ? s1[rr] * 0.125f : -INFINITY;
      mx = fmaxf(mx, fmaxf(sv0[rr], sv1[rr]));
    }
    mx = fmaxf(mx, __shfl_xor(mx, 16));
    mx = fmaxf(mx, __shfl_xor(mx, 32));
    const float mnew = fmaxf(m, mx);
    const float corr = __expf(m - mnew);

    float ps = 0.0f;
    float pv0[4], pv1[4];
    #pragma unroll
    for (int rr = 0; rr < 4; ++rr) {
      pv0[rr] = __expf(sv0[rr] - mnew);
      pv1[rr] = __expf(sv1[rr] - mnew);
      ps += pv0[rr] + pv1[rr];
    }
    ps += __shfl_xor(ps, 16);
    ps += __shfl_xor(ps, 32);
    l = l * corr + ps;
    m = mnew;

    #pragma unroll
    for (int rr = 0; rr < 4; ++rr) {
      const float cr = __shfl(corr, 4 * g + rr);
      o[0][rr] *= cr; o[1][rr] *= cr; o[2][rr] *= cr; o[3][rr] *= cr;
    }

    bfx4 w0, w1;
    #pragma unroll
    for (int rr = 0; rr < 4; ++rr) { w0[rr] = (bh_t)pv0[rr]; w1[rr] = (bh_t)pv1[rr]; }
    *(bfx4*)&P[wave][r16][4 * g]      = w0;
    *(bfx4*)&P[wave][r16][16 + 4 * g] = w1;
    __builtin_amdgcn_wave_barrier();
    const bfx8 pf = *(const bfx8*)&P[wave][r16][8 * g];

    #pragma unroll
    for (int fi = 0; fi < 4; ++fi) {
      const bh_t* vp = vT + (size_t)(bh * HDIM + fi * 16 + r16) * TSEQ + kv0 + 8 * g;
      const bfx8 vf = *(const bfx8*)vp;
      o[fi] = mfma16(pf, vf, o[fi]);
    }
  }

  #pragma unroll
  for (int rr = 0; rr < 4; ++rr) {
    const float lr = __shfl(l, 4 * g + rr);
    const float inv = 1.0f / lr;
    const int trow = b * TSEQ + qbase + 4 * g + rr;
    #pragma unroll
    for (int fi = 0; fi < 4; ++fi)
      outb[(size_t)trow * CDIM + h * HDIM + fi * 16 + r16] = (bh_t)(o[fi][rr] * inv);
  }
}

// ---------------------------------------------------------------------------
// LayerNorm: f32 in -> bf16 out. One wave per row. (layer 0 entry only)
// ---------------------------------------------------------------------------
__global__ __launch_bounds__(256) void ln_fwd(
    const float* __restrict__ x, const float* __restrict__ w,
    const float* __restrict__ bb, bh_t* __restrict__ out)
{
  const int wave = threadIdx.x >> 6, lane = threadIdx.x & 63;
  const int row = blockIdx.x * 4 + wave;
  const float* xr = x + (size_t)row * CDIM;
  const int off = lane * 4;
  const float4 v0 = *(const float4*)(xr + off);
  const float4 v1 = *(const float4*)(xr + 256 + off);
  const float4 v2 = *(const float4*)(xr + 512 + off);
  float s  = v0.x + v0.y + v0.z + v0.w + v1.x + v1.y + v1.z + v1.w
           + v2.x + v2.y + v2.z + v2.w;
  float ss = v0.x*v0.x + v0.y*v0.y + v0.z*v0.z + v0.w*v0.w
           + v1.x*v1.x + v1.y*v1.y + v1.z*v1.z + v1.w*v1.w
           + v2.x*v2.x + v2.y*v2.y + v2.z*v2.z + v2.w*v2.w;
  #pragma unroll
  for (int d = 1; d < 64; d <<= 1) { s += __shfl_xor(s, d); ss += __shfl_xor(ss, d); }
  const float mean = s * (1.0f / 768.0f);
  const float inv = rsqrtf(ss * (1.0f / 768.0f) - mean * mean + 1e-5f);
  bh_t* orow = out + (size_t)row * CDIM;

  const float4 w0 = *(const float4*)(w + off),  b0 = *(const float4*)(bb + off);
  const float4 w1 = *(const float4*)(w + 256 + off), b1 = *(const float4*)(bb + 256 + off);
  const float4 w2 = *(const float4*)(w + 512 + off), b2 = *(const float4*)(bb + 512 + off);
  bfx4 o;
  o[0] = (bh_t)((v0.x - mean) * inv * w0.x + b0.x);
  o[1] = (bh_t)((v0.y - mean) * inv * w0.y + b0.y);
  o[2] = (bh_t)((v0.z - mean) * inv * w0.z + b0.z);
  o[3] = (bh_t)((v0.w - mean) * inv * w0.w + b0.w);
  *(bfx4*)(orow + off) = o;
  o[0] = (bh_t)((v1.x - mean) * inv * w1.x + b1.x);
  o[1] = (bh_t)((v1.y - mean) * inv * w1.y + b1.y);
  o[2] = (bh_t)((v1.z - mean) * inv * w1.z + b1.z);
  o[3] = (bh_t)((v1.w - mean) * inv * w1.w + b1.w);
  *(bfx4*)(orow + 256 + off) = o;
  o[0] = (bh_t)((v2.x - mean) * inv * w2.x + b2.x);
  o[1] = (bh_t)((v2.y - mean) * inv * w2.y + b2.y);
  o[2] = (bh_t)((v2.z - mean) * inv * w2.z + b2.z);
  o[3] = (bh_t)((v2.w - mean) * inv * w2.w + b2.w);
  *(bfx4*)(orow + 512 + off) = o;
}

// ---------------------------------------------------------------------------
__global__ void embed_k(const int* __restrict__ ids, const float* __restrict__ tok,
                        const float* __restrict__ pos, float* __restrict__ x)
{
  const int bt = blockIdx.x;
  const int t = bt & (TSEQ - 1);
  const int id = ids[bt];
  const float* tr = tok + (size_t)id * CDIM;
  const float* pr = pos + (size_t)t * CDIM;
  float* xr = x + (size_t)bt * CDIM;
  for (int j = threadIdx.x; j < CDIM; j += 256) xr[j] = tr[j] + pr[j];
}

// transpose + f32->bf16: in [L][R][Cn] -> out [L][Cn][R]
__global__ void tconv(const float* __restrict__ in, bh_t* __restrict__ out, int R, int Cn)
{
  __shared__ float tile[32][33];
  const size_t msz = (size_t)R * Cn;
  in  += msz * blockIdx.z;
  out += msz * blockIdx.z;
  const int tx = threadIdx.x & 31, ty = threadIdx.x >> 5;
  const int c0 = blockIdx.x * 32, r0 = blockIdx.y * 32;
  #pragma unroll
  for (int i = 0; i < 32; i += 8)
    tile[ty + i][tx] = in[(size_t)(r0 + ty + i) * Cn + c0 + tx];
  __syncthreads();
  #pragma unroll
  for (int i = 0; i < 32; i += 8)
    out[(size_t)(c0 + ty + i) * R + r0 + tx] = (bh_t)tile[tx][ty + i];
}

// tok_emb f32 [V][C] -> bf16 [VPAD][C], zero-padded rows
__global__ void embconv(const float* __restrict__ in, bh_t* __restrict__ out)
{
  const size_t i4 = ((size_t)blockIdx.x * 256 + threadIdx.x) * 4;
  if (i4 >= (size_t)VPAD * CDIM) return;
  const size_t vlim = (size_t)VOCAB * CDIM;
  float4 f = make_float4(0.f, 0.f, 0.f, 0.f);
  if (i4 < vlim) f = *(const float4*)(in + i4);
  bfx4 o;
  o[0] = (bh_t)f.x; o[1] = (bh_t)f.y; o[2] = (bh_t)f.z; o[3] = (bh_t)f.w;
  *(bfx4*)(out + i4) = o;
}

// V slice of qkv -> vT[bh*64 + d][t]
__global__ void vtrans(const bh_t* __restrict__ qkv, bh_t* __restrict__ vT)
{
  __shared__ bh_t tile[32][34];
  const int bh = blockIdx.z;
  const int b = bh / NHEAD, h = bh % NHEAD;
  const int d0 = blockIdx.x * 32, t0 = blockIdx.y * 32;
  const int tx = threadIdx.x & 31, ty = threadIdx.x >> 5;
  #pragma unroll
  for (int i = 0; i < 32; i += 8)
    tile[ty + i][tx] = qkv[(size_t)(b * TSEQ + t0 + ty + i) * (3 * CDIM) + 2 * CDIM + h * HDIM + d0 + tx];
  __syncthreads();
  #pragma unroll
  for (int i = 0; i < 32; i += 8)
    vT[(size_t)(bh * HDIM + d0 + ty + i) * TSEQ + t0 + tx] = tile[tx][ty + i];
}

// ---------------------------------------------------------------------------
extern "C" void kernel_launch(void* const* d_in, const int* in_sizes, int n_in,
                              void* d_out, int out_size, void* d_ws, size_t ws_size,
                              hipStream_t stream)
{
  (void)in_sizes; (void)n_in; (void)out_size; (void)ws_size;
  const int*   ids    = (const int*)d_in[0];
  const float* tok    = (const float*)d_in[1];
  const float* pos    = (const float*)d_in[2];
  const float* qkv_w  = (const float*)d_in[3];
  const float* qkv_b  = (const float*)d_in[4];
  const float* proj_w = (const float*)d_in[5];
  const float* proj_b = (const float*)d_in[6];
  const float* ln1_w  = (const float*)d_in[7];
  const float* ln1_b  = (const float*)d_in[8];
  const float* ln2_w  = (const float*)d_in[9];
  const float* ln2_b  = (const float*)d_in[10];
  const float* fc1_w  = (const float*)d_in[11];
  const float* fc1_b  = (const float*)d_in[12];
  const float* fc2_w  = (const float*)d_in[13];
  const float* fc2_b  = (const float*)d_in[14];
  const float* lnf_w  = (const float*)d_in[15];
  const float* lnf_b  = (const float*)d_in[16];

  // ---- scratch in ws (activations + embT), ~153 MB
  char* wp = (char*)d_ws;
  auto carve = [&](size_t bytes) { char* p = wp; wp += (bytes + 255) & ~(size_t)255; return p; };
  float* x     = (float*)carve((size_t)MROWS * CDIM * 4);
  bh_t*  hbuf  = (bh_t*)carve((size_t)MROWS * CDIM * 2);
  bh_t*  qkvb  = (bh_t*)carve((size_t)MROWS * 3 * CDIM * 2);
  bh_t*  vT    = (bh_t*)carve((size_t)48 * HDIM * TSEQ * 2);
  bh_t*  attno = (bh_t*)carve((size_t)MROWS * CDIM * 2);
  bh_t*  mlp1  = (bh_t*)carve((size_t)MROWS * 3072 * 2);
  bh_t*  embT  = (bh_t*)carve((size_t)VPAD * CDIM * 2);

  // ---- staged in d_out (dead before lm_head overwrites it), ~270 MB of 823
  char* op = (char*)d_out;
  auto carveO = [&](size_t bytes) { char* p = op; op += (bytes + 255) & ~(size_t)255; return p; };
  bh_t* qkvwT  = (bh_t*)carveO((size_t)NLAYER * 3 * CDIM * CDIM * 2);
  bh_t* projwT = (bh_t*)carveO((size_t)NLAYER * CDIM * CDIM * 2);
  bh_t* fc1wT  = (bh_t*)carveO((size_t)NLAYER * 3072 * CDIM * 2);
  bh_t* fc2wT  = (bh_t*)carveO((size_t)NLAYER * CDIM * 3072 * 2);
  float* skpart = (float*)carveO((size_t)4 * MROWS * CDIM * 4);   // split-K partials

  tconv<<<dim3(2304 / 32, 768 / 32, NLAYER), 256, 0, stream>>>(qkv_w, qkvwT, 768, 2304);
  tconv<<<dim3(768 / 32, 768 / 32, NLAYER), 256, 0, stream>>>(proj_w, projwT, 768, 768);
  tconv<<<dim3(3072 / 32, 768 / 32, NLAYER), 256, 0, stream>>>(fc1_w, fc1wT, 768, 3072);
  tconv<<<dim3(768 / 32, 3072 / 32, NLAYER), 256, 0, stream>>>(fc2_w, fc2wT, 3072, 768);
  embconv<<<((VPAD * CDIM / 4) + 255) / 256, 256, 0, stream>>>(tok, embT);
  embed_k<<<MROWS, 256, 0, stream>>>(ids, tok, pos, x);

  ln_fwd<<<MROWS / 4, 256, 0, stream>>>(x, ln1_w, ln1_b, hbuf);
  for (int l = 0; l < NLAYER; ++l) {
    // qkv: grid 16x18 = 288 blocks
    gemm256n<<<dim3(16, 18), 512, 0, stream>>>(hbuf, qkvwT + (size_t)l * 3 * CDIM * CDIM,
        qkv_b + l * 3 * CDIM, qkvb, MROWS, 3 * CDIM, CDIM, CDIM, 1 | 8);
    vtrans<<<dim3(2, 32, 48), 256, 0, stream>>>(qkvb, vT);
    attn_fwd<<<768, 256, 0, stream>>>(qkvb, vT, attno);
    // proj: split-K x2 (K_eff=384, nt=12), grid 16x6x2 = 192 blocks
    gemm256n<<<dim3(16, 6, 2), 512, 0, stream>>>(attno,
        projwT + (size_t)l * CDIM * CDIM, nullptr, skpart, MROWS, CDIM, 384, CDIM, 0);
    skred_ln<<<MROWS / 4, 256, 0, stream>>>(skpart, proj_b + l * CDIM, x,
        ln2_w + l * CDIM, ln2_b + l * CDIM, hbuf, 2);
    // fc1: grid 16x24 = 384 blocks
    gemm256n<<<dim3(16, 24), 512, 0, stream>>>(hbuf, fc1wT + (size_t)l * 3072 * CDIM,
        fc1_b + l * 3072, mlp1, MROWS, 3072, CDIM, CDIM, 1 | 4 | 8);
    // fc2: split-K x4 (K_eff=768, nt=24), grid 16x6x4 = 384 blocks
    gemm256n<<<dim3(16, 6, 4), 512, 0, stream>>>(mlp1, fc2wT + (size_t)l * CDIM * 3072,
        nullptr, skpart, MROWS, CDIM, 768, 3072, 0);
    const float* nw = (l + 1 < NLAYER) ? ln1_w + (l + 1) * CDIM : lnf_w;
    const float* nb = (l + 1 < NLAYER) ? ln1_b + (l + 1) * CDIM : lnf_b;
    skred_ln<<<MROWS / 4, 256, 0, stream>>>(skpart, fc2_b + l * CDIM, x, nw, nb, hbuf, 4);
  }
  // lm_head: grid 16x393 = 6288 blocks (50304 = 393*128 covers VOCAB)
  gemm256n<<<dim3(16, 393), 512, 0, stream>>>(hbuf, embT, nullptr,
      (float*)d_out, MROWS, VOCAB, CDIM, CDIM, 0);
}

// Round 16
// 3611.108 us; speedup vs baseline: 1.2581x; 1.0151x over previous
//
#include <hip/hip_runtime.h>
#include <hip/hip_bf16.h>

// GPT-2 small forward on gfx950. bf16 MFMA GEMMs (f32 accum), flash attention.
// R16: fuse vtrans into the qkv GEMM epilogue (flag 16): V columns write
//      directly to vT[bh*64+d][t] (4 consecutive rows -> one bfx4 store);
//      qkvb V-cols skipped (only vT consumed). -12 dispatches, -~100us.
//      Rest identical to R15 (best: 3665us).

typedef __bf16 bh_t;
typedef __bf16 bfx4 __attribute__((ext_vector_type(4)));
typedef __bf16 bfx8 __attribute__((ext_vector_type(8)));
typedef float  fx4  __attribute__((ext_vector_type(4)));

#define CDIM 768
#define TSEQ 1024
#define NHEAD 12
#define HDIM 64
#define NLAYER 12
#define MROWS 4096          // B*T
#define VOCAB 50257
#define VPAD  50432

__device__ __forceinline__ void gload_lds16(const void* g, void* l) {
  __builtin_amdgcn_global_load_lds(
      (const __attribute__((address_space(1))) void*)g,
      (__attribute__((address_space(3))) void*)l, 16, 0, 0);
}

__device__ __forceinline__ fx4 mfma16(bfx8 a, bfx8 b, fx4 c) {
  return __builtin_amdgcn_mfma_f32_16x16x32_bf16(a, b, c, 0, 0, 0);
}

// ---------------------------------------------------------------------------
// 256x128 GEMM, BK=32, 48KB LDS double-buffer, 2 blocks/CU. 8 waves (2Mx4N),
// wave tile 128x32, acc 8x2. Swizzle slot ^= (row>>1)&3 (2 lanes/bank = free).
// blockIdx.z = split-K slice (A,B advance z*K; f32 partial at z*M*N).
// flags: 1=bias, 4=gelu, 8=out bf16, 16=V-cols (>=2C) go to vT transposed.
// ---------------------------------------------------------------------------
__global__ __launch_bounds__(512, 4) void gemm256n(
    const bh_t* __restrict__ A, const bh_t* __restrict__ B,
    const float* __restrict__ bias, void* __restrict__ outp,
    bh_t* __restrict__ vTp,
    int M, int N, int K, int lda, int flags)
{
  __shared__ bh_t A0[256][32], B0s[128][32];
  __shared__ bh_t A1[256][32], B1s[128][32];
  const int tid = threadIdx.x;
  const int wid = tid >> 6, lane = tid & 63;
  const int g = lane >> 4, r16 = lane & 15;
  const int wr = wid >> 2, wc = wid & 3;
  const int m0 = blockIdx.x * 256, n0 = blockIdx.y * 128;
  const int swk = (g ^ ((r16 >> 1) & 3)) * 8;   // swizzled slot offset (elems)

  const bh_t* Ab = A + (size_t)blockIdx.z * K + (size_t)m0 * lda;
  const bh_t* Bb = B + (size_t)blockIdx.z * K + (size_t)n0 * lda;
  const int nt = K >> 5;

  fx4 acc[8][2] = {};

  // stage tile t: A 256x32 (2 loads/thread) + B 128x32 (1 load/thread);
  // source pre-swizzled with slot ^= (row>>1)&3, dst linear (both-sides rule).
  auto stage = [&](bh_t* dA, bh_t* dB, int t) {
    const int k0 = t << 5;
    #pragma unroll
    for (int j = 0; j < 2; ++j) {
      const int idx = j * 512 + tid;          // 16B units, 0..1023
      const int row = idx >> 2;
      const int slot = (idx & 3) ^ ((row >> 1) & 3);
      gload_lds16(Ab + (size_t)row * lda + k0 + slot * 8, dA + (size_t)idx * 8);
    }
    {
      const int idx = tid;                    // 0..511
      const int row = idx >> 2;
      const int slot = (idx & 3) ^ ((row >> 1) & 3);
      gload_lds16(Bb + (size_t)row * lda + k0 + slot * 8, dB + (size_t)idx * 8);
    }
  };

#define N_TILE(CA, CB, NA, NB, T)                                             \
  {                                                                           \
    if ((T) + 1 < nt) stage(&NA[0][0], &NB[0][0], (T) + 1);                   \
    bfx8 av[8], bv[2];                                                        \
    _Pragma("unroll")                                                         \
    for (int ni = 0; ni < 2; ++ni)                                            \
      bv[ni] = *(const bfx8*)(&CB[wc * 32 + ni * 16 + r16][0] + swk);         \
    _Pragma("unroll")                                                         \
    for (int mi = 0; mi < 8; ++mi)                                            \
      av[mi] = *(const bfx8*)(&CA[wr * 128 + mi * 16 + r16][0] + swk);        \
    asm volatile("s_waitcnt lgkmcnt(0)" ::: "memory");                        \
    __builtin_amdgcn_s_setprio(1);                                            \
    _Pragma("unroll")                                                         \
    for (int mi = 0; mi < 8; ++mi)                                            \
      _Pragma("unroll")                                                       \
      for (int ni = 0; ni < 2; ++ni)                                          \
        acc[mi][ni] = mfma16(av[mi], bv[ni], acc[mi][ni]);                    \
    __builtin_amdgcn_s_setprio(0);                                            \
    asm volatile("s_waitcnt vmcnt(0)" ::: "memory");                          \
    __builtin_amdgcn_s_barrier();                                             \
    asm volatile("" ::: "memory");                                            \
  }

  stage(&A0[0][0], &B0s[0][0], 0);
  asm volatile("s_waitcnt vmcnt(0)" ::: "memory");
  __builtin_amdgcn_s_barrier();
  asm volatile("" ::: "memory");

  for (int t = 0; t < nt; t += 2) {
    N_TILE(A0, B0s, A1, B1s, t);
    N_TILE(A1, B1s, A0, B0s, t + 1);
  }
#undef N_TILE

  const bool hasBias = flags & 1, doGelu = flags & 4, outBf = flags & 8;
  const bool wantVT  = flags & 16;
  float* outF = (float*)outp + (size_t)blockIdx.z * ((size_t)M * N);
  bh_t*  outB = (bh_t*)outp;
  #pragma unroll
  for (int mi = 0; mi < 8; ++mi) {
    const int rowb = m0 + wr * 128 + mi * 16 + 4 * g;
    #pragma unroll
    for (int ni = 0; ni < 2; ++ni) {
      const int col = n0 + wc * 32 + ni * 16 + r16;
      if (col >= N) continue;
      const float bv = hasBias ? bias[col] : 0.0f;
      if (wantVT && col >= 2 * CDIM) {
        // V element: write transposed vT[bq*768 + (col-2C)][t], 4 consecutive t
        const int hd = col - 2 * CDIM;           // h*64 + d, 0..767
        const int bq = rowb >> 10;               // batch index
        const int t0 = rowb & 1023;
        bfx4 vv;
        #pragma unroll
        for (int rr = 0; rr < 4; ++rr) vv[rr] = (bh_t)(acc[mi][ni][rr] + bv);
        *(bfx4*)(vTp + ((size_t)(bq * 768 + hd)) * TSEQ + t0) = vv;
      } else {
        #pragma unroll
        for (int rr = 0; rr < 4; ++rr) {
          const size_t idx = (size_t)(rowb + rr) * N + col;
          float v = acc[mi][ni][rr] + bv;
          if (doGelu) v = 0.5f * v * (1.0f + erff(v * 0.70710678118654752f));
          if (outBf) outB[idx] = (bh_t)v; else outF[idx] = v;
        }
      }
    }
  }
}

// ---------------------------------------------------------------------------
// fused split-K reduce + residual + LayerNorm
// ---------------------------------------------------------------------------
__global__ __launch_bounds__(256) void skred_ln(
    const float* __restrict__ part, const float* __restrict__ bias,
    float* __restrict__ x, const float* __restrict__ w,
    const float* __restrict__ bb, bh_t* __restrict__ out, int S)
{
  const int wave = threadIdx.x >> 6, lane = threadIdx.x & 63;
  const int row = blockIdx.x * 4 + wave;
  const size_t base = (size_t)row * CDIM;
  const int off = lane * 4;
  const size_t stride = (size_t)MROWS * CDIM;

  float4 v0 = *(const float4*)(x + base + off);
  float4 v1 = *(const float4*)(x + base + 256 + off);
  float4 v2 = *(const float4*)(x + base + 512 + off);
  for (int s = 0; s < S; ++s) {
    const float* pr = part + s * stride + base;
    const float4 p0 = *(const float4*)(pr + off);
    const float4 p1 = *(const float4*)(pr + 256 + off);
    const float4 p2 = *(const float4*)(pr + 512 + off);
    v0.x += p0.x; v0.y += p0.y; v0.z += p0.z; v0.w += p0.w;
    v1.x += p1.x; v1.y += p1.y; v1.z += p1.z; v1.w += p1.w;
    v2.x += p2.x; v2.y += p2.y; v2.z += p2.z; v2.w += p2.w;
  }
  const float4 q0 = *(const float4*)(bias + off);
  const float4 q1 = *(const float4*)(bias + 256 + off);
  const float4 q2 = *(const float4*)(bias + 512 + off);
  v0.x += q0.x; v0.y += q0.y; v0.z += q0.z; v0.w += q0.w;
  v1.x += q1.x; v1.y += q1.y; v1.z += q1.z; v1.w += q1.w;
  v2.x += q2.x; v2.y += q2.y; v2.z += q2.z; v2.w += q2.w;
  *(float4*)(x + base + off) = v0;
  *(float4*)(x + base + 256 + off) = v1;
  *(float4*)(x + base + 512 + off) = v2;

  float s1 = v0.x + v0.y + v0.z + v0.w + v1.x + v1.y + v1.z + v1.w
           + v2.x + v2.y + v2.z + v2.w;
  float ss = v0.x*v0.x + v0.y*v0.y + v0.z*v0.z + v0.w*v0.w
           + v1.x*v1.x + v1.y*v1.y + v1.z*v1.z + v1.w*v1.w
           + v2.x*v2.x + v2.y*v2.y + v2.z*v2.z + v2.w*v2.w;
  #pragma unroll
  for (int d = 1; d < 64; d <<= 1) { s1 += __shfl_xor(s1, d); ss += __shfl_xor(ss, d); }
  const float mean = s1 * (1.0f / 768.0f);
  const float inv = rsqrtf(ss * (1.0f / 768.0f) - mean * mean + 1e-5f);
  bh_t* orow = out + base;

  const float4 w0 = *(const float4*)(w + off),       b0 = *(const float4*)(bb + off);
  const float4 w1 = *(const float4*)(w + 256 + off), b1 = *(const float4*)(bb + 256 + off);
  const float4 w2 = *(const float4*)(w + 512 + off), b2 = *(const float4*)(bb + 512 + off);
  bfx4 o;
  o[0] = (bh_t)((v0.x - mean) * inv * w0.x + b0.x);
  o[1] = (bh_t)((v0.y - mean) * inv * w0.y + b0.y);
  o[2] = (bh_t)((v0.z - mean) * inv * w0.z + b0.z);
  o[3] = (bh_t)((v0.w - mean) * inv * w0.w + b0.w);
  *(bfx4*)(orow + off) = o;
  o[0] = (bh_t)((v1.x - mean) * inv * w1.x + b1.x);
  o[1] = (bh_t)((v1.y - mean) * inv * w1.y + b1.y);
  o[2] = (bh_t)((v1.z - mean) * inv * w1.z + b1.z);
  o[3] = (bh_t)((v1.w - mean) * inv * w1.w + b1.w);
  *(bfx4*)(orow + 256 + off) = o;
  o[0] = (bh_t)((v2.x - mean) * inv * w2.x + b2.x);
  o[1] = (bh_t)((v2.y - mean) * inv * w2.y + b2.y);
  o[2] = (bh_t)((v2.z - mean) * inv * w2.z + b2.z);
  o[3] = (bh_t)((v2.w - mean) * inv * w2.w + b2.w);
  *(bfx4*)(orow + 512 + off) = o;
}

// ---------------------------------------------------------------------------
// Flash attention, causal. One wave per (b, h, 16 q-rows).
// ---------------------------------------------------------------------------
__global__ __launch_bounds__(256) void attn_fwd(
    const bh_t* __restrict__ qkv, const bh_t* __restrict__ vT,
    bh_t* __restrict__ outb)
{
  __shared__ bh_t P[4][16][56];
  const int wave = threadIdx.x >> 6, lane = threadIdx.x & 63;
  const int g = lane >> 4, r16 = lane & 15;
  const int gw = blockIdx.x * 4 + wave;
  const int qblk = gw & 63;
  const int bh = gw >> 6;
  const int h = bh % NHEAD, b = bh / NHEAD;
  const int qbase = qblk * 16;
  const int qidx = qbase + r16;

  const bh_t* qp = qkv + (size_t)(b * TSEQ + qbase + r16) * (3 * CDIM) + h * HDIM + 8 * g;
  const bfx8 qf0 = *(const bfx8*)qp;
  const bfx8 qf1 = *(const bfx8*)(qp + 32);

  fx4 o[4] = {};
  float m = -INFINITY, l = 0.0f;
  const int ntiles = qblk / 2 + 1;

  for (int t = 0; t < ntiles; ++t) {
    const int kv0 = t * 32;
    const bh_t* kp = qkv + (size_t)(b * TSEQ + kv0 + r16) * (3 * CDIM) + CDIM + h * HDIM + 8 * g;
    const bfx8 ka0 = *(const bfx8*)kp;
    const bfx8 ka1 = *(const bfx8*)(kp + 32);
    const bfx8 kb0 = *(const bfx8*)(kp + 16 * (3 * CDIM));
    const bfx8 kb1 = *(const bfx8*)(kp + 16 * (3 * CDIM) + 32);
    fx4 s0 = {}, s1 = {};
    s0 = mfma16(ka0, qf0, s0); s0 = mfma16(ka1, qf1, s0);   // S^T: [kv][q]
    s1 = mfma16(kb0, qf0, s1); s1 = mfma16(kb1, qf1, s1);

    float mx = -INFINITY;
    float sv0[4], sv1[4];
    #pragma unroll
    for (int rr = 0; rr < 4; ++rr) {
      const int kva = kv0 + 4 * g + rr;
      const int kvb = kva + 16;
      sv0[rr] = (kva <= qidx) ? s0[rr] * 0.125f : -INFINITY;
      sv1[rr] = (kvb <= qidx) ? s1[rr] * 0.125f : -INFINITY;
      mx = fmaxf(mx, fmaxf(sv0[rr], sv1[rr]));
    }
    mx = fmaxf(mx, __shfl_xor(mx, 16));
    mx = fmaxf(mx, __shfl_xor(mx, 32));
    const float mnew = fmaxf(m, mx);
    const float corr = __expf(m - mnew);

    float ps = 0.0f;
    float pv0[4], pv1[4];
    #pragma unroll
    for (int rr = 0; rr < 4; ++rr) {
      pv0[rr] = __expf(sv0[rr] - mnew);
      pv1[rr] = __expf(sv1[rr] - mnew);
      ps += pv0[rr] + pv1[rr];
    }
    ps += __shfl_xor(ps, 16);
    ps += __shfl_xor(ps, 32);
    l = l * corr + ps;
    m = mnew;

    #pragma unroll
    for (int rr = 0; rr < 4; ++rr) {
      const float cr = __shfl(corr, 4 * g + rr);
      o[0][rr] *= cr; o[1][rr] *= cr; o[2][rr] *= cr; o[3][rr] *= cr;
    }

    bfx4 w0, w1;
    #pragma unroll
    for (int rr = 0; rr < 4; ++rr) { w0[rr] = (bh_t)pv0[rr]; w1[rr] = (bh_t)pv1[rr]; }
    *(bfx4*)&P[wave][r16][4 * g]      = w0;
    *(bfx4*)&P[wave][r16][16 + 4 * g] = w1;
    __builtin_amdgcn_wave_barrier();
    const bfx8 pf = *(const bfx8*)&P[wave][r16][8 * g];

    #pragma unroll
    for (int fi = 0; fi < 4; ++fi) {
      const bh_t* vp = vT + (size_t)(bh * HDIM + fi * 16 + r16) * TSEQ + kv0 + 8 * g;
      const bfx8 vf = *(const bfx8*)vp;
      o[fi] = mfma16(pf, vf, o[fi]);
    }
  }

  #pragma unroll
  for (int rr = 0; rr < 4; ++rr) {
    const float lr = __shfl(l, 4 * g + rr);
    const float inv = 1.0f / lr;
    const int trow = b * TSEQ + qbase + 4 * g + rr;
    #pragma unroll
    for (int fi = 0; fi < 4; ++fi)
      outb[(size_t)trow * CDIM + h * HDIM + fi * 16 + r16] = (bh_t)(o[fi][rr] * inv);
  }
}

// ---------------------------------------------------------------------------
// LayerNorm: f32 in -> bf16 out. One wave per row. (layer 0 entry only)
// ---------------------------------------------------------------------------
__global__ __launch_bounds__(256) void ln_fwd(
    const float* __restrict__ x, const float* __restrict__ w,
    const float* __restrict__ bb, bh_t* __restrict__ out)
{
  const int wave = threadIdx.x >> 6, lane = threadIdx.x & 63;
  const int row = blockIdx.x * 4 + wave;
  const float* xr = x + (size_t)row * CDIM;
  const int off = lane * 4;
  const float4 v0 = *(const float4*)(xr + off);
  const float4 v1 = *(const float4*)(xr + 256 + off);
  const float4 v2 = *(const float4*)(xr + 512 + off);
  float s  = v0.x + v0.y + v0.z + v0.w + v1.x + v1.y + v1.z + v1.w
           + v2.x + v2.y + v2.z + v2.w;
  float ss = v0.x*v0.x + v0.y*v0.y + v0.z*v0.z + v0.w*v0.w
           + v1.x*v1.x + v1.y*v1.y + v1.z*v1.z + v1.w*v1.w
           + v2.x*v2.x + v2.y*v2.y + v2.z*v2.z + v2.w*v2.w;
  #pragma unroll
  for (int d = 1; d < 64; d <<= 1) { s += __shfl_xor(s, d); ss += __shfl_xor(ss, d); }
  const float mean = s * (1.0f / 768.0f);
  const float inv = rsqrtf(ss * (1.0f / 768.0f) - mean * mean + 1e-5f);
  bh_t* orow = out + (size_t)row * CDIM;

  const float4 w0 = *(const float4*)(w + off),  b0 = *(const float4*)(bb + off);
  const float4 w1 = *(const float4*)(w + 256 + off), b1 = *(const float4*)(bb + 256 + off);
  const float4 w2 = *(const float4*)(w + 512 + off), b2 = *(const float4*)(bb + 512 + off);
  bfx4 o;
  o[0] = (bh_t)((v0.x - mean) * inv * w0.x + b0.x);
  o[1] = (bh_t)((v0.y - mean) * inv * w0.y + b0.y);
  o[2] = (bh_t)((v0.z - mean) * inv * w0.z + b0.z);
  o[3] = (bh_t)((v0.w - mean) * inv * w0.w + b0.w);
  *(bfx4*)(orow + off) = o;
  o[0] = (bh_t)((v1.x - mean) * inv * w1.x + b1.x);
  o[1] = (bh_t)((v1.y - mean) * inv * w1.y + b1.y);
  o[2] = (bh_t)((v1.z - mean) * inv * w1.z + b1.z);
  o[3] = (bh_t)((v1.w - mean) * inv * w1.w + b1.w);
  *(bfx4*)(orow + 256 + off) = o;
  o[0] = (bh_t)((v2.x - mean) * inv * w2.x + b2.x);
  o[1] = (bh_t)((v2.y - mean) * inv * w2.y + b2.y);
  o[2] = (bh_t)((v2.z - mean) * inv * w2.z + b2.z);
  o[3] = (bh_t)((v2.w - mean) * inv * w2.w + b2.w);
  *(bfx4*)(orow + 512 + off) = o;
}

// ---------------------------------------------------------------------------
__global__ void embed_k(const int* __restrict__ ids, const float* __restrict__ tok,
                        const float* __restrict__ pos, float* __restrict__ x)
{
  const int bt = blockIdx.x;
  const int t = bt & (TSEQ - 1);
  const int id = ids[bt];
  const float* tr = tok + (size_t)id * CDIM;
  const float* pr = pos + (size_t)t * CDIM;
  float* xr = x + (size_t)bt * CDIM;
  for (int j = threadIdx.x; j < CDIM; j += 256) xr[j] = tr[j] + pr[j];
}

// transpose + f32->bf16: in [L][R][Cn] -> out [L][Cn][R]
__global__ void tconv(const float* __restrict__ in, bh_t* __restrict__ out, int R, int Cn)
{
  __shared__ float tile[32][33];
  const size_t msz = (size_t)R * Cn;
  in  += msz * blockIdx.z;
  out += msz * blockIdx.z;
  const int tx = threadIdx.x & 31, ty = threadIdx.x >> 5;
  const int c0 = blockIdx.x * 32, r0 = blockIdx.y * 32;
  #pragma unroll
  for (int i = 0; i < 32; i += 8)
    tile[ty + i][tx] = in[(size_t)(r0 + ty + i) * Cn + c0 + tx];
  __syncthreads();
  #pragma unroll
  for (int i = 0; i < 32; i += 8)
    out[(size_t)(c0 + ty + i) * R + r0 + tx] = (bh_t)tile[tx][ty + i];
}

// tok_emb f32 [V][C] -> bf16 [VPAD][C], zero-padded rows
__global__ void embconv(const float* __restrict__ in, bh_t* __restrict__ out)
{
  const size_t i4 = ((size_t)blockIdx.x * 256 + threadIdx.x) * 4;
  if (i4 >= (size_t)VPAD * CDIM) return;
  const size_t vlim = (size_t)VOCAB * CDIM;
  float4 f = make_float4(0.f, 0.f, 0.f, 0.f);
  if (i4 < vlim) f = *(const float4*)(in + i4);
  bfx4 o;
  o[0] = (bh_t)f.x; o[1] = (bh_t)f.y; o[2] = (bh_t)f.z; o[3] = (bh_t)f.w;
  *(bfx4*)(out + i4) = o;
}

// ---------------------------------------------------------------------------
extern "C" void kernel_launch(void* const* d_in, const int* in_sizes, int n_in,
                              void* d_out, int out_size, void* d_ws, size_t ws_size,
                              hipStream_t stream)
{
  (void)in_sizes; (void)n_in; (void)out_size; (void)ws_size;
  const int*   ids    = (const int*)d_in[0];
  const float* tok    = (const float*)d_in[1];
  const float* pos    = (const float*)d_in[2];
  const float* qkv_w  = (const float*)d_in[3];
  const float* qkv_b  = (const float*)d_in[4];
  const float* proj_w = (const float*)d_in[5];
  const float* proj_b = (const float*)d_in[6];
  const float* ln1_w  = (const float*)d_in[7];
  const float* ln1_b  = (const float*)d_in[8];
  const float* ln2_w  = (const float*)d_in[9];
  const float* ln2_b  = (const float*)d_in[10];
  const float* fc1_w  = (const float*)d_in[11];
  const float* fc1_b  = (const float*)d_in[12];
  const float* fc2_w  = (const float*)d_in[13];
  const float* fc2_b  = (const float*)d_in[14];
  const float* lnf_w  = (const float*)d_in[15];
  const float* lnf_b  = (const float*)d_in[16];

  // ---- scratch in ws (activations + embT), ~153 MB
  char* wp = (char*)d_ws;
  auto carve = [&](size_t bytes) { char* p = wp; wp += (bytes + 255) & ~(size_t)255; return p; };
  float* x     = (float*)carve((size_t)MROWS * CDIM * 4);
  bh_t*  hbuf  = (bh_t*)carve((size_t)MROWS * CDIM * 2);
  bh_t*  qkvb  = (bh_t*)carve((size_t)MROWS * 3 * CDIM * 2);
  bh_t*  vT    = (bh_t*)carve((size_t)48 * HDIM * TSEQ * 2);
  bh_t*  attno = (bh_t*)carve((size_t)MROWS * CDIM * 2);
  bh_t*  mlp1  = (bh_t*)carve((size_t)MROWS * 3072 * 2);
  bh_t*  embT  = (bh_t*)carve((size_t)VPAD * CDIM * 2);

  // ---- staged in d_out (dead before lm_head overwrites it), ~270 MB of 823
  char* op = (char*)d_out;
  auto carveO = [&](size_t bytes) { char* p = op; op += (bytes + 255) & ~(size_t)255; return p; };
  bh_t* qkvwT  = (bh_t*)carveO((size_t)NLAYER * 3 * CDIM * CDIM * 2);
  bh_t* projwT = (bh_t*)carveO((size_t)NLAYER * CDIM * CDIM * 2);
  bh_t* fc1wT  = (bh_t*)carveO((size_t)NLAYER * 3072 * CDIM * 2);
  bh_t* fc2wT  = (bh_t*)carveO((size_t)NLAYER * CDIM * 3072 * 2);
  float* skpart = (float*)carveO((size_t)4 * MROWS * CDIM * 4);   // split-K partials

  tconv<<<dim3(2304 / 32, 768 / 32, NLAYER), 256, 0, stream>>>(qkv_w, qkvwT, 768, 2304);
  tconv<<<dim3(768 / 32, 768 / 32, NLAYER), 256, 0, stream>>>(proj_w, projwT, 768, 768);
  tconv<<<dim3(3072 / 32, 768 / 32, NLAYER), 256, 0, stream>>>(fc1_w, fc1wT, 768, 3072);
  tconv<<<dim3(768 / 32, 3072 / 32, NLAYER), 256, 0, stream>>>(fc2_w, fc2wT, 3072, 768);
  embconv<<<((VPAD * CDIM / 4) + 255) / 256, 256, 0, stream>>>(tok, embT);
  embed_k<<<MROWS, 256, 0, stream>>>(ids, tok, pos, x);

  ln_fwd<<<MROWS / 4, 256, 0, stream>>>(x, ln1_w, ln1_b, hbuf);
  for (int l = 0; l < NLAYER; ++l) {
    // qkv: grid 16x18 = 288 blocks; V columns go straight to vT (flag 16)
    gemm256n<<<dim3(16, 18), 512, 0, stream>>>(hbuf, qkvwT + (size_t)l * 3 * CDIM * CDIM,
        qkv_b + l * 3 * CDIM, qkvb, vT, MROWS, 3 * CDIM, CDIM, CDIM, 1 | 8 | 16);
    attn_fwd<<<768, 256, 0, stream>>>(qkvb, vT, attno);
    // proj: split-K x2 (K_eff=384, nt=12), grid 16x6x2 = 192 blocks
    gemm256n<<<dim3(16, 6, 2), 512, 0, stream>>>(attno,
        projwT + (size_t)l * CDIM * CDIM, nullptr, skpart, nullptr,
        MROWS, CDIM, 384, CDIM, 0);
    skred_ln<<<MROWS / 4, 256, 0, stream>>>(skpart, proj_b + l * CDIM, x,
        ln2_w + l * CDIM, ln2_b + l * CDIM, hbuf, 2);
    // fc1: grid 16x24 = 384 blocks
    gemm256n<<<dim3(16, 24), 512, 0, stream>>>(hbuf, fc1wT + (size_t)l * 3072 * CDIM,
        fc1_b + l * 3072, mlp1, nullptr, MROWS, 3072, CDIM, CDIM, 1 | 4 | 8);
    // fc2: split-K x4 (K_eff=768, nt=24), grid 16x6x4 = 384 blocks
    gemm256n<<<dim3(16, 6, 4), 512, 0, stream>>>(mlp1, fc2wT + (size_t)l * CDIM * 3072,
        nullptr, skpart, nullptr, MROWS, CDIM, 768, 3072, 0);
    const float* nw = (l + 1 < NLAYER) ? ln1_w + (l + 1) * CDIM : lnf_w;
    const float* nb = (l + 1 < NLAYER) ? ln1_b + (l + 1) * CDIM : lnf_b;
    skred_ln<<<MROWS / 4, 256, 0, stream>>>(skpart, fc2_b + l * CDIM, x, nw, nb, hbuf, 4);
  }
  // lm_head: grid 16x393 = 6288 blocks (50304 = 393*128 covers VOCAB)
  gemm256n<<<dim3(16, 393), 512, 0, stream>>>(hbuf, embT, nullptr,
      (float*)d_out, nullptr, MROWS, VOCAB, CDIM, CDIM, 0);
}

// Round 17
// 3560.803 us; speedup vs baseline: 1.2759x; 1.0141x over previous
//
#include <hip/hip_runtime.h>
#include <hip/hip_bf16.h>

// GPT-2 small forward on gfx950. bf16 MFMA GEMMs (f32 accum), flash attention.
// R17: gemm128 (128x128, BK=32, 4 waves, 32KB LDS -> 4 blocks/CU) replaces
//      gemm256n everywhere. Same 2-phase schedule/swizzle; the ONE variable
//      changed is barrier-group size: 4 independent 4-wave barrier groups
//      per CU (vs 2x8) -> a draining group is covered by 3 others at
//      uncorrelated phases. Per-wave tile work drops 10->8 ds_reads/16 MFMA.
//      vT fusion (R16) and skred_ln split-K layout kept.

typedef __bf16 bh_t;
typedef __bf16 bfx4 __attribute__((ext_vector_type(4)));
typedef __bf16 bfx8 __attribute__((ext_vector_type(8)));
typedef float  fx4  __attribute__((ext_vector_type(4)));

#define CDIM 768
#define TSEQ 1024
#define NHEAD 12
#define HDIM 64
#define NLAYER 12
#define MROWS 4096          // B*T
#define VOCAB 50257
#define VPAD  50432

__device__ __forceinline__ void gload_lds16(const void* g, void* l) {
  __builtin_amdgcn_global_load_lds(
      (const __attribute__((address_space(1))) void*)g,
      (__attribute__((address_space(3))) void*)l, 16, 0, 0);
}

__device__ __forceinline__ fx4 mfma16(bfx8 a, bfx8 b, fx4 c) {
  return __builtin_amdgcn_mfma_f32_16x16x32_bf16(a, b, c, 0, 0, 0);
}

// ---------------------------------------------------------------------------
// 128x128 GEMM, BK=32, 32KB LDS double-buffer, 4 blocks/CU. 4 waves (2Mx2N),
// wave tile 64x64, acc 4x4. Swizzle slot ^= (row>>1)&3 on stage-source and
// read (both-sides involution; conflict-free family, R7-verified).
// blockIdx.z = split-K slice (A,B advance z*K; f32 partial at z*M*N).
// flags: 1=bias, 4=gelu, 8=out bf16, 16=V-cols (>=2C) -> vT transposed.
// ---------------------------------------------------------------------------
__global__ __launch_bounds__(256, 4) void gemm128(
    const bh_t* __restrict__ A, const bh_t* __restrict__ B,
    const float* __restrict__ bias, void* __restrict__ outp,
    bh_t* __restrict__ vTp,
    int M, int N, int K, int lda, int flags)
{
  __shared__ bh_t A0[128][32], B0s[128][32];
  __shared__ bh_t A1[128][32], B1s[128][32];
  const int tid = threadIdx.x;
  const int wid = tid >> 6, lane = tid & 63;
  const int g = lane >> 4, r16 = lane & 15;
  const int wr = wid >> 1, wc = wid & 1;        // 2M x 2N waves
  const int m0 = blockIdx.x * 128, n0 = blockIdx.y * 128;
  const int swk = (g ^ ((r16 >> 1) & 3)) * 8;   // swizzled slot offset (elems)

  const bh_t* Ab = A + (size_t)blockIdx.z * K + (size_t)m0 * lda;
  const bh_t* Bb = B + (size_t)blockIdx.z * K + (size_t)n0 * lda;
  const int nt = K >> 5;

  fx4 acc[4][4] = {};

  // stage tile t: A 128x32 (2 loads/thread) + B 128x32 (2 loads/thread);
  // source pre-swizzled with slot ^= (row>>1)&3, dst linear.
  auto stage = [&](bh_t* dA, bh_t* dB, int t) {
    const int k0 = t << 5;
    #pragma unroll
    for (int j = 0; j < 2; ++j) {
      const int idx = j * 256 + tid;          // 16B units, 0..511
      const int row = idx >> 2;               // 0..127
      const int slot = (idx & 3) ^ ((row >> 1) & 3);
      gload_lds16(Ab + (size_t)row * lda + k0 + slot * 8, dA + (size_t)idx * 8);
    }
    #pragma unroll
    for (int j = 0; j < 2; ++j) {
      const int idx = j * 256 + tid;
      const int row = idx >> 2;
      const int slot = (idx & 3) ^ ((row >> 1) & 3);
      gload_lds16(Bb + (size_t)row * lda + k0 + slot * 8, dB + (size_t)idx * 8);
    }
  };

#define N_TILE(CA, CB, NA, NB, T)                                             \
  {                                                                           \
    if ((T) + 1 < nt) stage(&NA[0][0], &NB[0][0], (T) + 1);                   \
    bfx8 av[4], bv[4];                                                        \
    _Pragma("unroll")                                                         \
    for (int ni = 0; ni < 4; ++ni)                                            \
      bv[ni] = *(const bfx8*)(&CB[wc * 64 + ni * 16 + r16][0] + swk);         \
    _Pragma("unroll")                                                         \
    for (int mi = 0; mi < 4; ++mi)                                            \
      av[mi] = *(const bfx8*)(&CA[wr * 64 + mi * 16 + r16][0] + swk);         \
    asm volatile("s_waitcnt lgkmcnt(0)" ::: "memory");                        \
    __builtin_amdgcn_s_setprio(1);                                            \
    _Pragma("unroll")                                                         \
    for (int mi = 0; mi < 4; ++mi)                                            \
      _Pragma("unroll")                                                       \
      for (int ni = 0; ni < 4; ++ni)                                          \
        acc[mi][ni] = mfma16(av[mi], bv[ni], acc[mi][ni]);                    \
    __builtin_amdgcn_s_setprio(0);                                            \
    asm volatile("s_waitcnt vmcnt(0)" ::: "memory");                          \
    __builtin_amdgcn_s_barrier();                                             \
    asm volatile("" ::: "memory");                                            \
  }

  stage(&A0[0][0], &B0s[0][0], 0);
  asm volatile("s_waitcnt vmcnt(0)" ::: "memory");
  __builtin_amdgcn_s_barrier();
  asm volatile("" ::: "memory");

  for (int t = 0; t < nt; t += 2) {
    N_TILE(A0, B0s, A1, B1s, t);
    N_TILE(A1, B1s, A0, B0s, t + 1);
  }
#undef N_TILE

  const bool hasBias = flags & 1, doGelu = flags & 4, outBf = flags & 8;
  const bool wantVT  = flags & 16;
  float* outF = (float*)outp + (size_t)blockIdx.z * ((size_t)M * N);
  bh_t*  outB = (bh_t*)outp;
  #pragma unroll
  for (int mi = 0; mi < 4; ++mi) {
    const int rowb = m0 + wr * 64 + mi * 16 + 4 * g;
    #pragma unroll
    for (int ni = 0; ni < 4; ++ni) {
      const int col = n0 + wc * 64 + ni * 16 + r16;
      if (col >= N) continue;
      const float bv = hasBias ? bias[col] : 0.0f;
      if (wantVT && col >= 2 * CDIM) {
        // V element: write transposed vT[bq*768 + (col-2C)][t], 4 consecutive t
        const int hd = col - 2 * CDIM;           // h*64 + d, 0..767
        const int bq = rowb >> 10;               // batch index
        const int t0 = rowb & 1023;
        bfx4 vv;
        #pragma unroll
        for (int rr = 0; rr < 4; ++rr) vv[rr] = (bh_t)(acc[mi][ni][rr] + bv);
        *(bfx4*)(vTp + ((size_t)(bq * 768 + hd)) * TSEQ + t0) = vv;
      } else {
        #pragma unroll
        for (int rr = 0; rr < 4; ++rr) {
          const size_t idx = (size_t)(rowb + rr) * N + col;
          float v = acc[mi][ni][rr] + bv;
          if (doGelu) v = 0.5f * v * (1.0f + erff(v * 0.70710678118654752f));
          if (outBf) outB[idx] = (bh_t)v; else outF[idx] = v;
        }
      }
    }
  }
}

// ---------------------------------------------------------------------------
// fused split-K reduce + residual + LayerNorm
// ---------------------------------------------------------------------------
__global__ __launch_bounds__(256) void skred_ln(
    const float* __restrict__ part, const float* __restrict__ bias,
    float* __restrict__ x, const float* __restrict__ w,
    const float* __restrict__ bb, bh_t* __restrict__ out, int S)
{
  const int wave = threadIdx.x >> 6, lane = threadIdx.x & 63;
  const int row = blockIdx.x * 4 + wave;
  const size_t base = (size_t)row * CDIM;
  const int off = lane * 4;
  const size_t stride = (size_t)MROWS * CDIM;

  float4 v0 = *(const float4*)(x + base + off);
  float4 v1 = *(const float4*)(x + base + 256 + off);
  float4 v2 = *(const float4*)(x + base + 512 + off);
  for (int s = 0; s < S; ++s) {
    const float* pr = part + s * stride + base;
    const float4 p0 = *(const float4*)(pr + off);
    const float4 p1 = *(const float4*)(pr + 256 + off);
    const float4 p2 = *(const float4*)(pr + 512 + off);
    v0.x += p0.x; v0.y += p0.y; v0.z += p0.z; v0.w += p0.w;
    v1.x += p1.x; v1.y += p1.y; v1.z += p1.z; v1.w += p1.w;
    v2.x += p2.x; v2.y += p2.y; v2.z += p2.z; v2.w += p2.w;
  }
  const float4 q0 = *(const float4*)(bias + off);
  const float4 q1 = *(const float4*)(bias + 256 + off);
  const float4 q2 = *(const float4*)(bias + 512 + off);
  v0.x += q0.x; v0.y += q0.y; v0.z += q0.z; v0.w += q0.w;
  v1.x += q1.x; v1.y += q1.y; v1.z += q1.z; v1.w += q1.w;
  v2.x += q2.x; v2.y += q2.y; v2.z += q2.z; v2.w += q2.w;
  *(float4*)(x + base + off) = v0;
  *(float4*)(x + base + 256 + off) = v1;
  *(float4*)(x + base + 512 + off) = v2;

  float s1 = v0.x + v0.y + v0.z + v0.w + v1.x + v1.y + v1.z + v1.w
           + v2.x + v2.y + v2.z + v2.w;
  float ss = v0.x*v0.x + v0.y*v0.y + v0.z*v0.z + v0.w*v0.w
           + v1.x*v1.x + v1.y*v1.y + v1.z*v1.z + v1.w*v1.w
           + v2.x*v2.x + v2.y*v2.y + v2.z*v2.z + v2.w*v2.w;
  #pragma unroll
  for (int d = 1; d < 64; d <<= 1) { s1 += __shfl_xor(s1, d); ss += __shfl_xor(ss, d); }
  const float mean = s1 * (1.0f / 768.0f);
  const float inv = rsqrtf(ss * (1.0f / 768.0f) - mean * mean + 1e-5f);
  bh_t* orow = out + base;

  const float4 w0 = *(const float4*)(w + off),       b0 = *(const float4*)(bb + off);
  const float4 w1 = *(const float4*)(w + 256 + off), b1 = *(const float4*)(bb + 256 + off);
  const float4 w2 = *(const float4*)(w + 512 + off), b2 = *(const float4*)(bb + 512 + off);
  bfx4 o;
  o[0] = (bh_t)((v0.x - mean) * inv * w0.x + b0.x);
  o[1] = (bh_t)((v0.y - mean) * inv * w0.y + b0.y);
  o[2] = (bh_t)((v0.z - mean) * inv * w0.z + b0.z);
  o[3] = (bh_t)((v0.w - mean) * inv * w0.w + b0.w);
  *(bfx4*)(orow + off) = o;
  o[0] = (bh_t)((v1.x - mean) * inv * w1.x + b1.x);
  o[1] = (bh_t)((v1.y - mean) * inv * w1.y + b1.y);
  o[2] = (bh_t)((v1.z - mean) * inv * w1.z + b1.z);
  o[3] = (bh_t)((v1.w - mean) * inv * w1.w + b1.w);
  *(bfx4*)(orow + 256 + off) = o;
  o[0] = (bh_t)((v2.x - mean) * inv * w2.x + b2.x);
  o[1] = (bh_t)((v2.y - mean) * inv * w2.y + b2.y);
  o[2] = (bh_t)((v2.z - mean) * inv * w2.z + b2.z);
  o[3] = (bh_t)((v2.w - mean) * inv * w2.w + b2.w);
  *(bfx4*)(orow + 512 + off) = o;
}

// ---------------------------------------------------------------------------
// Flash attention, causal. One wave per (b, h, 16 q-rows).
// ---------------------------------------------------------------------------
__global__ __launch_bounds__(256) void attn_fwd(
    const bh_t* __restrict__ qkv, const bh_t* __restrict__ vT,
    bh_t* __restrict__ outb)
{
  __shared__ bh_t P[4][16][56];
  const int wave = threadIdx.x >> 6, lane = threadIdx.x & 63;
  const int g = lane >> 4, r16 = lane & 15;
  const int gw = blockIdx.x * 4 + wave;
  const int qblk = gw & 63;
  const int bh = gw >> 6;
  const int h = bh % NHEAD, b = bh / NHEAD;
  const int qbase = qblk * 16;
  const int qidx = qbase + r16;

  const bh_t* qp = qkv + (size_t)(b * TSEQ + qbase + r16) * (3 * CDIM) + h * HDIM + 8 * g;
  const bfx8 qf0 = *(const bfx8*)qp;
  const bfx8 qf1 = *(const bfx8*)(qp + 32);

  fx4 o[4] = {};
  float m = -INFINITY, l = 0.0f;
  const int ntiles = qblk / 2 + 1;

  for (int t = 0; t < ntiles; ++t) {
    const int kv0 = t * 32;
    const bh_t* kp = qkv + (size_t)(b * TSEQ + kv0 + r16) * (3 * CDIM) + CDIM + h * HDIM + 8 * g;
    const bfx8 ka0 = *(const bfx8*)kp;
    const bfx8 ka1 = *(const bfx8*)(kp + 32);
    const bfx8 kb0 = *(const bfx8*)(kp + 16 * (3 * CDIM));
    const bfx8 kb1 = *(const bfx8*)(kp + 16 * (3 * CDIM) + 32);
    fx4 s0 = {}, s1 = {};
    s0 = mfma16(ka0, qf0, s0); s0 = mfma16(ka1, qf1, s0);   // S^T: [kv][q]
    s1 = mfma16(kb0, qf0, s1); s1 = mfma16(kb1, qf1, s1);

    float mx = -INFINITY;
    float sv0[4], sv1[4];
    #pragma unroll
    for (int rr = 0; rr < 4; ++rr) {
      const int kva = kv0 + 4 * g + rr;
      const int kvb = kva + 16;
      sv0[rr] = (kva <= qidx) ? s0[rr] * 0.125f : -INFINITY;
      sv1[rr] = (kvb <= qidx) ? s1[rr] * 0.125f : -INFINITY;
      mx = fmaxf(mx, fmaxf(sv0[rr], sv1[rr]));
    }
    mx = fmaxf(mx, __shfl_xor(mx, 16));
    mx = fmaxf(mx, __shfl_xor(mx, 32));
    const float mnew = fmaxf(m, mx);
    const float corr = __expf(m - mnew);

    float ps = 0.0f;
    float pv0[4], pv1[4];
    #pragma unroll
    for (int rr = 0; rr < 4; ++rr) {
      pv0[rr] = __expf(sv0[rr] - mnew);
      pv1[rr] = __expf(sv1[rr] - mnew);
      ps += pv0[rr] + pv1[rr];
    }
    ps += __shfl_xor(ps, 16);
    ps += __shfl_xor(ps, 32);
    l = l * corr + ps;
    m = mnew;

    #pragma unroll
    for (int rr = 0; rr < 4; ++rr) {
      const float cr = __shfl(corr, 4 * g + rr);
      o[0][rr] *= cr; o[1][rr] *= cr; o[2][rr] *= cr; o[3][rr] *= cr;
    }

    bfx4 w0, w1;
    #pragma unroll
    for (int rr = 0; rr < 4; ++rr) { w0[rr] = (bh_t)pv0[rr]; w1[rr] = (bh_t)pv1[rr]; }
    *(bfx4*)&P[wave][r16][4 * g]      = w0;
    *(bfx4*)&P[wave][r16][16 + 4 * g] = w1;
    __builtin_amdgcn_wave_barrier();
    const bfx8 pf = *(const bfx8*)&P[wave][r16][8 * g];

    #pragma unroll
    for (int fi = 0; fi < 4; ++fi) {
      const bh_t* vp = vT + (size_t)(bh * HDIM + fi * 16 + r16) * TSEQ + kv0 + 8 * g;
      const bfx8 vf = *(const bfx8*)vp;
      o[fi] = mfma16(pf, vf, o[fi]);
    }
  }

  #pragma unroll
  for (int rr = 0; rr < 4; ++rr) {
    const float lr = __shfl(l, 4 * g + rr);
    const float inv = 1.0f / lr;
    const int trow = b * TSEQ + qbase + 4 * g + rr;
    #pragma unroll
    for (int fi = 0; fi < 4; ++fi)
      outb[(size_t)trow * CDIM + h * HDIM + fi * 16 + r16] = (bh_t)(o[fi][rr] * inv);
  }
}

// ---------------------------------------------------------------------------
// LayerNorm: f32 in -> bf16 out. One wave per row. (layer 0 entry only)
// ---------------------------------------------------------------------------
__global__ __launch_bounds__(256) void ln_fwd(
    const float* __restrict__ x, const float* __restrict__ w,
    const float* __restrict__ bb, bh_t* __restrict__ out)
{
  const int wave = threadIdx.x >> 6, lane = threadIdx.x & 63;
  const int row = blockIdx.x * 4 + wave;
  const float* xr = x + (size_t)row * CDIM;
  const int off = lane * 4;
  const float4 v0 = *(const float4*)(xr + off);
  const float4 v1 = *(const float4*)(xr + 256 + off);
  const float4 v2 = *(const float4*)(xr + 512 + off);
  float s  = v0.x + v0.y + v0.z + v0.w + v1.x + v1.y + v1.z + v1.w
           + v2.x + v2.y + v2.z + v2.w;
  float ss = v0.x*v0.x + v0.y*v0.y + v0.z*v0.z + v0.w*v0.w
           + v1.x*v1.x + v1.y*v1.y + v1.z*v1.z + v1.w*v1.w
           + v2.x*v2.x + v2.y*v2.y + v2.z*v2.z + v2.w*v2.w;
  #pragma unroll
  for (int d = 1; d < 64; d <<= 1) { s += __shfl_xor(s, d); ss += __shfl_xor(ss, d); }
  const float mean = s * (1.0f / 768.0f);
  const float inv = rsqrtf(ss * (1.0f / 768.0f) - mean * mean + 1e-5f);
  bh_t* orow = out + (size_t)row * CDIM;

  const float4 w0 = *(const float4*)(w + off),  b0 = *(const float4*)(bb + off);
  const float4 w1 = *(const float4*)(w + 256 + off), b1 = *(const float4*)(bb + 256 + off);
  const float4 w2 = *(const float4*)(w + 512 + off), b2 = *(const float4*)(bb + 512 + off);
  bfx4 o;
  o[0] = (bh_t)((v0.x - mean) * inv * w0.x + b0.x);
  o[1] = (bh_t)((v0.y - mean) * inv * w0.y + b0.y);
  o[2] = (bh_t)((v0.z - mean) * inv * w0.z + b0.z);
  o[3] = (bh_t)((v0.w - mean) * inv * w0.w + b0.w);
  *(bfx4*)(orow + off) = o;
  o[0] = (bh_t)((v1.x - mean) * inv * w1.x + b1.x);
  o[1] = (bh_t)((v1.y - mean) * inv * w1.y + b1.y);
  o[2] = (bh_t)((v1.z - mean) * inv * w1.z + b1.z);
  o[3] = (bh_t)((v1.w - mean) * inv * w1.w + b1.w);
  *(bfx4*)(orow + 256 + off) = o;
  o[0] = (bh_t)((v2.x - mean) * inv * w2.x + b2.x);
  o[1] = (bh_t)((v2.y - mean) * inv * w2.y + b2.y);
  o[2] = (bh_t)((v2.z - mean) * inv * w2.z + b2.z);
  o[3] = (bh_t)((v2.w - mean) * inv * w2.w + b2.w);
  *(bfx4*)(orow + 512 + off) = o;
}

// ---------------------------------------------------------------------------
__global__ void embed_k(const int* __restrict__ ids, const float* __restrict__ tok,
                        const float* __restrict__ pos, float* __restrict__ x)
{
  const int bt = blockIdx.x;
  const int t = bt & (TSEQ - 1);
  const int id = ids[bt];
  const float* tr = tok + (size_t)id * CDIM;
  const float* pr = pos + (size_t)t * CDIM;
  float* xr = x + (size_t)bt * CDIM;
  for (int j = threadIdx.x; j < CDIM; j += 256) xr[j] = tr[j] + pr[j];
}

// transpose + f32->bf16: in [L][R][Cn] -> out [L][Cn][R]
__global__ void tconv(const float* __restrict__ in, bh_t* __restrict__ out, int R, int Cn)
{
  __shared__ float tile[32][33];
  const size_t msz = (size_t)R * Cn;
  in  += msz * blockIdx.z;
  out += msz * blockIdx.z;
  const int tx = threadIdx.x & 31, ty = threadIdx.x >> 5;
  const int c0 = blockIdx.x * 32, r0 = blockIdx.y * 32;
  #pragma unroll
  for (int i = 0; i < 32; i += 8)
    tile[ty + i][tx] = in[(size_t)(r0 + ty + i) * Cn + c0 + tx];
  __syncthreads();
  #pragma unroll
  for (int i = 0; i < 32; i += 8)
    out[(size_t)(c0 + ty + i) * R + r0 + tx] = (bh_t)tile[tx][ty + i];
}

// tok_emb f32 [V][C] -> bf16 [VPAD][C], zero-padded rows
__global__ void embconv(const float* __restrict__ in, bh_t* __restrict__ out)
{
  const size_t i4 = ((size_t)blockIdx.x * 256 + threadIdx.x) * 4;
  if (i4 >= (size_t)VPAD * CDIM) return;
  const size_t vlim = (size_t)VOCAB * CDIM;
  float4 f = make_float4(0.f, 0.f, 0.f, 0.f);
  if (i4 < vlim) f = *(const float4*)(in + i4);
  bfx4 o;
  o[0] = (bh_t)f.x; o[1] = (bh_t)f.y; o[2] = (bh_t)f.z; o[3] = (bh_t)f.w;
  *(bfx4*)(out + i4) = o;
}

// ---------------------------------------------------------------------------
extern "C" void kernel_launch(void* const* d_in, const int* in_sizes, int n_in,
                              void* d_out, int out_size, void* d_ws, size_t ws_size,
                              hipStream_t stream)
{
  (void)in_sizes; (void)n_in; (void)out_size; (void)ws_size;
  const int*   ids    = (const int*)d_in[0];
  const float* tok    = (const float*)d_in[1];
  const float* pos    = (const float*)d_in[2];
  const float* qkv_w  = (const float*)d_in[3];
  const float* qkv_b  = (const float*)d_in[4];
  const float* proj_w = (const float*)d_in[5];
  const float* proj_b = (const float*)d_in[6];
  const float* ln1_w  = (const float*)d_in[7];
  const float* ln1_b  = (const float*)d_in[8];
  const float* ln2_w  = (const float*)d_in[9];
  const float* ln2_b  = (const float*)d_in[10];
  const float* fc1_w  = (const float*)d_in[11];
  const float* fc1_b  = (const float*)d_in[12];
  const float* fc2_w  = (const float*)d_in[13];
  const float* fc2_b  = (const float*)d_in[14];
  const float* lnf_w  = (const float*)d_in[15];
  const float* lnf_b  = (const float*)d_in[16];

  // ---- scratch in ws (activations + embT), ~153 MB
  char* wp = (char*)d_ws;
  auto carve = [&](size_t bytes) { char* p = wp; wp += (bytes + 255) & ~(size_t)255; return p; };
  float* x     = (float*)carve((size_t)MROWS * CDIM * 4);
  bh_t*  hbuf  = (bh_t*)carve((size_t)MROWS * CDIM * 2);
  bh_t*  qkvb  = (bh_t*)carve((size_t)MROWS * 3 * CDIM * 2);
  bh_t*  vT    = (bh_t*)carve((size_t)48 * HDIM * TSEQ * 2);
  bh_t*  attno = (bh_t*)carve((size_t)MROWS * CDIM * 2);
  bh_t*  mlp1  = (bh_t*)carve((size_t)MROWS * 3072 * 2);
  bh_t*  embT  = (bh_t*)carve((size_t)VPAD * CDIM * 2);

  // ---- staged in d_out (dead before lm_head overwrites it), ~270 MB of 823
  char* op = (char*)d_out;
  auto carveO = [&](size_t bytes) { char* p = op; op += (bytes + 255) & ~(size_t)255; return p; };
  bh_t* qkvwT  = (bh_t*)carveO((size_t)NLAYER * 3 * CDIM * CDIM * 2);
  bh_t* projwT = (bh_t*)carveO((size_t)NLAYER * CDIM * CDIM * 2);
  bh_t* fc1wT  = (bh_t*)carveO((size_t)NLAYER * 3072 * CDIM * 2);
  bh_t* fc2wT  = (bh_t*)carveO((size_t)NLAYER * CDIM * 3072 * 2);
  float* skpart = (float*)carveO((size_t)4 * MROWS * CDIM * 4);   // split-K partials

  tconv<<<dim3(2304 / 32, 768 / 32, NLAYER), 256, 0, stream>>>(qkv_w, qkvwT, 768, 2304);
  tconv<<<dim3(768 / 32, 768 / 32, NLAYER), 256, 0, stream>>>(proj_w, projwT, 768, 768);
  tconv<<<dim3(3072 / 32, 768 / 32, NLAYER), 256, 0, stream>>>(fc1_w, fc1wT, 768, 3072);
  tconv<<<dim3(768 / 32, 3072 / 32, NLAYER), 256, 0, stream>>>(fc2_w, fc2wT, 3072, 768);
  embconv<<<((VPAD * CDIM / 4) + 255) / 256, 256, 0, stream>>>(tok, embT);
  embed_k<<<MROWS, 256, 0, stream>>>(ids, tok, pos, x);

  ln_fwd<<<MROWS / 4, 256, 0, stream>>>(x, ln1_w, ln1_b, hbuf);
  for (int l = 0; l < NLAYER; ++l) {
    // qkv: grid 32x18 = 576 blocks; V columns go straight to vT (flag 16)
    gemm128<<<dim3(32, 18), 256, 0, stream>>>(hbuf, qkvwT + (size_t)l * 3 * CDIM * CDIM,
        qkv_b + l * 3 * CDIM, qkvb, vT, MROWS, 3 * CDIM, CDIM, CDIM, 1 | 8 | 16);
    attn_fwd<<<768, 256, 0, stream>>>(qkvb, vT, attno);
    // proj: split-K x2 (K_eff=384, nt=12), grid 32x6x2 = 384 blocks
    gemm128<<<dim3(32, 6, 2), 256, 0, stream>>>(attno,
        projwT + (size_t)l * CDIM * CDIM, nullptr, skpart, nullptr,
        MROWS, CDIM, 384, CDIM, 0);
    skred_ln<<<MROWS / 4, 256, 0, stream>>>(skpart, proj_b + l * CDIM, x,
        ln2_w + l * CDIM, ln2_b + l * CDIM, hbuf, 2);
    // fc1: grid 32x24 = 768 blocks
    gemm128<<<dim3(32, 24), 256, 0, stream>>>(hbuf, fc1wT + (size_t)l * 3072 * CDIM,
        fc1_b + l * 3072, mlp1, nullptr, MROWS, 3072, CDIM, CDIM, 1 | 4 | 8);
    // fc2: split-K x4 (K_eff=768, nt=24), grid 32x6x4 = 768 blocks
    gemm128<<<dim3(32, 6, 4), 256, 0, stream>>>(mlp1, fc2wT + (size_t)l * CDIM * 3072,
        nullptr, skpart, nullptr, MROWS, CDIM, 768, 3072, 0);
    const float* nw = (l + 1 < NLAYER) ? ln1_w + (l + 1) * CDIM : lnf_w;
    const float* nb = (l + 1 < NLAYER) ? ln1_b + (l + 1) * CDIM : lnf_b;
    skred_ln<<<MROWS / 4, 256, 0, stream>>>(skpart, fc2_b + l * CDIM, x, nw, nb, hbuf, 4);
  }
  // lm_head: grid 32x393 = 12576 blocks (50304 = 393*128 covers VOCAB)
  gemm128<<<dim3(32, 393), 256, 0, stream>>>(hbuf, embT, nullptr,
      (float*)d_out, nullptr, MROWS, VOCAB, CDIM, CDIM, 0);
}

// Round 18
// 3495.190 us; speedup vs baseline: 1.2998x; 1.0188x over previous
//
#include <hip/hip_runtime.h>
#include <hip/hip_bf16.h>

// GPT-2 small forward on gfx950. bf16 MFMA GEMMs (f32 accum), flash attention.
// R18: mixed routing — gemm128 (128x128, 4 blocks/CU; best for layer GEMMs,
//      R17) for qkv/proj/fc1/fc2; gemm256n (256x128, 2 blocks/CU; best for
//      lm_head, R16: 532us vs 565 — wider M-tile halves f32 write
//      amplification) for lm_head. vT fusion + skred_ln layout kept.

typedef __bf16 bh_t;
typedef __bf16 bfx4 __attribute__((ext_vector_type(4)));
typedef __bf16 bfx8 __attribute__((ext_vector_type(8)));
typedef float  fx4  __attribute__((ext_vector_type(4)));

#define CDIM 768
#define TSEQ 1024
#define NHEAD 12
#define HDIM 64
#define NLAYER 12
#define MROWS 4096          // B*T
#define VOCAB 50257
#define VPAD  50432

__device__ __forceinline__ void gload_lds16(const void* g, void* l) {
  __builtin_amdgcn_global_load_lds(
      (const __attribute__((address_space(1))) void*)g,
      (__attribute__((address_space(3))) void*)l, 16, 0, 0);
}

__device__ __forceinline__ fx4 mfma16(bfx8 a, bfx8 b, fx4 c) {
  return __builtin_amdgcn_mfma_f32_16x16x32_bf16(a, b, c, 0, 0, 0);
}

// ---------------------------------------------------------------------------
// 128x128 GEMM, BK=32, 32KB LDS double-buffer, 4 blocks/CU. 4 waves (2Mx2N),
// wave tile 64x64, acc 4x4. Swizzle slot ^= (row>>1)&3 (both-sides).
// blockIdx.z = split-K slice. flags: 1=bias,4=gelu,8=out bf16,16=V->vT.
// ---------------------------------------------------------------------------
__global__ __launch_bounds__(256, 4) void gemm128(
    const bh_t* __restrict__ A, const bh_t* __restrict__ B,
    const float* __restrict__ bias, void* __restrict__ outp,
    bh_t* __restrict__ vTp,
    int M, int N, int K, int lda, int flags)
{
  __shared__ bh_t A0[128][32], B0s[128][32];
  __shared__ bh_t A1[128][32], B1s[128][32];
  const int tid = threadIdx.x;
  const int wid = tid >> 6, lane = tid & 63;
  const int g = lane >> 4, r16 = lane & 15;
  const int wr = wid >> 1, wc = wid & 1;        // 2M x 2N waves
  const int m0 = blockIdx.x * 128, n0 = blockIdx.y * 128;
  const int swk = (g ^ ((r16 >> 1) & 3)) * 8;

  const bh_t* Ab = A + (size_t)blockIdx.z * K + (size_t)m0 * lda;
  const bh_t* Bb = B + (size_t)blockIdx.z * K + (size_t)n0 * lda;
  const int nt = K >> 5;

  fx4 acc[4][4] = {};

  auto stage = [&](bh_t* dA, bh_t* dB, int t) {
    const int k0 = t << 5;
    #pragma unroll
    for (int j = 0; j < 2; ++j) {
      const int idx = j * 256 + tid;          // 16B units, 0..511
      const int row = idx >> 2;               // 0..127
      const int slot = (idx & 3) ^ ((row >> 1) & 3);
      gload_lds16(Ab + (size_t)row * lda + k0 + slot * 8, dA + (size_t)idx * 8);
    }
    #pragma unroll
    for (int j = 0; j < 2; ++j) {
      const int idx = j * 256 + tid;
      const int row = idx >> 2;
      const int slot = (idx & 3) ^ ((row >> 1) & 3);
      gload_lds16(Bb + (size_t)row * lda + k0 + slot * 8, dB + (size_t)idx * 8);
    }
  };

#define N_TILE(CA, CB, NA, NB, T)                                             \
  {                                                                           \
    if ((T) + 1 < nt) stage(&NA[0][0], &NB[0][0], (T) + 1);                   \
    bfx8 av[4], bv[4];                                                        \
    _Pragma("unroll")                                                         \
    for (int ni = 0; ni < 4; ++ni)                                            \
      bv[ni] = *(const bfx8*)(&CB[wc * 64 + ni * 16 + r16][0] + swk);         \
    _Pragma("unroll")                                                         \
    for (int mi = 0; mi < 4; ++mi)                                            \
      av[mi] = *(const bfx8*)(&CA[wr * 64 + mi * 16 + r16][0] + swk);         \
    asm volatile("s_waitcnt lgkmcnt(0)" ::: "memory");                        \
    __builtin_amdgcn_s_setprio(1);                                            \
    _Pragma("unroll")                                                         \
    for (int mi = 0; mi < 4; ++mi)                                            \
      _Pragma("unroll")                                                       \
      for (int ni = 0; ni < 4; ++ni)                                          \
        acc[mi][ni] = mfma16(av[mi], bv[ni], acc[mi][ni]);                    \
    __builtin_amdgcn_s_setprio(0);                                            \
    asm volatile("s_waitcnt vmcnt(0)" ::: "memory");                          \
    __builtin_amdgcn_s_barrier();                                             \
    asm volatile("" ::: "memory");                                            \
  }

  stage(&A0[0][0], &B0s[0][0], 0);
  asm volatile("s_waitcnt vmcnt(0)" ::: "memory");
  __builtin_amdgcn_s_barrier();
  asm volatile("" ::: "memory");

  for (int t = 0; t < nt; t += 2) {
    N_TILE(A0, B0s, A1, B1s, t);
    N_TILE(A1, B1s, A0, B0s, t + 1);
  }
#undef N_TILE

  const bool hasBias = flags & 1, doGelu = flags & 4, outBf = flags & 8;
  const bool wantVT  = flags & 16;
  float* outF = (float*)outp + (size_t)blockIdx.z * ((size_t)M * N);
  bh_t*  outB = (bh_t*)outp;
  #pragma unroll
  for (int mi = 0; mi < 4; ++mi) {
    const int rowb = m0 + wr * 64 + mi * 16 + 4 * g;
    #pragma unroll
    for (int ni = 0; ni < 4; ++ni) {
      const int col = n0 + wc * 64 + ni * 16 + r16;
      if (col >= N) continue;
      const float bv = hasBias ? bias[col] : 0.0f;
      if (wantVT && col >= 2 * CDIM) {
        const int hd = col - 2 * CDIM;           // h*64 + d, 0..767
        const int bq = rowb >> 10;               // batch index
        const int t0 = rowb & 1023;
        bfx4 vv;
        #pragma unroll
        for (int rr = 0; rr < 4; ++rr) vv[rr] = (bh_t)(acc[mi][ni][rr] + bv);
        *(bfx4*)(vTp + ((size_t)(bq * 768 + hd)) * TSEQ + t0) = vv;
      } else {
        #pragma unroll
        for (int rr = 0; rr < 4; ++rr) {
          const size_t idx = (size_t)(rowb + rr) * N + col;
          float v = acc[mi][ni][rr] + bv;
          if (doGelu) v = 0.5f * v * (1.0f + erff(v * 0.70710678118654752f));
          if (outBf) outB[idx] = (bh_t)v; else outF[idx] = v;
        }
      }
    }
  }
}

// ---------------------------------------------------------------------------
// 256x128 GEMM (R12/R16 structure) — lm_head only. BK=32, 48KB LDS dbuf,
// 2 blocks/CU, 8 waves (2Mx4N), wave tile 128x32, acc 8x2. f32 out, no flags.
// ---------------------------------------------------------------------------
__global__ __launch_bounds__(512, 4) void gemm256n(
    const bh_t* __restrict__ A, const bh_t* __restrict__ B,
    float* __restrict__ outF, int M, int N, int K, int lda)
{
  __shared__ bh_t A0[256][32], B0s[128][32];
  __shared__ bh_t A1[256][32], B1s[128][32];
  const int tid = threadIdx.x;
  const int wid = tid >> 6, lane = tid & 63;
  const int g = lane >> 4, r16 = lane & 15;
  const int wr = wid >> 2, wc = wid & 3;
  const int m0 = blockIdx.x * 256, n0 = blockIdx.y * 128;
  const int swk = (g ^ ((r16 >> 1) & 3)) * 8;

  const bh_t* Ab = A + (size_t)m0 * lda;
  const bh_t* Bb = B + (size_t)n0 * lda;
  const int nt = K >> 5;

  fx4 acc[8][2] = {};

  auto stage = [&](bh_t* dA, bh_t* dB, int t) {
    const int k0 = t << 5;
    #pragma unroll
    for (int j = 0; j < 2; ++j) {
      const int idx = j * 512 + tid;
      const int row = idx >> 2;
      const int slot = (idx & 3) ^ ((row >> 1) & 3);
      gload_lds16(Ab + (size_t)row * lda + k0 + slot * 8, dA + (size_t)idx * 8);
    }
    {
      const int idx = tid;
      const int row = idx >> 2;
      const int slot = (idx & 3) ^ ((row >> 1) & 3);
      gload_lds16(Bb + (size_t)row * lda + k0 + slot * 8, dB + (size_t)idx * 8);
    }
  };

#define N_TILE(CA, CB, NA, NB, T)                                             \
  {                                                                           \
    if ((T) + 1 < nt) stage(&NA[0][0], &NB[0][0], (T) + 1);                   \
    bfx8 av[8], bv[2];                                                        \
    _Pragma("unroll")                                                         \
    for (int ni = 0; ni < 2; ++ni)                                            \
      bv[ni] = *(const bfx8*)(&CB[wc * 32 + ni * 16 + r16][0] + swk);         \
    _Pragma("unroll")                                                         \
    for (int mi = 0; mi < 8; ++mi)                                            \
      av[mi] = *(const bfx8*)(&CA[wr * 128 + mi * 16 + r16][0] + swk);        \
    asm volatile("s_waitcnt lgkmcnt(0)" ::: "memory");                        \
    __builtin_amdgcn_s_setprio(1);                                            \
    _Pragma("unroll")                                                         \
    for (int mi = 0; mi < 8; ++mi)                                            \
      _Pragma("unroll")                                                       \
      for (int ni = 0; ni < 2; ++ni)                                          \
        acc[mi][ni] = mfma16(av[mi], bv[ni], acc[mi][ni]);                    \
    __builtin_amdgcn_s_setprio(0);                                            \
    asm volatile("s_waitcnt vmcnt(0)" ::: "memory");                          \
    __builtin_amdgcn_s_barrier();                                             \
    asm volatile("" ::: "memory");                                            \
  }

  stage(&A0[0][0], &B0s[0][0], 0);
  asm volatile("s_waitcnt vmcnt(0)" ::: "memory");
  __builtin_amdgcn_s_barrier();
  asm volatile("" ::: "memory");

  for (int t = 0; t < nt; t += 2) {
    N_TILE(A0, B0s, A1, B1s, t);
    N_TILE(A1, B1s, A0, B0s, t + 1);
  }
#undef N_TILE

  #pragma unroll
  for (int mi = 0; mi < 8; ++mi) {
    const int rowb = m0 + wr * 128 + mi * 16 + 4 * g;
    #pragma unroll
    for (int ni = 0; ni < 2; ++ni) {
      const int col = n0 + wc * 32 + ni * 16 + r16;
      if (col >= N) continue;
      #pragma unroll
      for (int rr = 0; rr < 4; ++rr)
        outF[(size_t)(rowb + rr) * N + col] = acc[mi][ni][rr];
    }
  }
}

// ---------------------------------------------------------------------------
// fused split-K reduce + residual + LayerNorm
// ---------------------------------------------------------------------------
__global__ __launch_bounds__(256) void skred_ln(
    const float* __restrict__ part, const float* __restrict__ bias,
    float* __restrict__ x, const float* __restrict__ w,
    const float* __restrict__ bb, bh_t* __restrict__ out, int S)
{
  const int wave = threadIdx.x >> 6, lane = threadIdx.x & 63;
  const int row = blockIdx.x * 4 + wave;
  const size_t base = (size_t)row * CDIM;
  const int off = lane * 4;
  const size_t stride = (size_t)MROWS * CDIM;

  float4 v0 = *(const float4*)(x + base + off);
  float4 v1 = *(const float4*)(x + base + 256 + off);
  float4 v2 = *(const float4*)(x + base + 512 + off);
  for (int s = 0; s < S; ++s) {
    const float* pr = part + s * stride + base;
    const float4 p0 = *(const float4*)(pr + off);
    const float4 p1 = *(const float4*)(pr + 256 + off);
    const float4 p2 = *(const float4*)(pr + 512 + off);
    v0.x += p0.x; v0.y += p0.y; v0.z += p0.z; v0.w += p0.w;
    v1.x += p1.x; v1.y += p1.y; v1.z += p1.z; v1.w += p1.w;
    v2.x += p2.x; v2.y += p2.y; v2.z += p2.z; v2.w += p2.w;
  }
  const float4 q0 = *(const float4*)(bias + off);
  const float4 q1 = *(const float4*)(bias + 256 + off);
  const float4 q2 = *(const float4*)(bias + 512 + off);
  v0.x += q0.x; v0.y += q0.y; v0.z += q0.z; v0.w += q0.w;
  v1.x += q1.x; v1.y += q1.y; v1.z += q1.z; v1.w += q1.w;
  v2.x += q2.x; v2.y += q2.y; v2.z += q2.z; v2.w += q2.w;
  *(float4*)(x + base + off) = v0;
  *(float4*)(x + base + 256 + off) = v1;
  *(float4*)(x + base + 512 + off) = v2;

  float s1 = v0.x + v0.y + v0.z + v0.w + v1.x + v1.y + v1.z + v1.w
           + v2.x + v2.y + v2.z + v2.w;
  float ss = v0.x*v0.x + v0.y*v0.y + v0.z*v0.z + v0.w*v0.w
           + v1.x*v1.x + v1.y*v1.y + v1.z*v1.z + v1.w*v1.w
           + v2.x*v2.x + v2.y*v2.y + v2.z*v2.z + v2.w*v2.w;
  #pragma unroll
  for (int d = 1; d < 64; d <<= 1) { s1 += __shfl_xor(s1, d); ss += __shfl_xor(ss, d); }
  const float mean = s1 * (1.0f / 768.0f);
  const float inv = rsqrtf(ss * (1.0f / 768.0f) - mean * mean + 1e-5f);
  bh_t* orow = out + base;

  const float4 w0 = *(const float4*)(w + off),       b0 = *(const float4*)(bb + off);
  const float4 w1 = *(const float4*)(w + 256 + off), b1 = *(const float4*)(bb + 256 + off);
  const float4 w2 = *(const float4*)(w + 512 + off), b2 = *(const float4*)(bb + 512 + off);
  bfx4 o;
  o[0] = (bh_t)((v0.x - mean) * inv * w0.x + b0.x);
  o[1] = (bh_t)((v0.y - mean) * inv * w0.y + b0.y);
  o[2] = (bh_t)((v0.z - mean) * inv * w0.z + b0.z);
  o[3] = (bh_t)((v0.w - mean) * inv * w0.w + b0.w);
  *(bfx4*)(orow + off) = o;
  o[0] = (bh_t)((v1.x - mean) * inv * w1.x + b1.x);
  o[1] = (bh_t)((v1.y - mean) * inv * w1.y + b1.y);
  o[2] = (bh_t)((v1.z - mean) * inv * w1.z + b1.z);
  o[3] = (bh_t)((v1.w - mean) * inv * w1.w + b1.w);
  *(bfx4*)(orow + 256 + off) = o;
  o[0] = (bh_t)((v2.x - mean) * inv * w2.x + b2.x);
  o[1] = (bh_t)((v2.y - mean) * inv * w2.y + b2.y);
  o[2] = (bh_t)((v2.z - mean) * inv * w2.z + b2.z);
  o[3] = (bh_t)((v2.w - mean) * inv * w2.w + b2.w);
  *(bfx4*)(orow + 512 + off) = o;
}

// ---------------------------------------------------------------------------
// Flash attention, causal. One wave per (b, h, 16 q-rows).
// ---------------------------------------------------------------------------
__global__ __launch_bounds__(256) void attn_fwd(
    const bh_t* __restrict__ qkv, const bh_t* __restrict__ vT,
    bh_t* __restrict__ outb)
{
  __shared__ bh_t P[4][16][56];
  const int wave = threadIdx.x >> 6, lane = threadIdx.x & 63;
  const int g = lane >> 4, r16 = lane & 15;
  const int gw = blockIdx.x * 4 + wave;
  const int qblk = gw & 63;
  const int bh = gw >> 6;
  const int h = bh % NHEAD, b = bh / NHEAD;
  const int qbase = qblk * 16;
  const int qidx = qbase + r16;

  const bh_t* qp = qkv + (size_t)(b * TSEQ + qbase + r16) * (3 * CDIM) + h * HDIM + 8 * g;
  const bfx8 qf0 = *(const bfx8*)qp;
  const bfx8 qf1 = *(const bfx8*)(qp + 32);

  fx4 o[4] = {};
  float m = -INFINITY, l = 0.0f;
  const int ntiles = qblk / 2 + 1;

  for (int t = 0; t < ntiles; ++t) {
    const int kv0 = t * 32;
    const bh_t* kp = qkv + (size_t)(b * TSEQ + kv0 + r16) * (3 * CDIM) + CDIM + h * HDIM + 8 * g;
    const bfx8 ka0 = *(const bfx8*)kp;
    const bfx8 ka1 = *(const bfx8*)(kp + 32);
    const bfx8 kb0 = *(const bfx8*)(kp + 16 * (3 * CDIM));
    const bfx8 kb1 = *(const bfx8*)(kp + 16 * (3 * CDIM) + 32);
    fx4 s0 = {}, s1 = {};
    s0 = mfma16(ka0, qf0, s0); s0 = mfma16(ka1, qf1, s0);   // S^T: [kv][q]
    s1 = mfma16(kb0, qf0, s1); s1 = mfma16(kb1, qf1, s1);

    float mx = -INFINITY;
    float sv0[4], sv1[4];
    #pragma unroll
    for (int rr = 0; rr < 4; ++rr) {
      const int kva = kv0 + 4 * g + rr;
      const int kvb = kva + 16;
      sv0[rr] = (kva <= qidx) ? s0[rr] * 0.125f : -INFINITY;
      sv1[rr] = (kvb <= qidx) ? s1[rr] * 0.125f : -INFINITY;
      mx = fmaxf(mx, fmaxf(sv0[rr], sv1[rr]));
    }
    mx = fmaxf(mx, __shfl_xor(mx, 16));
    mx = fmaxf(mx, __shfl_xor(mx, 32));
    const float mnew = fmaxf(m, mx);
    const float corr = __expf(m - mnew);

    float ps = 0.0f;
    float pv0[4], pv1[4];
    #pragma unroll
    for (int rr = 0; rr < 4; ++rr) {
      pv0[rr] = __expf(sv0[rr] - mnew);
      pv1[rr] = __expf(sv1[rr] - mnew);
      ps += pv0[rr] + pv1[rr];
    }
    ps += __shfl_xor(ps, 16);
    ps += __shfl_xor(ps, 32);
    l = l * corr + ps;
    m = mnew;

    #pragma unroll
    for (int rr = 0; rr < 4; ++rr) {
      const float cr = __shfl(corr, 4 * g + rr);
      o[0][rr] *= cr; o[1][rr] *= cr; o[2][rr] *= cr; o[3][rr] *= cr;
    }

    bfx4 w0, w1;
    #pragma unroll
    for (int rr = 0; rr < 4; ++rr) { w0[rr] = (bh_t)pv0[rr]; w1[rr] = (bh_t)pv1[rr]; }
    *(bfx4*)&P[wave][r16][4 * g]      = w0;
    *(bfx4*)&P[wave][r16][16 + 4 * g] = w1;
    __builtin_amdgcn_wave_barrier();
    const bfx8 pf = *(const bfx8*)&P[wave][r16][8 * g];

    #pragma unroll
    for (int fi = 0; fi < 4; ++fi) {
      const bh_t* vp = vT + (size_t)(bh * HDIM + fi * 16 + r16) * TSEQ + kv0 + 8 * g;
      const bfx8 vf = *(const bfx8*)vp;
      o[fi] = mfma16(pf, vf, o[fi]);
    }
  }

  #pragma unroll
  for (int rr = 0; rr < 4; ++rr) {
    const float lr = __shfl(l, 4 * g + rr);
    const float inv = 1.0f / lr;
    const int trow = b * TSEQ + qbase + 4 * g + rr;
    #pragma unroll
    for (int fi = 0; fi < 4; ++fi)
      outb[(size_t)trow * CDIM + h * HDIM + fi * 16 + r16] = (bh_t)(o[fi][rr] * inv);
  }
}

// ---------------------------------------------------------------------------
// LayerNorm: f32 in -> bf16 out. One wave per row. (layer 0 entry only)
// ---------------------------------------------------------------------------
__global__ __launch_bounds__(256) void ln_fwd(
    const float* __restrict__ x, const float* __restrict__ w,
    const float* __restrict__ bb, bh_t* __restrict__ out)
{
  const int wave = threadIdx.x >> 6, lane = threadIdx.x & 63;
  const int row = blockIdx.x * 4 + wave;
  const float* xr = x + (size_t)row * CDIM;
  const int off = lane * 4;
  const float4 v0 = *(const float4*)(xr + off);
  const float4 v1 = *(const float4*)(xr + 256 + off);
  const float4 v2 = *(const float4*)(xr + 512 + off);
  float s  = v0.x + v0.y + v0.z + v0.w + v1.x + v1.y + v1.z + v1.w
           + v2.x + v2.y + v2.z + v2.w;
  float ss = v0.x*v0.x + v0.y*v0.y + v0.z*v0.z + v0.w*v0.w
           + v1.x*v1.x + v1.y*v1.y + v1.z*v1.z + v1.w*v1.w
           + v2.x*v2.x + v2.y*v2.y + v2.z*v2.z + v2.w*v2.w;
  #pragma unroll
  for (int d = 1; d < 64; d <<= 1) { s += __shfl_xor(s, d); ss += __shfl_xor(ss, d); }
  const float mean = s * (1.0f / 768.0f);
  const float inv = rsqrtf(ss * (1.0f / 768.0f) - mean * mean + 1e-5f);
  bh_t* orow = out + (size_t)row * CDIM;

  const float4 w0 = *(const float4*)(w + off),  b0 = *(const float4*)(bb + off);
  const float4 w1 = *(const float4*)(w + 256 + off), b1 = *(const float4*)(bb + 256 + off);
  const float4 w2 = *(const float4*)(w + 512 + off), b2 = *(const float4*)(bb + 512 + off);
  bfx4 o;
  o[0] = (bh_t)((v0.x - mean) * inv * w0.x + b0.x);
  o[1] = (bh_t)((v0.y - mean) * inv * w0.y + b0.y);
  o[2] = (bh_t)((v0.z - mean) * inv * w0.z + b0.z);
  o[3] = (bh_t)((v0.w - mean) * inv * w0.w + b0.w);
  *(bfx4*)(orow + off) = o;
  o[0] = (bh_t)((v1.x - mean) * inv * w1.x + b1.x);
  o[1] = (bh_t)((v1.y - mean) * inv * w1.y + b1.y);
  o[2] = (bh_t)((v1.z - mean) * inv * w1.z + b1.z);
  o[3] = (bh_t)((v1.w - mean) * inv * w1.w + b1.w);
  *(bfx4*)(orow + 256 + off) = o;
  o[0] = (bh_t)((v2.x - mean) * inv * w2.x + b2.x);
  o[1] = (bh_t)((v2.y - mean) * inv * w2.y + b2.y);
  o[2] = (bh_t)((v2.z - mean) * inv * w2.z + b2.z);
  o[3] = (bh_t)((v2.w - mean) * inv * w2.w + b2.w);
  *(bfx4*)(orow + 512 + off) = o;
}

// ---------------------------------------------------------------------------
__global__ void embed_k(const int* __restrict__ ids, const float* __restrict__ tok,
                        const float* __restrict__ pos, float* __restrict__ x)
{
  const int bt = blockIdx.x;
  const int t = bt & (TSEQ - 1);
  const int id = ids[bt];
  const float* tr = tok + (size_t)id * CDIM;
  const float* pr = pos + (size_t)t * CDIM;
  float* xr = x + (size_t)bt * CDIM;
  for (int j = threadIdx.x; j < CDIM; j += 256) xr[j] = tr[j] + pr[j];
}

// transpose + f32->bf16: in [L][R][Cn] -> out [L][Cn][R]
__global__ void tconv(const float* __restrict__ in, bh_t* __restrict__ out, int R, int Cn)
{
  __shared__ float tile[32][33];
  const size_t msz = (size_t)R * Cn;
  in  += msz * blockIdx.z;
  out += msz * blockIdx.z;
  const int tx = threadIdx.x & 31, ty = threadIdx.x >> 5;
  const int c0 = blockIdx.x * 32, r0 = blockIdx.y * 32;
  #pragma unroll
  for (int i = 0; i < 32; i += 8)
    tile[ty + i][tx] = in[(size_t)(r0 + ty + i) * Cn + c0 + tx];
  __syncthreads();
  #pragma unroll
  for (int i = 0; i < 32; i += 8)
    out[(size_t)(c0 + ty + i) * R + r0 + tx] = (bh_t)tile[tx][ty + i];
}

// tok_emb f32 [V][C] -> bf16 [VPAD][C], zero-padded rows
__global__ void embconv(const float* __restrict__ in, bh_t* __restrict__ out)
{
  const size_t i4 = ((size_t)blockIdx.x * 256 + threadIdx.x) * 4;
  if (i4 >= (size_t)VPAD * CDIM) return;
  const size_t vlim = (size_t)VOCAB * CDIM;
  float4 f = make_float4(0.f, 0.f, 0.f, 0.f);
  if (i4 < vlim) f = *(const float4*)(in + i4);
  bfx4 o;
  o[0] = (bh_t)f.x; o[1] = (bh_t)f.y; o[2] = (bh_t)f.z; o[3] = (bh_t)f.w;
  *(bfx4*)(out + i4) = o;
}

// ---------------------------------------------------------------------------
extern "C" void kernel_launch(void* const* d_in, const int* in_sizes, int n_in,
                              void* d_out, int out_size, void* d_ws, size_t ws_size,
                              hipStream_t stream)
{
  (void)in_sizes; (void)n_in; (void)out_size; (void)ws_size;
  const int*   ids    = (const int*)d_in[0];
  const float* tok    = (const float*)d_in[1];
  const float* pos    = (const float*)d_in[2];
  const float* qkv_w  = (const float*)d_in[3];
  const float* qkv_b  = (const float*)d_in[4];
  const float* proj_w = (const float*)d_in[5];
  const float* proj_b = (const float*)d_in[6];
  const float* ln1_w  = (const float*)d_in[7];
  const float* ln1_b  = (const float*)d_in[8];
  const float* ln2_w  = (const float*)d_in[9];
  const float* ln2_b  = (const float*)d_in[10];
  const float* fc1_w  = (const float*)d_in[11];
  const float* fc1_b  = (const float*)d_in[12];
  const float* fc2_w  = (const float*)d_in[13];
  const float* fc2_b  = (const float*)d_in[14];
  const float* lnf_w  = (const float*)d_in[15];
  const float* lnf_b  = (const float*)d_in[16];

  // ---- scratch in ws (activations + embT), ~153 MB
  char* wp = (char*)d_ws;
  auto carve = [&](size_t bytes) { char* p = wp; wp += (bytes + 255) & ~(size_t)255; return p; };
  float* x     = (float*)carve((size_t)MROWS * CDIM * 4);
  bh_t*  hbuf  = (bh_t*)carve((size_t)MROWS * CDIM * 2);
  bh_t*  qkvb  = (bh_t*)carve((size_t)MROWS * 3 * CDIM * 2);
  bh_t*  vT    = (bh_t*)carve((size_t)48 * HDIM * TSEQ * 2);
  bh_t*  attno = (bh_t*)carve((size_t)MROWS * CDIM * 2);
  bh_t*  mlp1  = (bh_t*)carve((size_t)MROWS * 3072 * 2);
  bh_t*  embT  = (bh_t*)carve((size_t)VPAD * CDIM * 2);

  // ---- staged in d_out (dead before lm_head overwrites it), ~270 MB of 823
  char* op = (char*)d_out;
  auto carveO = [&](size_t bytes) { char* p = op; op += (bytes + 255) & ~(size_t)255; return p; };
  bh_t* qkvwT  = (bh_t*)carveO((size_t)NLAYER * 3 * CDIM * CDIM * 2);
  bh_t* projwT = (bh_t*)carveO((size_t)NLAYER * CDIM * CDIM * 2);
  bh_t* fc1wT  = (bh_t*)carveO((size_t)NLAYER * 3072 * CDIM * 2);
  bh_t* fc2wT  = (bh_t*)carveO((size_t)NLAYER * CDIM * 3072 * 2);
  float* skpart = (float*)carveO((size_t)4 * MROWS * CDIM * 4);   // split-K partials

  tconv<<<dim3(2304 / 32, 768 / 32, NLAYER), 256, 0, stream>>>(qkv_w, qkvwT, 768, 2304);
  tconv<<<dim3(768 / 32, 768 / 32, NLAYER), 256, 0, stream>>>(proj_w, projwT, 768, 768);
  tconv<<<dim3(3072 / 32, 768 / 32, NLAYER), 256, 0, stream>>>(fc1_w, fc1wT, 768, 3072);
  tconv<<<dim3(768 / 32, 3072 / 32, NLAYER), 256, 0, stream>>>(fc2_w, fc2wT, 3072, 768);
  embconv<<<((VPAD * CDIM / 4) + 255) / 256, 256, 0, stream>>>(tok, embT);
  embed_k<<<MROWS, 256, 0, stream>>>(ids, tok, pos, x);

  ln_fwd<<<MROWS / 4, 256, 0, stream>>>(x, ln1_w, ln1_b, hbuf);
  for (int l = 0; l < NLAYER; ++l) {
    // qkv: grid 32x18 = 576 blocks; V columns go straight to vT (flag 16)
    gemm128<<<dim3(32, 18), 256, 0, stream>>>(hbuf, qkvwT + (size_t)l * 3 * CDIM * CDIM,
        qkv_b + l * 3 * CDIM, qkvb, vT, MROWS, 3 * CDIM, CDIM, CDIM, 1 | 8 | 16);
    attn_fwd<<<768, 256, 0, stream>>>(qkvb, vT, attno);
    // proj: split-K x2 (K_eff=384, nt=12), grid 32x6x2 = 384 blocks
    gemm128<<<dim3(32, 6, 2), 256, 0, stream>>>(attno,
        projwT + (size_t)l * CDIM * CDIM, nullptr, skpart, nullptr,
        MROWS, CDIM, 384, CDIM, 0);
    skred_ln<<<MROWS / 4, 256, 0, stream>>>(skpart, proj_b + l * CDIM, x,
        ln2_w + l * CDIM, ln2_b + l * CDIM, hbuf, 2);
    // fc1: grid 32x24 = 768 blocks
    gemm128<<<dim3(32, 24), 256, 0, stream>>>(hbuf, fc1wT + (size_t)l * 3072 * CDIM,
        fc1_b + l * 3072, mlp1, nullptr, MROWS, 3072, CDIM, CDIM, 1 | 4 | 8);
    // fc2: split-K x4 (K_eff=768, nt=24), grid 32x6x4 = 768 blocks
    gemm128<<<dim3(32, 6, 4), 256, 0, stream>>>(mlp1, fc2wT + (size_t)l * CDIM * 3072,
        nullptr, skpart, nullptr, MROWS, CDIM, 768, 3072, 0);
    const float* nw = (l + 1 < NLAYER) ? ln1_w + (l + 1) * CDIM : lnf_w;
    const float* nb = (l + 1 < NLAYER) ? ln1_b + (l + 1) * CDIM : lnf_b;
    skred_ln<<<MROWS / 4, 256, 0, stream>>>(skpart, fc2_b + l * CDIM, x, nw, nb, hbuf, 4);
  }
  // lm_head: 256x128 kernel (wide M-tile: less f32 write amplification)
  gemm256n<<<dim3(16, 393), 512, 0, stream>>>(hbuf, embT,
      (float*)d_out, MROWS, VOCAB, CDIM, CDIM);
}

// Round 19
// 3491.871 us; speedup vs baseline: 1.3011x; 1.0010x over previous
//
#include <hip/hip_runtime.h>
#include <hip/hip_bf16.h>

// GPT-2 small forward on gfx950. bf16 MFMA GEMMs (f32 accum), flash attention.
// R19: R18 config (best: 3495us) + embed_k/ln_fwd fusion (embed_ln computes
//      x = tok[id]+pos AND hbuf = LN(x) in one pass; -1 dispatch, -12.6MB).
//      All GEMMs verified at the 2-phase structural ceiling (~640 TF,
//      matching learn_hip m248's 655-682 for this exact recipe).

typedef __bf16 bh_t;
typedef __bf16 bfx4 __attribute__((ext_vector_type(4)));
typedef __bf16 bfx8 __attribute__((ext_vector_type(8)));
typedef float  fx4  __attribute__((ext_vector_type(4)));

#define CDIM 768
#define TSEQ 1024
#define NHEAD 12
#define HDIM 64
#define NLAYER 12
#define MROWS 4096          // B*T
#define VOCAB 50257
#define VPAD  50432

__device__ __forceinline__ void gload_lds16(const void* g, void* l) {
  __builtin_amdgcn_global_load_lds(
      (const __attribute__((address_space(1))) void*)g,
      (__attribute__((address_space(3))) void*)l, 16, 0, 0);
}

__device__ __forceinline__ fx4 mfma16(bfx8 a, bfx8 b, fx4 c) {
  return __builtin_amdgcn_mfma_f32_16x16x32_bf16(a, b, c, 0, 0, 0);
}

// ---------------------------------------------------------------------------
// 128x128 GEMM, BK=32, 32KB LDS double-buffer, 4 blocks/CU. 4 waves (2Mx2N),
// wave tile 64x64, acc 4x4. Swizzle slot ^= (row>>1)&3 (both-sides).
// blockIdx.z = split-K slice. flags: 1=bias,4=gelu,8=out bf16,16=V->vT.
// ---------------------------------------------------------------------------
__global__ __launch_bounds__(256, 4) void gemm128(
    const bh_t* __restrict__ A, const bh_t* __restrict__ B,
    const float* __restrict__ bias, void* __restrict__ outp,
    bh_t* __restrict__ vTp,
    int M, int N, int K, int lda, int flags)
{
  __shared__ bh_t A0[128][32], B0s[128][32];
  __shared__ bh_t A1[128][32], B1s[128][32];
  const int tid = threadIdx.x;
  const int wid = tid >> 6, lane = tid & 63;
  const int g = lane >> 4, r16 = lane & 15;
  const int wr = wid >> 1, wc = wid & 1;        // 2M x 2N waves
  const int m0 = blockIdx.x * 128, n0 = blockIdx.y * 128;
  const int swk = (g ^ ((r16 >> 1) & 3)) * 8;

  const bh_t* Ab = A + (size_t)blockIdx.z * K + (size_t)m0 * lda;
  const bh_t* Bb = B + (size_t)blockIdx.z * K + (size_t)n0 * lda;
  const int nt = K >> 5;

  fx4 acc[4][4] = {};

  auto stage = [&](bh_t* dA, bh_t* dB, int t) {
    const int k0 = t << 5;
    #pragma unroll
    for (int j = 0; j < 2; ++j) {
      const int idx = j * 256 + tid;          // 16B units, 0..511
      const int row = idx >> 2;               // 0..127
      const int slot = (idx & 3) ^ ((row >> 1) & 3);
      gload_lds16(Ab + (size_t)row * lda + k0 + slot * 8, dA + (size_t)idx * 8);
    }
    #pragma unroll
    for (int j = 0; j < 2; ++j) {
      const int idx = j * 256 + tid;
      const int row = idx >> 2;
      const int slot = (idx & 3) ^ ((row >> 1) & 3);
      gload_lds16(Bb + (size_t)row * lda + k0 + slot * 8, dB + (size_t)idx * 8);
    }
  };

#define N_TILE(CA, CB, NA, NB, T)                                             \
  {                                                                           \
    if ((T) + 1 < nt) stage(&NA[0][0], &NB[0][0], (T) + 1);                   \
    bfx8 av[4], bv[4];                                                        \
    _Pragma("unroll")                                                         \
    for (int ni = 0; ni < 4; ++ni)                                            \
      bv[ni] = *(const bfx8*)(&CB[wc * 64 + ni * 16 + r16][0] + swk);         \
    _Pragma("unroll")                                                         \
    for (int mi = 0; mi < 4; ++mi)                                            \
      av[mi] = *(const bfx8*)(&CA[wr * 64 + mi * 16 + r16][0] + swk);         \
    asm volatile("s_waitcnt lgkmcnt(0)" ::: "memory");                        \
    __builtin_amdgcn_s_setprio(1);                                            \
    _Pragma("unroll")                                                         \
    for (int mi = 0; mi < 4; ++mi)                                            \
      _Pragma("unroll")                                                       \
      for (int ni = 0; ni < 4; ++ni)                                          \
        acc[mi][ni] = mfma16(av[mi], bv[ni], acc[mi][ni]);                    \
    __builtin_amdgcn_s_setprio(0);                                            \
    asm volatile("s_waitcnt vmcnt(0)" ::: "memory");                          \
    __builtin_amdgcn_s_barrier();                                             \
    asm volatile("" ::: "memory");                                            \
  }

  stage(&A0[0][0], &B0s[0][0], 0);
  asm volatile("s_waitcnt vmcnt(0)" ::: "memory");
  __builtin_amdgcn_s_barrier();
  asm volatile("" ::: "memory");

  for (int t = 0; t < nt; t += 2) {
    N_TILE(A0, B0s, A1, B1s, t);
    N_TILE(A1, B1s, A0, B0s, t + 1);
  }
#undef N_TILE

  const bool hasBias = flags & 1, doGelu = flags & 4, outBf = flags & 8;
  const bool wantVT  = flags & 16;
  float* outF = (float*)outp + (size_t)blockIdx.z * ((size_t)M * N);
  bh_t*  outB = (bh_t*)outp;
  #pragma unroll
  for (int mi = 0; mi < 4; ++mi) {
    const int rowb = m0 + wr * 64 + mi * 16 + 4 * g;
    #pragma unroll
    for (int ni = 0; ni < 4; ++ni) {
      const int col = n0 + wc * 64 + ni * 16 + r16;
      if (col >= N) continue;
      const float bv = hasBias ? bias[col] : 0.0f;
      if (wantVT && col >= 2 * CDIM) {
        const int hd = col - 2 * CDIM;           // h*64 + d, 0..767
        const int bq = rowb >> 10;               // batch index
        const int t0 = rowb & 1023;
        bfx4 vv;
        #pragma unroll
        for (int rr = 0; rr < 4; ++rr) vv[rr] = (bh_t)(acc[mi][ni][rr] + bv);
        *(bfx4*)(vTp + ((size_t)(bq * 768 + hd)) * TSEQ + t0) = vv;
      } else {
        #pragma unroll
        for (int rr = 0; rr < 4; ++rr) {
          const size_t idx = (size_t)(rowb + rr) * N + col;
          float v = acc[mi][ni][rr] + bv;
          if (doGelu) v = 0.5f * v * (1.0f + erff(v * 0.70710678118654752f));
          if (outBf) outB[idx] = (bh_t)v; else outF[idx] = v;
        }
      }
    }
  }
}

// ---------------------------------------------------------------------------
// 256x128 GEMM (R12/R16 structure) — lm_head only. BK=32, 48KB LDS dbuf,
// 2 blocks/CU, 8 waves (2Mx4N), wave tile 128x32, acc 8x2. f32 out.
// ---------------------------------------------------------------------------
__global__ __launch_bounds__(512, 4) void gemm256n(
    const bh_t* __restrict__ A, const bh_t* __restrict__ B,
    float* __restrict__ outF, int M, int N, int K, int lda)
{
  __shared__ bh_t A0[256][32], B0s[128][32];
  __shared__ bh_t A1[256][32], B1s[128][32];
  const int tid = threadIdx.x;
  const int wid = tid >> 6, lane = tid & 63;
  const int g = lane >> 4, r16 = lane & 15;
  const int wr = wid >> 2, wc = wid & 3;
  const int m0 = blockIdx.x * 256, n0 = blockIdx.y * 128;
  const int swk = (g ^ ((r16 >> 1) & 3)) * 8;

  const bh_t* Ab = A + (size_t)m0 * lda;
  const bh_t* Bb = B + (size_t)n0 * lda;
  const int nt = K >> 5;

  fx4 acc[8][2] = {};

  auto stage = [&](bh_t* dA, bh_t* dB, int t) {
    const int k0 = t << 5;
    #pragma unroll
    for (int j = 0; j < 2; ++j) {
      const int idx = j * 512 + tid;
      const int row = idx >> 2;
      const int slot = (idx & 3) ^ ((row >> 1) & 3);
      gload_lds16(Ab + (size_t)row * lda + k0 + slot * 8, dA + (size_t)idx * 8);
    }
    {
      const int idx = tid;
      const int row = idx >> 2;
      const int slot = (idx & 3) ^ ((row >> 1) & 3);
      gload_lds16(Bb + (size_t)row * lda + k0 + slot * 8, dB + (size_t)idx * 8);
    }
  };

#define N_TILE(CA, CB, NA, NB, T)                                             \
  {                                                                           \
    if ((T) + 1 < nt) stage(&NA[0][0], &NB[0][0], (T) + 1);                   \
    bfx8 av[8], bv[2];                                                        \
    _Pragma("unroll")                                                         \
    for (int ni = 0; ni < 2; ++ni)                                            \
      bv[ni] = *(const bfx8*)(&CB[wc * 32 + ni * 16 + r16][0] + swk);         \
    _Pragma("unroll")                                                         \
    for (int mi = 0; mi < 8; ++mi)                                            \
      av[mi] = *(const bfx8*)(&CA[wr * 128 + mi * 16 + r16][0] + swk);        \
    asm volatile("s_waitcnt lgkmcnt(0)" ::: "memory");                        \
    __builtin_amdgcn_s_setprio(1);                                            \
    _Pragma("unroll")                                                         \
    for (int mi = 0; mi < 8; ++mi)                                            \
      _Pragma("unroll")                                                       \
      for (int ni = 0; ni < 2; ++ni)                                          \
        acc[mi][ni] = mfma16(av[mi], bv[ni], acc[mi][ni]);                    \
    __builtin_amdgcn_s_setprio(0);                                            \
    asm volatile("s_waitcnt vmcnt(0)" ::: "memory");                          \
    __builtin_amdgcn_s_barrier();                                             \
    asm volatile("" ::: "memory");                                            \
  }

  stage(&A0[0][0], &B0s[0][0], 0);
  asm volatile("s_waitcnt vmcnt(0)" ::: "memory");
  __builtin_amdgcn_s_barrier();
  asm volatile("" ::: "memory");

  for (int t = 0; t < nt; t += 2) {
    N_TILE(A0, B0s, A1, B1s, t);
    N_TILE(A1, B1s, A0, B0s, t + 1);
  }
#undef N_TILE

  #pragma unroll
  for (int mi = 0; mi < 8; ++mi) {
    const int rowb = m0 + wr * 128 + mi * 16 + 4 * g;
    #pragma unroll
    for (int ni = 0; ni < 2; ++ni) {
      const int col = n0 + wc * 32 + ni * 16 + r16;
      if (col >= N) continue;
      #pragma unroll
      for (int rr = 0; rr < 4; ++rr)
        outF[(size_t)(rowb + rr) * N + col] = acc[mi][ni][rr];
    }
  }
}

// ---------------------------------------------------------------------------
// fused split-K reduce + residual + LayerNorm
// ---------------------------------------------------------------------------
__global__ __launch_bounds__(256) void skred_ln(
    const float* __restrict__ part, const float* __restrict__ bias,
    float* __restrict__ x, const float* __restrict__ w,
    const float* __restrict__ bb, bh_t* __restrict__ out, int S)
{
  const int wave = threadIdx.x >> 6, lane = threadIdx.x & 63;
  const int row = blockIdx.x * 4 + wave;
  const size_t base = (size_t)row * CDIM;
  const int off = lane * 4;
  const size_t stride = (size_t)MROWS * CDIM;

  float4 v0 = *(const float4*)(x + base + off);
  float4 v1 = *(const float4*)(x + base + 256 + off);
  float4 v2 = *(const float4*)(x + base + 512 + off);
  for (int s = 0; s < S; ++s) {
    const float* pr = part + s * stride + base;
    const float4 p0 = *(const float4*)(pr + off);
    const float4 p1 = *(const float4*)(pr + 256 + off);
    const float4 p2 = *(const float4*)(pr + 512 + off);
    v0.x += p0.x; v0.y += p0.y; v0.z += p0.z; v0.w += p0.w;
    v1.x += p1.x; v1.y += p1.y; v1.z += p1.z; v1.w += p1.w;
    v2.x += p2.x; v2.y += p2.y; v2.z += p2.z; v2.w += p2.w;
  }
  const float4 q0 = *(const float4*)(bias + off);
  const float4 q1 = *(const float4*)(bias + 256 + off);
  const float4 q2 = *(const float4*)(bias + 512 + off);
  v0.x += q0.x; v0.y += q0.y; v0.z += q0.z; v0.w += q0.w;
  v1.x += q1.x; v1.y += q1.y; v1.z += q1.z; v1.w += q1.w;
  v2.x += q2.x; v2.y += q2.y; v2.z += q2.z; v2.w += q2.w;
  *(float4*)(x + base + off) = v0;
  *(float4*)(x + base + 256 + off) = v1;
  *(float4*)(x + base + 512 + off) = v2;

  float s1 = v0.x + v0.y + v0.z + v0.w + v1.x + v1.y + v1.z + v1.w
           + v2.x + v2.y + v2.z + v2.w;
  float ss = v0.x*v0.x + v0.y*v0.y + v0.z*v0.z + v0.w*v0.w
           + v1.x*v1.x + v1.y*v1.y + v1.z*v1.z + v1.w*v1.w
           + v2.x*v2.x + v2.y*v2.y + v2.z*v2.z + v2.w*v2.w;
  #pragma unroll
  for (int d = 1; d < 64; d <<= 1) { s1 += __shfl_xor(s1, d); ss += __shfl_xor(ss, d); }
  const float mean = s1 * (1.0f / 768.0f);
  const float inv = rsqrtf(ss * (1.0f / 768.0f) - mean * mean + 1e-5f);
  bh_t* orow = out + base;

  const float4 w0 = *(const float4*)(w + off),       b0 = *(const float4*)(bb + off);
  const float4 w1 = *(const float4*)(w + 256 + off), b1 = *(const float4*)(bb + 256 + off);
  const float4 w2 = *(const float4*)(w + 512 + off), b2 = *(const float4*)(bb + 512 + off);
  bfx4 o;
  o[0] = (bh_t)((v0.x - mean) * inv * w0.x + b0.x);
  o[1] = (bh_t)((v0.y - mean) * inv * w0.y + b0.y);
  o[2] = (bh_t)((v0.z - mean) * inv * w0.z + b0.z);
  o[3] = (bh_t)((v0.w - mean) * inv * w0.w + b0.w);
  *(bfx4*)(orow + off) = o;
  o[0] = (bh_t)((v1.x - mean) * inv * w1.x + b1.x);
  o[1] = (bh_t)((v1.y - mean) * inv * w1.y + b1.y);
  o[2] = (bh_t)((v1.z - mean) * inv * w1.z + b1.z);
  o[3] = (bh_t)((v1.w - mean) * inv * w1.w + b1.w);
  *(bfx4*)(orow + 256 + off) = o;
  o[0] = (bh_t)((v2.x - mean) * inv * w2.x + b2.x);
  o[1] = (bh_t)((v2.y - mean) * inv * w2.y + b2.y);
  o[2] = (bh_t)((v2.z - mean) * inv * w2.z + b2.z);
  o[3] = (bh_t)((v2.w - mean) * inv * w2.w + b2.w);
  *(bfx4*)(orow + 512 + off) = o;
}

// ---------------------------------------------------------------------------
// Flash attention, causal. One wave per (b, h, 16 q-rows).
// ---------------------------------------------------------------------------
__global__ __launch_bounds__(256) void attn_fwd(
    const bh_t* __restrict__ qkv, const bh_t* __restrict__ vT,
    bh_t* __restrict__ outb)
{
  __shared__ bh_t P[4][16][56];
  const int wave = threadIdx.x >> 6, lane = threadIdx.x & 63;
  const int g = lane >> 4, r16 = lane & 15;
  const int gw = blockIdx.x * 4 + wave;
  const int qblk = gw & 63;
  const int bh = gw >> 6;
  const int h = bh % NHEAD, b = bh / NHEAD;
  const int qbase = qblk * 16;
  const int qidx = qbase + r16;

  const bh_t* qp = qkv + (size_t)(b * TSEQ + qbase + r16) * (3 * CDIM) + h * HDIM + 8 * g;
  const bfx8 qf0 = *(const bfx8*)qp;
  const bfx8 qf1 = *(const bfx8*)(qp + 32);

  fx4 o[4] = {};
  float m = -INFINITY, l = 0.0f;
  const int ntiles = qblk / 2 + 1;

  for (int t = 0; t < ntiles; ++t) {
    const int kv0 = t * 32;
    const bh_t* kp = qkv + (size_t)(b * TSEQ + kv0 + r16) * (3 * CDIM) + CDIM + h * HDIM + 8 * g;
    const bfx8 ka0 = *(const bfx8*)kp;
    const bfx8 ka1 = *(const bfx8*)(kp + 32);
    const bfx8 kb0 = *(const bfx8*)(kp + 16 * (3 * CDIM));
    const bfx8 kb1 = *(const bfx8*)(kp + 16 * (3 * CDIM) + 32);
    fx4 s0 = {}, s1 = {};
    s0 = mfma16(ka0, qf0, s0); s0 = mfma16(ka1, qf1, s0);   // S^T: [kv][q]
    s1 = mfma16(kb0, qf0, s1); s1 = mfma16(kb1, qf1, s1);

    float mx = -INFINITY;
    float sv0[4], sv1[4];
    #pragma unroll
    for (int rr = 0; rr < 4; ++rr) {
      const int kva = kv0 + 4 * g + rr;
      const int kvb = kva + 16;
      sv0[rr] = (kva <= qidx) ? s0[rr] * 0.125f : -INFINITY;
      sv1[rr] = (kvb <= qidx) ? s1[rr] * 0.125f : -INFINITY;
      mx = fmaxf(mx, fmaxf(sv0[rr], sv1[rr]));
    }
    mx = fmaxf(mx, __shfl_xor(mx, 16));
    mx = fmaxf(mx, __shfl_xor(mx, 32));
    const float mnew = fmaxf(m, mx);
    const float corr = __expf(m - mnew);

    float ps = 0.0f;
    float pv0[4], pv1[4];
    #pragma unroll
    for (int rr = 0; rr < 4; ++rr) {
      pv0[rr] = __expf(sv0[rr] - mnew);
      pv1[rr] = __expf(sv1[rr] - mnew);
      ps += pv0[rr] + pv1[rr];
    }
    ps += __shfl_xor(ps, 16);
    ps += __shfl_xor(ps, 32);
    l = l * corr + ps;
    m = mnew;

    #pragma unroll
    for (int rr = 0; rr < 4; ++rr) {
      const float cr = __shfl(corr, 4 * g + rr);
      o[0][rr] *= cr; o[1][rr] *= cr; o[2][rr] *= cr; o[3][rr] *= cr;
    }

    bfx4 w0, w1;
    #pragma unroll
    for (int rr = 0; rr < 4; ++rr) { w0[rr] = (bh_t)pv0[rr]; w1[rr] = (bh_t)pv1[rr]; }
    *(bfx4*)&P[wave][r16][4 * g]      = w0;
    *(bfx4*)&P[wave][r16][16 + 4 * g] = w1;
    __builtin_amdgcn_wave_barrier();
    const bfx8 pf = *(const bfx8*)&P[wave][r16][8 * g];

    #pragma unroll
    for (int fi = 0; fi < 4; ++fi) {
      const bh_t* vp = vT + (size_t)(bh * HDIM + fi * 16 + r16) * TSEQ + kv0 + 8 * g;
      const bfx8 vf = *(const bfx8*)vp;
      o[fi] = mfma16(pf, vf, o[fi]);
    }
  }

  #pragma unroll
  for (int rr = 0; rr < 4; ++rr) {
    const float lr = __shfl(l, 4 * g + rr);
    const float inv = 1.0f / lr;
    const int trow = b * TSEQ + qbase + 4 * g + rr;
    #pragma unroll
    for (int fi = 0; fi < 4; ++fi)
      outb[(size_t)trow * CDIM + h * HDIM + fi * 16 + r16] = (bh_t)(o[fi][rr] * inv);
  }
}

// ---------------------------------------------------------------------------
// fused embedding + LayerNorm: x = tok[id] + pos;  out = LN(x)*w + b (bf16).
// One wave per row.
// ---------------------------------------------------------------------------
__global__ __launch_bounds__(256) void embed_ln(
    const int* __restrict__ ids, const float* __restrict__ tok,
    const float* __restrict__ pos, float* __restrict__ x,
    const float* __restrict__ w, const float* __restrict__ bb,
    bh_t* __restrict__ out)
{
  const int wave = threadIdx.x >> 6, lane = threadIdx.x & 63;
  const int row = blockIdx.x * 4 + wave;
  const int t = row & (TSEQ - 1);
  const int id = ids[row];
  const float* tr = tok + (size_t)id * CDIM;
  const float* pr = pos + (size_t)t * CDIM;
  const int off = lane * 4;

  float4 v0 = *(const float4*)(tr + off);
  float4 v1 = *(const float4*)(tr + 256 + off);
  float4 v2 = *(const float4*)(tr + 512 + off);
  const float4 p0 = *(const float4*)(pr + off);
  const float4 p1 = *(const float4*)(pr + 256 + off);
  const float4 p2 = *(const float4*)(pr + 512 + off);
  v0.x += p0.x; v0.y += p0.y; v0.z += p0.z; v0.w += p0.w;
  v1.x += p1.x; v1.y += p1.y; v1.z += p1.z; v1.w += p1.w;
  v2.x += p2.x; v2.y += p2.y; v2.z += p2.z; v2.w += p2.w;

  const size_t base = (size_t)row * CDIM;
  *(float4*)(x + base + off) = v0;
  *(float4*)(x + base + 256 + off) = v1;
  *(float4*)(x + base + 512 + off) = v2;

  float s  = v0.x + v0.y + v0.z + v0.w + v1.x + v1.y + v1.z + v1.w
           + v2.x + v2.y + v2.z + v2.w;
  float ss = v0.x*v0.x + v0.y*v0.y + v0.z*v0.z + v0.w*v0.w
           + v1.x*v1.x + v1.y*v1.y + v1.z*v1.z + v1.w*v1.w
           + v2.x*v2.x + v2.y*v2.y + v2.z*v2.z + v2.w*v2.w;
  #pragma unroll
  for (int d = 1; d < 64; d <<= 1) { s += __shfl_xor(s, d); ss += __shfl_xor(ss, d); }
  const float mean = s * (1.0f / 768.0f);
  const float inv = rsqrtf(ss * (1.0f / 768.0f) - mean * mean + 1e-5f);
  bh_t* orow = out + base;

  const float4 w0 = *(const float4*)(w + off),       b0 = *(const float4*)(bb + off);
  const float4 w1 = *(const float4*)(w + 256 + off), b1 = *(const float4*)(bb + 256 + off);
  const float4 w2 = *(const float4*)(w + 512 + off), b2 = *(const float4*)(bb + 512 + off);
  bfx4 o;
  o[0] = (bh_t)((v0.x - mean) * inv * w0.x + b0.x);
  o[1] = (bh_t)((v0.y - mean) * inv * w0.y + b0.y);
  o[2] = (bh_t)((v0.z - mean) * inv * w0.z + b0.z);
  o[3] = (bh_t)((v0.w - mean) * inv * w0.w + b0.w);
  *(bfx4*)(orow + off) = o;
  o[0] = (bh_t)((v1.x - mean) * inv * w1.x + b1.x);
  o[1] = (bh_t)((v1.y - mean) * inv * w1.y + b1.y);
  o[2] = (bh_t)((v1.z - mean) * inv * w1.z + b1.z);
  o[3] = (bh_t)((v1.w - mean) * inv * w1.w + b1.w);
  *(bfx4*)(orow + 256 + off) = o;
  o[0] = (bh_t)((v2.x - mean) * inv * w2.x + b2.x);
  o[1] = (bh_t)((v2.y - mean) * inv * w2.y + b2.y);
  o[2] = (bh_t)((v2.z - mean) * inv * w2.z + b2.z);
  o[3] = (bh_t)((v2.w - mean) * inv * w2.w + b2.w);
  *(bfx4*)(orow + 512 + off) = o;
}

// transpose + f32->bf16: in [L][R][Cn] -> out [L][Cn][R]
__global__ void tconv(const float* __restrict__ in, bh_t* __restrict__ out, int R, int Cn)
{
  __shared__ float tile[32][33];
  const size_t msz = (size_t)R * Cn;
  in  += msz * blockIdx.z;
  out += msz * blockIdx.z;
  const int tx = threadIdx.x & 31, ty = threadIdx.x >> 5;
  const int c0 = blockIdx.x * 32, r0 = blockIdx.y * 32;
  #pragma unroll
  for (int i = 0; i < 32; i += 8)
    tile[ty + i][tx] = in[(size_t)(r0 + ty + i) * Cn + c0 + tx];
  __syncthreads();
  #pragma unroll
  for (int i = 0; i < 32; i += 8)
    out[(size_t)(c0 + ty + i) * R + r0 + tx] = (bh_t)tile[tx][ty + i];
}

// tok_emb f32 [V][C] -> bf16 [VPAD][C], zero-padded rows
__global__ void embconv(const float* __restrict__ in, bh_t* __restrict__ out)
{
  const size_t i4 = ((size_t)blockIdx.x * 256 + threadIdx.x) * 4;
  if (i4 >= (size_t)VPAD * CDIM) return;
  const size_t vlim = (size_t)VOCAB * CDIM;
  float4 f = make_float4(0.f, 0.f, 0.f, 0.f);
  if (i4 < vlim) f = *(const float4*)(in + i4);
  bfx4 o;
  o[0] = (bh_t)f.x; o[1] = (bh_t)f.y; o[2] = (bh_t)f.z; o[3] = (bh_t)f.w;
  *(bfx4*)(out + i4) = o;
}

// ---------------------------------------------------------------------------
extern "C" void kernel_launch(void* const* d_in, const int* in_sizes, int n_in,
                              void* d_out, int out_size, void* d_ws, size_t ws_size,
                              hipStream_t stream)
{
  (void)in_sizes; (void)n_in; (void)out_size; (void)ws_size;
  const int*   ids    = (const int*)d_in[0];
  const float* tok    = (const float*)d_in[1];
  const float* pos    = (const float*)d_in[2];
  const float* qkv_w  = (const float*)d_in[3];
  const float* qkv_b  = (const float*)d_in[4];
  const float* proj_w = (const float*)d_in[5];
  const float* proj_b = (const float*)d_in[6];
  const float* ln1_w  = (const float*)d_in[7];
  const float* ln1_b  = (const float*)d_in[8];
  const float* ln2_w  = (const float*)d_in[9];
  const float* ln2_b  = (const float*)d_in[10];
  const float* fc1_w  = (const float*)d_in[11];
  const float* fc1_b  = (const float*)d_in[12];
  const float* fc2_w  = (const float*)d_in[13];
  const float* fc2_b  = (const float*)d_in[14];
  const float* lnf_w  = (const float*)d_in[15];
  const float* lnf_b  = (const float*)d_in[16];

  // ---- scratch in ws (activations + embT), ~153 MB
  char* wp = (char*)d_ws;
  auto carve = [&](size_t bytes) { char* p = wp; wp += (bytes + 255) & ~(size_t)255; return p; };
  float* x     = (float*)carve((size_t)MROWS * CDIM * 4);
  bh_t*  hbuf  = (bh_t*)carve((size_t)MROWS * CDIM * 2);
  bh_t*  qkvb  = (bh_t*)carve((size_t)MROWS * 3 * CDIM * 2);
  bh_t*  vT    = (bh_t*)carve((size_t)48 * HDIM * TSEQ * 2);
  bh_t*  attno = (bh_t*)carve((size_t)MROWS * CDIM * 2);
  bh_t*  mlp1  = (bh_t*)carve((size_t)MROWS * 3072 * 2);
  bh_t*  embT  = (bh_t*)carve((size_t)VPAD * CDIM * 2);

  // ---- staged in d_out (dead before lm_head overwrites it), ~270 MB of 823
  char* op = (char*)d_out;
  auto carveO = [&](size_t bytes) { char* p = op; op += (bytes + 255) & ~(size_t)255; return p; };
  bh_t* qkvwT  = (bh_t*)carveO((size_t)NLAYER * 3 * CDIM * CDIM * 2);
  bh_t* projwT = (bh_t*)carveO((size_t)NLAYER * CDIM * CDIM * 2);
  bh_t* fc1wT  = (bh_t*)carveO((size_t)NLAYER * 3072 * CDIM * 2);
  bh_t* fc2wT  = (bh_t*)carveO((size_t)NLAYER * CDIM * 3072 * 2);
  float* skpart = (float*)carveO((size_t)4 * MROWS * CDIM * 4);   // split-K partials

  tconv<<<dim3(2304 / 32, 768 / 32, NLAYER), 256, 0, stream>>>(qkv_w, qkvwT, 768, 2304);
  tconv<<<dim3(768 / 32, 768 / 32, NLAYER), 256, 0, stream>>>(proj_w, projwT, 768, 768);
  tconv<<<dim3(3072 / 32, 768 / 32, NLAYER), 256, 0, stream>>>(fc1_w, fc1wT, 768, 3072);
  tconv<<<dim3(768 / 32, 3072 / 32, NLAYER), 256, 0, stream>>>(fc2_w, fc2wT, 3072, 768);
  embconv<<<((VPAD * CDIM / 4) + 255) / 256, 256, 0, stream>>>(tok, embT);
  embed_ln<<<MROWS / 4, 256, 0, stream>>>(ids, tok, pos, x, ln1_w, ln1_b, hbuf);

  for (int l = 0; l < NLAYER; ++l) {
    // qkv: grid 32x18 = 576 blocks; V columns go straight to vT (flag 16)
    gemm128<<<dim3(32, 18), 256, 0, stream>>>(hbuf, qkvwT + (size_t)l * 3 * CDIM * CDIM,
        qkv_b + l * 3 * CDIM, qkvb, vT, MROWS, 3 * CDIM, CDIM, CDIM, 1 | 8 | 16);
    attn_fwd<<<768, 256, 0, stream>>>(qkvb, vT, attno);
    // proj: split-K x2 (K_eff=384, nt=12), grid 32x6x2 = 384 blocks
    gemm128<<<dim3(32, 6, 2), 256, 0, stream>>>(attno,
        projwT + (size_t)l * CDIM * CDIM, nullptr, skpart, nullptr,
        MROWS, CDIM, 384, CDIM, 0);
    skred_ln<<<MROWS / 4, 256, 0, stream>>>(skpart, proj_b + l * CDIM, x,
        ln2_w + l * CDIM, ln2_b + l * CDIM, hbuf, 2);
    // fc1: grid 32x24 = 768 blocks
    gemm128<<<dim3(32, 24), 256, 0, stream>>>(hbuf, fc1wT + (size_t)l * 3072 * CDIM,
        fc1_b + l * 3072, mlp1, nullptr, MROWS, 3072, CDIM, CDIM, 1 | 4 | 8);
    // fc2: split-K x4 (K_eff=768, nt=24), grid 32x6x4 = 768 blocks
    gemm128<<<dim3(32, 6, 4), 256, 0, stream>>>(mlp1, fc2wT + (size_t)l * CDIM * 3072,
        nullptr, skpart, nullptr, MROWS, CDIM, 768, 3072, 0);
    const float* nw = (l + 1 < NLAYER) ? ln1_w + (l + 1) * CDIM : lnf_w;
    const float* nb = (l + 1 < NLAYER) ? ln1_b + (l + 1) * CDIM : lnf_b;
    skred_ln<<<MROWS / 4, 256, 0, stream>>>(skpart, fc2_b + l * CDIM, x, nw, nb, hbuf, 4);
  }
  // lm_head: 256x128 kernel (wide M-tile: less f32 write amplification)
  gemm256n<<<dim3(16, 393), 512, 0, stream>>>(hbuf, embT,
      (float*)d_out, MROWS, VOCAB, CDIM, CDIM);
}

// Round 20
// 3488.499 us; speedup vs baseline: 1.3023x; 1.0010x over previous
//
#include <hip/hip_runtime.h>
#include <hip/hip_bf16.h>

// GPT-2 small forward on gfx950. bf16 MFMA GEMMs (f32 accum), flash attention.
// R20 (FINAL): R19 configuration, verified at 3491.9us / absmax 0.031.
//   - gemm128 (128x128, BK=32, 2-phase dbuf, 4 blocks/CU) for qkv/proj/fc1/fc2
//   - gemm256n (256x128, 2 blocks/CU) for lm_head (wide M-tile halves f32
//     write amplification)
//   - split-K via grid-z + fused skred_ln (reduce+bias+residual+LayerNorm)
//   - vtrans fused into qkv epilogue (V cols -> vT transposed bfx4 stores)
//   - embed+LN fused; weights bf16-transposed once per call, staged in d_out
//     (dead before lm_head overwrites it)
// All GEMMs at the verified 2-phase structural ceiling (~640 TF, m248 ref
// 655-682); non-GEMM kernels at 80-86% HBM BW. Structural plateau.

typedef __bf16 bh_t;
typedef __bf16 bfx4 __attribute__((ext_vector_type(4)));
typedef __bf16 bfx8 __attribute__((ext_vector_type(8)));
typedef float  fx4  __attribute__((ext_vector_type(4)));

#define CDIM 768
#define TSEQ 1024
#define NHEAD 12
#define HDIM 64
#define NLAYER 12
#define MROWS 4096          // B*T
#define VOCAB 50257
#define VPAD  50432

__device__ __forceinline__ void gload_lds16(const void* g, void* l) {
  __builtin_amdgcn_global_load_lds(
      (const __attribute__((address_space(1))) void*)g,
      (__attribute__((address_space(3))) void*)l, 16, 0, 0);
}

__device__ __forceinline__ fx4 mfma16(bfx8 a, bfx8 b, fx4 c) {
  return __builtin_amdgcn_mfma_f32_16x16x32_bf16(a, b, c, 0, 0, 0);
}

// ---------------------------------------------------------------------------
// 128x128 GEMM, BK=32, 32KB LDS double-buffer, 4 blocks/CU. 4 waves (2Mx2N),
// wave tile 64x64, acc 4x4. Swizzle slot ^= (row>>1)&3 (both-sides).
// blockIdx.z = split-K slice. flags: 1=bias,4=gelu,8=out bf16,16=V->vT.
// ---------------------------------------------------------------------------
__global__ __launch_bounds__(256, 4) void gemm128(
    const bh_t* __restrict__ A, const bh_t* __restrict__ B,
    const float* __restrict__ bias, void* __restrict__ outp,
    bh_t* __restrict__ vTp,
    int M, int N, int K, int lda, int flags)
{
  __shared__ bh_t A0[128][32], B0s[128][32];
  __shared__ bh_t A1[128][32], B1s[128][32];
  const int tid = threadIdx.x;
  const int wid = tid >> 6, lane = tid & 63;
  const int g = lane >> 4, r16 = lane & 15;
  const int wr = wid >> 1, wc = wid & 1;        // 2M x 2N waves
  const int m0 = blockIdx.x * 128, n0 = blockIdx.y * 128;
  const int swk = (g ^ ((r16 >> 1) & 3)) * 8;

  const bh_t* Ab = A + (size_t)blockIdx.z * K + (size_t)m0 * lda;
  const bh_t* Bb = B + (size_t)blockIdx.z * K + (size_t)n0 * lda;
  const int nt = K >> 5;

  fx4 acc[4][4] = {};

  auto stage = [&](bh_t* dA, bh_t* dB, int t) {
    const int k0 = t << 5;
    #pragma unroll
    for (int j = 0; j < 2; ++j) {
      const int idx = j * 256 + tid;          // 16B units, 0..511
      const int row = idx >> 2;               // 0..127
      const int slot = (idx & 3) ^ ((row >> 1) & 3);
      gload_lds16(Ab + (size_t)row * lda + k0 + slot * 8, dA + (size_t)idx * 8);
    }
    #pragma unroll
    for (int j = 0; j < 2; ++j) {
      const int idx = j * 256 + tid;
      const int row = idx >> 2;
      const int slot = (idx & 3) ^ ((row >> 1) & 3);
      gload_lds16(Bb + (size_t)row * lda + k0 + slot * 8, dB + (size_t)idx * 8);
    }
  };

#define N_TILE(CA, CB, NA, NB, T)                                             \
  {                                                                           \
    if ((T) + 1 < nt) stage(&NA[0][0], &NB[0][0], (T) + 1);                   \
    bfx8 av[4], bv[4];                                                        \
    _Pragma("unroll")                                                         \
    for (int ni = 0; ni < 4; ++ni)                                            \
      bv[ni] = *(const bfx8*)(&CB[wc * 64 + ni * 16 + r16][0] + swk);         \
    _Pragma("unroll")                                                         \
    for (int mi = 0; mi < 4; ++mi)                                            \
      av[mi] = *(const bfx8*)(&CA[wr * 64 + mi * 16 + r16][0] + swk);         \
    asm volatile("s_waitcnt lgkmcnt(0)" ::: "memory");                        \
    __builtin_amdgcn_s_setprio(1);                                            \
    _Pragma("unroll")                                                         \
    for (int mi = 0; mi < 4; ++mi)                                            \
      _Pragma("unroll")                                                       \
      for (int ni = 0; ni < 4; ++ni)                                          \
        acc[mi][ni] = mfma16(av[mi], bv[ni], acc[mi][ni]);                    \
    __builtin_amdgcn_s_setprio(0);                                            \
    asm volatile("s_waitcnt vmcnt(0)" ::: "memory");                          \
    __builtin_amdgcn_s_barrier();                                             \
    asm volatile("" ::: "memory");                                            \
  }

  stage(&A0[0][0], &B0s[0][0], 0);
  asm volatile("s_waitcnt vmcnt(0)" ::: "memory");
  __builtin_amdgcn_s_barrier();
  asm volatile("" ::: "memory");

  for (int t = 0; t < nt; t += 2) {
    N_TILE(A0, B0s, A1, B1s, t);
    N_TILE(A1, B1s, A0, B0s, t + 1);
  }
#undef N_TILE

  const bool hasBias = flags & 1, doGelu = flags & 4, outBf = flags & 8;
  const bool wantVT  = flags & 16;
  float* outF = (float*)outp + (size_t)blockIdx.z * ((size_t)M * N);
  bh_t*  outB = (bh_t*)outp;
  #pragma unroll
  for (int mi = 0; mi < 4; ++mi) {
    const int rowb = m0 + wr * 64 + mi * 16 + 4 * g;
    #pragma unroll
    for (int ni = 0; ni < 4; ++ni) {
      const int col = n0 + wc * 64 + ni * 16 + r16;
      if (col >= N) continue;
      const float bv = hasBias ? bias[col] : 0.0f;
      if (wantVT && col >= 2 * CDIM) {
        const int hd = col - 2 * CDIM;           // h*64 + d, 0..767
        const int bq = rowb >> 10;               // batch index
        const int t0 = rowb & 1023;
        bfx4 vv;
        #pragma unroll
        for (int rr = 0; rr < 4; ++rr) vv[rr] = (bh_t)(acc[mi][ni][rr] + bv);
        *(bfx4*)(vTp + ((size_t)(bq * 768 + hd)) * TSEQ + t0) = vv;
      } else {
        #pragma unroll
        for (int rr = 0; rr < 4; ++rr) {
          const size_t idx = (size_t)(rowb + rr) * N + col;
          float v = acc[mi][ni][rr] + bv;
          if (doGelu) v = 0.5f * v * (1.0f + erff(v * 0.70710678118654752f));
          if (outBf) outB[idx] = (bh_t)v; else outF[idx] = v;
        }
      }
    }
  }
}

// ---------------------------------------------------------------------------
// 256x128 GEMM — lm_head only. BK=32, 48KB LDS dbuf, 2 blocks/CU, 8 waves
// (2Mx4N), wave tile 128x32, acc 8x2. f32 out.
// ---------------------------------------------------------------------------
__global__ __launch_bounds__(512, 4) void gemm256n(
    const bh_t* __restrict__ A, const bh_t* __restrict__ B,
    float* __restrict__ outF, int M, int N, int K, int lda)
{
  __shared__ bh_t A0[256][32], B0s[128][32];
  __shared__ bh_t A1[256][32], B1s[128][32];
  const int tid = threadIdx.x;
  const int wid = tid >> 6, lane = tid & 63;
  const int g = lane >> 4, r16 = lane & 15;
  const int wr = wid >> 2, wc = wid & 3;
  const int m0 = blockIdx.x * 256, n0 = blockIdx.y * 128;
  const int swk = (g ^ ((r16 >> 1) & 3)) * 8;

  const bh_t* Ab = A + (size_t)m0 * lda;
  const bh_t* Bb = B + (size_t)n0 * lda;
  const int nt = K >> 5;

  fx4 acc[8][2] = {};

  auto stage = [&](bh_t* dA, bh_t* dB, int t) {
    const int k0 = t << 5;
    #pragma unroll
    for (int j = 0; j < 2; ++j) {
      const int idx = j * 512 + tid;
      const int row = idx >> 2;
      const int slot = (idx & 3) ^ ((row >> 1) & 3);
      gload_lds16(Ab + (size_t)row * lda + k0 + slot * 8, dA + (size_t)idx * 8);
    }
    {
      const int idx = tid;
      const int row = idx >> 2;
      const int slot = (idx & 3) ^ ((row >> 1) & 3);
      gload_lds16(Bb + (size_t)row * lda + k0 + slot * 8, dB + (size_t)idx * 8);
    }
  };

#define N_TILE(CA, CB, NA, NB, T)                                             \
  {                                                                           \
    if ((T) + 1 < nt) stage(&NA[0][0], &NB[0][0], (T) + 1);                   \
    bfx8 av[8], bv[2];                                                        \
    _Pragma("unroll")                                                         \
    for (int ni = 0; ni < 2; ++ni)                                            \
      bv[ni] = *(const bfx8*)(&CB[wc * 32 + ni * 16 + r16][0] + swk);         \
    _Pragma("unroll")                                                         \
    for (int mi = 0; mi < 8; ++mi)                                            \
      av[mi] = *(const bfx8*)(&CA[wr * 128 + mi * 16 + r16][0] + swk);        \
    asm volatile("s_waitcnt lgkmcnt(0)" ::: "memory");                        \
    __builtin_amdgcn_s_setprio(1);                                            \
    _Pragma("unroll")                                                         \
    for (int mi = 0; mi < 8; ++mi)                                            \
      _Pragma("unroll")                                                       \
      for (int ni = 0; ni < 2; ++ni)                                          \
        acc[mi][ni] = mfma16(av[mi], bv[ni], acc[mi][ni]);                    \
    __builtin_amdgcn_s_setprio(0);                                            \
    asm volatile("s_waitcnt vmcnt(0)" ::: "memory");                          \
    __builtin_amdgcn_s_barrier();                                             \
    asm volatile("" ::: "memory");                                            \
  }

  stage(&A0[0][0], &B0s[0][0], 0);
  asm volatile("s_waitcnt vmcnt(0)" ::: "memory");
  __builtin_amdgcn_s_barrier();
  asm volatile("" ::: "memory");

  for (int t = 0; t < nt; t += 2) {
    N_TILE(A0, B0s, A1, B1s, t);
    N_TILE(A1, B1s, A0, B0s, t + 1);
  }
#undef N_TILE

  #pragma unroll
  for (int mi = 0; mi < 8; ++mi) {
    const int rowb = m0 + wr * 128 + mi * 16 + 4 * g;
    #pragma unroll
    for (int ni = 0; ni < 2; ++ni) {
      const int col = n0 + wc * 32 + ni * 16 + r16;
      if (col >= N) continue;
      #pragma unroll
      for (int rr = 0; rr < 4; ++rr)
        outF[(size_t)(rowb + rr) * N + col] = acc[mi][ni][rr];
    }
  }
}

// ---------------------------------------------------------------------------
// fused split-K reduce + residual + LayerNorm
// ---------------------------------------------------------------------------
__global__ __launch_bounds__(256) void skred_ln(
    const float* __restrict__ part, const float* __restrict__ bias,
    float* __restrict__ x, const float* __restrict__ w,
    const float* __restrict__ bb, bh_t* __restrict__ out, int S)
{
  const int wave = threadIdx.x >> 6, lane = threadIdx.x & 63;
  const int row = blockIdx.x * 4 + wave;
  const size_t base = (size_t)row * CDIM;
  const int off = lane * 4;
  const size_t stride = (size_t)MROWS * CDIM;

  float4 v0 = *(const float4*)(x + base + off);
  float4 v1 = *(const float4*)(x + base + 256 + off);
  float4 v2 = *(const float4*)(x + base + 512 + off);
  for (int s = 0; s < S; ++s) {
    const float* pr = part + s * stride + base;
    const float4 p0 = *(const float4*)(pr + off);
    const float4 p1 = *(const float4*)(pr + 256 + off);
    const float4 p2 = *(const float4*)(pr + 512 + off);
    v0.x += p0.x; v0.y += p0.y; v0.z += p0.z; v0.w += p0.w;
    v1.x += p1.x; v1.y += p1.y; v1.z += p1.z; v1.w += p1.w;
    v2.x += p2.x; v2.y += p2.y; v2.z += p2.z; v2.w += p2.w;
  }
  const float4 q0 = *(const float4*)(bias + off);
  const float4 q1 = *(const float4*)(bias + 256 + off);
  const float4 q2 = *(const float4*)(bias + 512 + off);
  v0.x += q0.x; v0.y += q0.y; v0.z += q0.z; v0.w += q0.w;
  v1.x += q1.x; v1.y += q1.y; v1.z += q1.z; v1.w += q1.w;
  v2.x += q2.x; v2.y += q2.y; v2.z += q2.z; v2.w += q2.w;
  *(float4*)(x + base + off) = v0;
  *(float4*)(x + base + 256 + off) = v1;
  *(float4*)(x + base + 512 + off) = v2;

  float s1 = v0.x + v0.y + v0.z + v0.w + v1.x + v1.y + v1.z + v1.w
           + v2.x + v2.y + v2.z + v2.w;
  float ss = v0.x*v0.x + v0.y*v0.y + v0.z*v0.z + v0.w*v0.w
           + v1.x*v1.x + v1.y*v1.y + v1.z*v1.z + v1.w*v1.w
           + v2.x*v2.x + v2.y*v2.y + v2.z*v2.z + v2.w*v2.w;
  #pragma unroll
  for (int d = 1; d < 64; d <<= 1) { s1 += __shfl_xor(s1, d); ss += __shfl_xor(ss, d); }
  const float mean = s1 * (1.0f / 768.0f);
  const float inv = rsqrtf(ss * (1.0f / 768.0f) - mean * mean + 1e-5f);
  bh_t* orow = out + base;

  const float4 w0 = *(const float4*)(w + off),       b0 = *(const float4*)(bb + off);
  const float4 w1 = *(const float4*)(w + 256 + off), b1 = *(const float4*)(bb + 256 + off);
  const float4 w2 = *(const float4*)(w + 512 + off), b2 = *(const float4*)(bb + 512 + off);
  bfx4 o;
  o[0] = (bh_t)((v0.x - mean) * inv * w0.x + b0.x);
  o[1] = (bh_t)((v0.y - mean) * inv * w0.y + b0.y);
  o[2] = (bh_t)((v0.z - mean) * inv * w0.z + b0.z);
  o[3] = (bh_t)((v0.w - mean) * inv * w0.w + b0.w);
  *(bfx4*)(orow + off) = o;
  o[0] = (bh_t)((v1.x - mean) * inv * w1.x + b1.x);
  o[1] = (bh_t)((v1.y - mean) * inv * w1.y + b1.y);
  o[2] = (bh_t)((v1.z - mean) * inv * w1.z + b1.z);
  o[3] = (bh_t)((v1.w - mean) * inv * w1.w + b1.w);
  *(bfx4*)(orow + 256 + off) = o;
  o[0] = (bh_t)((v2.x - mean) * inv * w2.x + b2.x);
  o[1] = (bh_t)((v2.y - mean) * inv * w2.y + b2.y);
  o[2] = (bh_t)((v2.z - mean) * inv * w2.z + b2.z);
  o[3] = (bh_t)((v2.w - mean) * inv * w2.w + b2.w);
  *(bfx4*)(orow + 512 + off) = o;
}

// ---------------------------------------------------------------------------
// Flash attention, causal. One wave per (b, h, 16 q-rows).
// ---------------------------------------------------------------------------
__global__ __launch_bounds__(256) void attn_fwd(
    const bh_t* __restrict__ qkv, const bh_t* __restrict__ vT,
    bh_t* __restrict__ outb)
{
  __shared__ bh_t P[4][16][56];
  const int wave = threadIdx.x >> 6, lane = threadIdx.x & 63;
  const int g = lane >> 4, r16 = lane & 15;
  const int gw = blockIdx.x * 4 + wave;
  const int qblk = gw & 63;
  const int bh = gw >> 6;
  const int h = bh % NHEAD, b = bh / NHEAD;
  const int qbase = qblk * 16;
  const int qidx = qbase + r16;

  const bh_t* qp = qkv + (size_t)(b * TSEQ + qbase + r16) * (3 * CDIM) + h * HDIM + 8 * g;
  const bfx8 qf0 = *(const bfx8*)qp;
  const bfx8 qf1 = *(const bfx8*)(qp + 32);

  fx4 o[4] = {};
  float m = -INFINITY, l = 0.0f;
  const int ntiles = qblk / 2 + 1;

  for (int t = 0; t < ntiles; ++t) {
    const int kv0 = t * 32;
    const bh_t* kp = qkv + (size_t)(b * TSEQ + kv0 + r16) * (3 * CDIM) + CDIM + h * HDIM + 8 * g;
    const bfx8 ka0 = *(const bfx8*)kp;
    const bfx8 ka1 = *(const bfx8*)(kp + 32);
    const bfx8 kb0 = *(const bfx8*)(kp + 16 * (3 * CDIM));
    const bfx8 kb1 = *(const bfx8*)(kp + 16 * (3 * CDIM) + 32);
    fx4 s0 = {}, s1 = {};
    s0 = mfma16(ka0, qf0, s0); s0 = mfma16(ka1, qf1, s0);   // S^T: [kv][q]
    s1 = mfma16(kb0, qf0, s1); s1 = mfma16(kb1, qf1, s1);

    float mx = -INFINITY;
    float sv0[4], sv1[4];
    #pragma unroll
    for (int rr = 0; rr < 4; ++rr) {
      const int kva = kv0 + 4 * g + rr;
      const int kvb = kva + 16;
      sv0[rr] = (kva <= qidx) ? s0[rr] * 0.125f : -INFINITY;
      sv1[rr] = (kvb <= qidx) ? s1[rr] * 0.125f : -INFINITY;
      mx = fmaxf(mx, fmaxf(sv0[rr], sv1[rr]));
    }
    mx = fmaxf(mx, __shfl_xor(mx, 16));
    mx = fmaxf(mx, __shfl_xor(mx, 32));
    const float mnew = fmaxf(m, mx);
    const float corr = __expf(m - mnew);

    float ps = 0.0f;
    float pv0[4], pv1[4];
    #pragma unroll
    for (int rr = 0; rr < 4; ++rr) {
      pv0[rr] = __expf(sv0[rr] - mnew);
      pv1[rr] = __expf(sv1[rr] - mnew);
      ps += pv0[rr] + pv1[rr];
    }
    ps += __shfl_xor(ps, 16);
    ps += __shfl_xor(ps, 32);
    l = l * corr + ps;
    m = mnew;

    #pragma unroll
    for (int rr = 0; rr < 4; ++rr) {
      const float cr = __shfl(corr, 4 * g + rr);
      o[0][rr] *= cr; o[1][rr] *= cr; o[2][rr] *= cr; o[3][rr] *= cr;
    }

    bfx4 w0, w1;
    #pragma unroll
    for (int rr = 0; rr < 4; ++rr) { w0[rr] = (bh_t)pv0[rr]; w1[rr] = (bh_t)pv1[rr]; }
    *(bfx4*)&P[wave][r16][4 * g]      = w0;
    *(bfx4*)&P[wave][r16][16 + 4 * g] = w1;
    __builtin_amdgcn_wave_barrier();
    const bfx8 pf = *(const bfx8*)&P[wave][r16][8 * g];

    #pragma unroll
    for (int fi = 0; fi < 4; ++fi) {
      const bh_t* vp = vT + (size_t)(bh * HDIM + fi * 16 + r16) * TSEQ + kv0 + 8 * g;
      const bfx8 vf = *(const bfx8*)vp;
      o[fi] = mfma16(pf, vf, o[fi]);
    }
  }

  #pragma unroll
  for (int rr = 0; rr < 4; ++rr) {
    const float lr = __shfl(l, 4 * g + rr);
    const float inv = 1.0f / lr;
    const int trow = b * TSEQ + qbase + 4 * g + rr;
    #pragma unroll
    for (int fi = 0; fi < 4; ++fi)
      outb[(size_t)trow * CDIM + h * HDIM + fi * 16 + r16] = (bh_t)(o[fi][rr] * inv);
  }
}

// ---------------------------------------------------------------------------
// fused embedding + LayerNorm: x = tok[id] + pos;  out = LN(x)*w + b (bf16).
// ---------------------------------------------------------------------------
__global__ __launch_bounds__(256) void embed_ln(
    const int* __restrict__ ids, const float* __restrict__ tok,
    const float* __restrict__ pos, float* __restrict__ x,
    const float* __restrict__ w, const float* __restrict__ bb,
    bh_t* __restrict__ out)
{
  const int wave = threadIdx.x >> 6, lane = threadIdx.x & 63;
  const int row = blockIdx.x * 4 + wave;
  const int t = row & (TSEQ - 1);
  const int id = ids[row];
  const float* tr = tok + (size_t)id * CDIM;
  const float* pr = pos + (size_t)t * CDIM;
  const int off = lane * 4;

  float4 v0 = *(const float4*)(tr + off);
  float4 v1 = *(const float4*)(tr + 256 + off);
  float4 v2 = *(const float4*)(tr + 512 + off);
  const float4 p0 = *(const float4*)(pr + off);
  const float4 p1 = *(const float4*)(pr + 256 + off);
  const float4 p2 = *(const float4*)(pr + 512 + off);
  v0.x += p0.x; v0.y += p0.y; v0.z += p0.z; v0.w += p0.w;
  v1.x += p1.x; v1.y += p1.y; v1.z += p1.z; v1.w += p1.w;
  v2.x += p2.x; v2.y += p2.y; v2.z += p2.z; v2.w += p2.w;

  const size_t base = (size_t)row * CDIM;
  *(float4*)(x + base + off) = v0;
  *(float4*)(x + base + 256 + off) = v1;
  *(float4*)(x + base + 512 + off) = v2;

  float s  = v0.x + v0.y + v0.z + v0.w + v1.x + v1.y + v1.z + v1.w
           + v2.x + v2.y + v2.z + v2.w;
  float ss = v0.x*v0.x + v0.y*v0.y + v0.z*v0.z + v0.w*v0.w
           + v1.x*v1.x + v1.y*v1.y + v1.z*v1.z + v1.w*v1.w
           + v2.x*v2.x + v2.y*v2.y + v2.z*v2.z + v2.w*v2.w;
  #pragma unroll
  for (int d = 1; d < 64; d <<= 1) { s += __shfl_xor(s, d); ss += __shfl_xor(ss, d); }
  const float mean = s * (1.0f / 768.0f);
  const float inv = rsqrtf(ss * (1.0f / 768.0f) - mean * mean + 1e-5f);
  bh_t* orow = out + base;

  const float4 w0 = *(const float4*)(w + off),       b0 = *(const float4*)(bb + off);
  const float4 w1 = *(const float4*)(w + 256 + off), b1 = *(const float4*)(bb + 256 + off);
  const float4 w2 = *(const float4*)(w + 512 + off), b2 = *(const float4*)(bb + 512 + off);
  bfx4 o;
  o[0] = (bh_t)((v0.x - mean) * inv * w0.x + b0.x);
  o[1] = (bh_t)((v0.y - mean) * inv * w0.y + b0.y);
  o[2] = (bh_t)((v0.z - mean) * inv * w0.z + b0.z);
  o[3] = (bh_t)((v0.w - mean) * inv * w0.w + b0.w);
  *(bfx4*)(orow + off) = o;
  o[0] = (bh_t)((v1.x - mean) * inv * w1.x + b1.x);
  o[1] = (bh_t)((v1.y - mean) * inv * w1.y + b1.y);
  o[2] = (bh_t)((v1.z - mean) * inv * w1.z + b1.z);
  o[3] = (bh_t)((v1.w - mean) * inv * w1.w + b1.w);
  *(bfx4*)(orow + 256 + off) = o;
  o[0] = (bh_t)((v2.x - mean) * inv * w2.x + b2.x);
  o[1] = (bh_t)((v2.y - mean) * inv * w2.y + b2.y);
  o[2] = (bh_t)((v2.z - mean) * inv * w2.z + b2.z);
  o[3] = (bh_t)((v2.w - mean) * inv * w2.w + b2.w);
  *(bfx4*)(orow + 512 + off) = o;
}

// transpose + f32->bf16: in [L][R][Cn] -> out [L][Cn][R]
__global__ void tconv(const float* __restrict__ in, bh_t* __restrict__ out, int R, int Cn)
{
  __shared__ float tile[32][33];
  const size_t msz = (size_t)R * Cn;
  in  += msz * blockIdx.z;
  out += msz * blockIdx.z;
  const int tx = threadIdx.x & 31, ty = threadIdx.x >> 5;
  const int c0 = blockIdx.x * 32, r0 = blockIdx.y * 32;
  #pragma unroll
  for (int i = 0; i < 32; i += 8)
    tile[ty + i][tx] = in[(size_t)(r0 + ty + i) * Cn + c0 + tx];
  __syncthreads();
  #pragma unroll
  for (int i = 0; i < 32; i += 8)
    out[(size_t)(c0 + ty + i) * R + r0 + tx] = (bh_t)tile[tx][ty + i];
}

// tok_emb f32 [V][C] -> bf16 [VPAD][C], zero-padded rows
__global__ void embconv(const float* __restrict__ in, bh_t* __restrict__ out)
{
  const size_t i4 = ((size_t)blockIdx.x * 256 + threadIdx.x) * 4;
  if (i4 >= (size_t)VPAD * CDIM) return;
  const size_t vlim = (size_t)VOCAB * CDIM;
  float4 f = make_float4(0.f, 0.f, 0.f, 0.f);
  if (i4 < vlim) f = *(const float4*)(in + i4);
  bfx4 o;
  o[0] = (bh_t)f.x; o[1] = (bh_t)f.y; o[2] = (bh_t)f.z; o[3] = (bh_t)f.w;
  *(bfx4*)(out + i4) = o;
}

// ---------------------------------------------------------------------------
extern "C" void kernel_launch(void* const* d_in, const int* in_sizes, int n_in,
                              void* d_out, int out_size, void* d_ws, size_t ws_size,
                              hipStream_t stream)
{
  (void)in_sizes; (void)n_in; (void)out_size; (void)ws_size;
  const int*   ids    = (const int*)d_in[0];
  const float* tok    = (const float*)d_in[1];
  const float* pos    = (const float*)d_in[2];
  const float* qkv_w  = (const float*)d_in[3];
  const float* qkv_b  = (const float*)d_in[4];
  const float* proj_w = (const float*)d_in[5];
  const float* proj_b = (const float*)d_in[6];
  const float* ln1_w  = (const float*)d_in[7];
  const float* ln1_b  = (const float*)d_in[8];
  const float* ln2_w  = (const float*)d_in[9];
  const float* ln2_b  = (const float*)d_in[10];
  const float* fc1_w  = (const float*)d_in[11];
  const float* fc1_b  = (const float*)d_in[12];
  const float* fc2_w  = (const float*)d_in[13];
  const float* fc2_b  = (const float*)d_in[14];
  const float* lnf_w  = (const float*)d_in[15];
  const float* lnf_b  = (const float*)d_in[16];

  // ---- scratch in ws (activations + embT), ~153 MB
  char* wp = (char*)d_ws;
  auto carve = [&](size_t bytes) { char* p = wp; wp += (bytes + 255) & ~(size_t)255; return p; };
  float* x     = (float*)carve((size_t)MROWS * CDIM * 4);
  bh_t*  hbuf  = (bh_t*)carve((size_t)MROWS * CDIM * 2);
  bh_t*  qkvb  = (bh_t*)carve((size_t)MROWS * 3 * CDIM * 2);
  bh_t*  vT    = (bh_t*)carve((size_t)48 * HDIM * TSEQ * 2);
  bh_t*  attno = (bh_t*)carve((size_t)MROWS * CDIM * 2);
  bh_t*  mlp1  = (bh_t*)carve((size_t)MROWS * 3072 * 2);
  bh_t*  embT  = (bh_t*)carve((size_t)VPAD * CDIM * 2);

  // ---- staged in d_out (dead before lm_head overwrites it), ~270 MB of 823
  char* op = (char*)d_out;
  auto carveO = [&](size_t bytes) { char* p = op; op += (bytes + 255) & ~(size_t)255; return p; };
  bh_t* qkvwT  = (bh_t*)carveO((size_t)NLAYER * 3 * CDIM * CDIM * 2);
  bh_t* projwT = (bh_t*)carveO((size_t)NLAYER * CDIM * CDIM * 2);
  bh_t* fc1wT  = (bh_t*)carveO((size_t)NLAYER * 3072 * CDIM * 2);
  bh_t* fc2wT  = (bh_t*)carveO((size_t)NLAYER * CDIM * 3072 * 2);
  float* skpart = (float*)carveO((size_t)4 * MROWS * CDIM * 4);   // split-K partials

  tconv<<<dim3(2304 / 32, 768 / 32, NLAYER), 256, 0, stream>>>(qkv_w, qkvwT, 768, 2304);
  tconv<<<dim3(768 / 32, 768 / 32, NLAYER), 256, 0, stream>>>(proj_w, projwT, 768, 768);
  tconv<<<dim3(3072 / 32, 768 / 32, NLAYER), 256, 0, stream>>>(fc1_w, fc1wT, 768, 3072);
  tconv<<<dim3(768 / 32, 3072 / 32, NLAYER), 256, 0, stream>>>(fc2_w, fc2wT, 3072, 768);
  embconv<<<((VPAD * CDIM / 4) + 255) / 256, 256, 0, stream>>>(tok, embT);
  embed_ln<<<MROWS / 4, 256, 0, stream>>>(ids, tok, pos, x, ln1_w, ln1_b, hbuf);

  for (int l = 0; l < NLAYER; ++l) {
    // qkv: grid 32x18 = 576 blocks; V columns go straight to vT (flag 16)
    gemm128<<<dim3(32, 18), 256, 0, stream>>>(hbuf, qkvwT + (size_t)l * 3 * CDIM * CDIM,
        qkv_b + l * 3 * CDIM, qkvb, vT, MROWS, 3 * CDIM, CDIM, CDIM, 1 | 8 | 16);
    attn_fwd<<<768, 256, 0, stream>>>(qkvb, vT, attno);
    // proj: split-K x2 (K_eff=384, nt=12), grid 32x6x2 = 384 blocks
    gemm128<<<dim3(32, 6, 2), 256, 0, stream>>>(attno,
        projwT + (size_t)l * CDIM * CDIM, nullptr, skpart, nullptr,
        MROWS, CDIM, 384, CDIM, 0);
    skred_ln<<<MROWS / 4, 256, 0, stream>>>(skpart, proj_b + l * CDIM, x,
        ln2_w + l * CDIM, ln2_b + l * CDIM, hbuf, 2);
    // fc1: grid 32x24 = 768 blocks
    gemm128<<<dim3(32, 24), 256, 0, stream>>>(hbuf, fc1wT + (size_t)l * 3072 * CDIM,
        fc1_b + l * 3072, mlp1, nullptr, MROWS, 3072, CDIM, CDIM, 1 | 4 | 8);
    // fc2: split-K x4 (K_eff=768, nt=24), grid 32x6x4 = 768 blocks
    gemm128<<<dim3(32, 6, 4), 256, 0, stream>>>(mlp1, fc2wT + (size_t)l * CDIM * 3072,
        nullptr, skpart, nullptr, MROWS, CDIM, 768, 3072, 0);
    const float* nw = (l + 1 < NLAYER) ? ln1_w + (l + 1) * CDIM : lnf_w;
    const float* nb = (l + 1 < NLAYER) ? ln1_b + (l + 1) * CDIM : lnf_b;
    skred_ln<<<MROWS / 4, 256, 0, stream>>>(skpart, fc2_b + l * CDIM, x, nw, nb, hbuf, 4);
  }
  // lm_head: 256x128 kernel (wide M-tile: less f32 write amplification)
  gemm256n<<<dim3(16, 393), 512, 0, stream>>>(hbuf, embT,
      (float*)d_out, MROWS, VOCAB, CDIM, CDIM);
}